// Round 11
// baseline (466.138 us; speedup 1.0000x reference)
//
#include <hip/hip_runtime.h>
#include <hip/hip_bf16.h>
#include <math.h>

#define NN 10000
#define NE 160000
#define MUL 128
#define ADIM 10
#define RADF 8
#define HID 64
#define INV_SQRT3 0.57735026918962576f
#define NB64 157           // ceil(NN/64)
#define WEDGE 16           // edges per wave-window
#define NWIN (NE/WEDGE)    // 10000 windows

typedef __attribute__((ext_vector_type(8))) short bf16x8;
typedef __attribute__((ext_vector_type(4))) float f32x4;

__device__ __forceinline__ float silu_f(float x){ return x / (1.0f + __expf(-x)); }
__device__ __forceinline__ float sigmoid_f(float x){ return 1.0f / (1.0f + __expf(-x)); }
__device__ __forceinline__ unsigned short f2b(float f){
  union{float f; unsigned u;} v; v.f=f;
  unsigned r = (v.u + 0x7fffu + ((v.u>>16)&1u))>>16;
  return (unsigned short)r;
}
__device__ __forceinline__ unsigned short f2bh(float f){
  __hip_bfloat16 h = __float2bfloat16(f);
  union{ __hip_bfloat16 h; unsigned short u; } v; v.h=h; return v.u;
}
__device__ __forceinline__ unsigned f2b2(float lo, float hi){
  float2 t; t.x=lo; t.y=hi;
  __hip_bfloat162 h2 = __float22bfloat162_rn(t);
  union{ __hip_bfloat162 h; unsigned u; } v; v.h=h2; return v.u;
}
__device__ __forceinline__ float b2f(unsigned short h){
  union{unsigned u; float f;} v; v.u = ((unsigned)h)<<16; return v.f;
}
__device__ __forceinline__ float b2f_lo(unsigned u){
  union{unsigned u; float f;} v; v.u = u<<16; return v.f;
}
__device__ __forceinline__ float b2f_hi(unsigned u){
  union{unsigned u; float f;} v; v.u = u & 0xffff0000u; return v.f;
}

// ---------------- per-node layer1 partials, packed {rad, den} float2 ----------------
__global__ __launch_bounds__(256) void k_nodeemb(
    const float* __restrict__ attrs, const float* __restrict__ Wc,
    float* __restrict__ pA, float* __restrict__ pB){
  int idx = blockIdx.x*256 + threadIdx.x;
  if (idx >= NN*64) return;
  int n = idx>>6, c = idx&63;
  float s0=0,s1=0,s2=0,s3=0;
  #pragma unroll
  for (int a=0;a<ADIM;a++){
    float x = attrs[n*ADIM+a];
    s0 += x*Wc[(0*ADIM+a)*64+c];
    s1 += x*Wc[(1*ADIM+a)*64+c];
    s2 += x*Wc[(2*ADIM+a)*64+c];
    s3 += x*Wc[(3*ADIM+a)*64+c];
  }
  pA[(size_t)n*128 + c*2 + 0] = s0;
  pA[(size_t)n*128 + c*2 + 1] = s2;
  pB[(size_t)n*128 + c*2 + 0] = s1;
  pB[(size_t)n*128 + c*2 + 1] = s3;
}

// ---------------- feat prep ----------------
__global__ __launch_bounds__(256) void k_feat_prep(
    const float* __restrict__ feats, unsigned short* __restrict__ fs16,
    unsigned short* __restrict__ fv16){
  int idx = blockIdx.x*256 + threadIdx.x;
  int n = idx >> 9, c = idx & 511;
  float v = feats[idx];
  if (c < 128) fs16[n*128 + c] = f2bh(v);
  else {
    int q = c - 128; int u = q/3; int i = q - 3*u;
    fv16[((size_t)n*3 + i)*128 + u] = f2bh(v);
  }
}

// ---------------- weight prep: transpose + bf16 cast (+ wcomb merged) ----------------
__global__ __launch_bounds__(256) void k_prep(
    const float* __restrict__ Wr2, const float* __restrict__ Wr3,
    const float* __restrict__ Wr4,
    const float* __restrict__ Wl10, const float* __restrict__ Wl11,
    const float* __restrict__ Wl20, const float* __restrict__ Wl21,
    const float* __restrict__ Wsk0, const float* __restrict__ Wup0, const float* __restrict__ Wres0,
    const float* __restrict__ Wsk1, const float* __restrict__ Wup1, const float* __restrict__ Wres1,
    const float* __restrict__ Wsrc, const float* __restrict__ Wtgt,
    const float* __restrict__ Wr1, const float* __restrict__ Wd1,
    unsigned short* __restrict__ WTr2, unsigned short* __restrict__ WTr3,
    unsigned short* __restrict__ WTr4,
    unsigned short* __restrict__ Wl10T, unsigned short* __restrict__ Wl11T,
    unsigned short* __restrict__ Wl20T, unsigned short* __restrict__ Wl21T,
    unsigned short* __restrict__ WnsT, unsigned short* __restrict__ WnvT,
    float* __restrict__ Wc){
  int idx = blockIdx.x*256 + threadIdx.x;
  if (idx < 4096){
    int j = idx; int n=j>>6, k=j&63;
    WTr2[j] = f2b(Wr2[k*64+n]);
  } else if (idx < 8192){
    int j = idx-4096; int n=j>>6, k=j&63;
    WTr3[j] = f2b(Wr3[k*64+n]);
  } else if (idx < 40960){
    int j = idx-8192; int n=j>>6, k=j&63;
    WTr4[j] = f2b(Wr4[k*512+n]);
  } else if (idx < 106496){
    int j = idx-40960; int n=j>>8, k=j&255;
    Wl10T[j] = f2b(Wl10[k*256+n]);
  } else if (idx < 139264){
    int j = idx-106496; int n=j>>8, k=j&255;
    Wl11T[j] = f2b(Wl11[k*128+n]);
  } else if (idx < 155648){
    int j = idx-139264; int n=j>>7, k=j&127;
    Wl20T[j] = f2b(Wl20[k*128+n]);
  } else if (idx < 172032){
    int j = idx-155648; int n=j>>7, k=j&127;
    Wl21T[j] = f2b(Wl21[k*128+n]);
  } else if (idx < 237568){
    int j = idx-172032; int n=j>>7, k=j&127;
    float v;
    if (n < 128)      v = Wsk0[k*128+n];
    else if (n < 256) v = Wup0[k*128+(n-128)];
    else              v = Wres0[k*256+(n-256)];
    WnsT[j] = f2b(v);
  } else if (idx < 286720){
    int j = idx-237568; int n=j>>7, k=j&127;
    float v;
    if (n < 128)      v = Wsk1[k*128+n];
    else if (n < 256) v = Wup1[k*128+(n-128)];
    else              v = Wres1[k*128+(n-256)];
    WnvT[j] = f2b(v);
  } else if (idx < 286976){
    int j = idx - 286720;      // wcomb: Wc[m][10][64]
    int m = j>>6, c = j&63;
    const float* WA = (m&1)? Wtgt : Wsrc;
    const float* WB = (m<2)? Wr1 : Wd1;
    int koff = (m&1)? 136 : 8;
    for (int a=0;a<ADIM;a++){
      float s=0.f;
      for (int k=0;k<128;k++) s += WA[a*128+k]*WB[(koff+k)*64+c];
      Wc[(m*ADIM+a)*64+c] = s;
    }
  }
}

// ---------------- K1: per-node precompute via MFMA ----------------
__global__ __launch_bounds__(256) void k_node_pre2(
    const unsigned short* __restrict__ fs16, const unsigned short* __restrict__ fv16,
    const unsigned short* __restrict__ WnsT, const unsigned short* __restrict__ WnvT,
    float* __restrict__ out_sc,
    unsigned short* __restrict__ upk16,
    float* __restrict__ res_s, float* __restrict__ res_v){
  __shared__ unsigned short fA[64][136];
  int nb = blockIdx.x*64;
  int c = blockIdx.y;
  int g, ntc;
  if (c < 4){ g=0; ntc=c; } else { g = 1 + (c-4)/3; ntc = (c-4)%3; }
  int tid = threadIdx.x;
  int w = tid>>6, l = tid&63, m0 = w*16, lr = l&15, lg = l>>4;
  for (int idx=tid; idx<64*16; idx+=256){
    int row = idx>>4, s8 = idx&15;
    int n = min(nb+row, NN-1);
    const unsigned short* src = (g==0) ? &fs16[(size_t)n*128 + s8*8]
                                       : &fv16[((size_t)n*3 + (g-1))*128 + s8*8];
    *(uint4*)&fA[row][s8*8] = *(const uint4*)src;
  }
  __syncthreads();
  const unsigned short* WT = ((g==0)? WnsT : WnvT) + (size_t)ntc*128*128;
  f32x4 acc[8];
  #pragma unroll
  for (int t=0;t<8;t++) acc[t]=(f32x4)(0.f);
  #pragma unroll
  for (int kb=0;kb<4;kb++){
    bf16x8 a = *(const bf16x8*)&fA[m0+lr][kb*32 + lg*8];
    #pragma unroll
    for (int t=0;t<8;t++){
      bf16x8 b = *(const bf16x8*)&WT[(size_t)(t*16+lr)*128 + kb*32 + lg*8];
      acc[t] = __builtin_amdgcn_mfma_f32_16x16x32_bf16(a, b, acc[t], 0,0,0);
    }
  }
  #pragma unroll
  for (int t=0;t<8;t++){
    #pragma unroll
    for (int r=0;r<4;r++){
      int col = (ntc*8+t)*16 + lr;
      int row = m0 + lg*4 + r;
      int n = nb + row;
      if (n < NN){
        float v = acc[t][r];
        if (g==0){
          if (col < 128)      out_sc[(size_t)n*512 + col] = v;
          else if (col < 256){
            int cc = col-128;
            upk16[(size_t)n*512 + (cc&63)*8 + (cc>>6)] = f2bh(v);
          } else              res_s[(size_t)n*256 + col-256] = v;
        } else {
          int i = g-1;
          if (col < 128)      out_sc[(size_t)n*512 + 128 + col*3 + i] = v;
          else if (col < 256){
            int cc = col-128;
            upk16[(size_t)n*512 + (cc&63)*8 + (1+i)*2 + (cc>>6)] = f2bh(v);
          } else              res_v[((size_t)n*3+i)*128 + col-256] = v;
        }
      }
    }
  }
}

// ---------------- CSR build ----------------
__global__ __launch_bounds__(256) void k_deg(const int* __restrict__ eidx, int* __restrict__ deg){
  int i = blockIdx.x*256+threadIdx.x;
  if (i<NE) atomicAdd(&deg[eidx[2*i+1]],1);
}
__global__ __launch_bounds__(256) void k_scan(const int* __restrict__ deg, int* __restrict__ offsets){
  __shared__ int part[256];
  int t = threadIdx.x; int base = t*40;
  int s=0;
  for (int k=0;k<40;k++){ int idx=base+k; if (idx<NN) s+=deg[idx]; }
  part[t]=s; __syncthreads();
  if (t==0){ int run=0; for (int i=0;i<256;i++){ int v=part[i]; part[i]=run; run+=v; } }
  __syncthreads();
  int run = part[t];
  for (int k=0;k<40;k++){
    int idx=base+k;
    if (idx<=NN) offsets[idx]=run;
    if (idx<NN) run+=deg[idx];
  }
}
__global__ __launch_bounds__(256) void k_fill(
    const int* __restrict__ eidx, const float* __restrict__ ef, const float* __restrict__ ea,
    const int* __restrict__ offsets, int* __restrict__ cursor,
    int* __restrict__ sndbuf, int* __restrict__ rcvbuf,
    float4* __restrict__ ybuf, float* __restrict__ efb){
  int i = blockIdx.x*256+threadIdx.x;
  if (i<NE){
    int sn = eidx[2*i], rc = eidx[2*i+1];
    int p = offsets[rc] + atomicAdd(&cursor[rc],1);
    sndbuf[p]=sn; rcvbuf[p]=rc;
    ybuf[p] = ((const float4*)ea)[i];
    *(float4*)&efb[(size_t)p*8]     = *(const float4*)&ef[(size_t)i*8];
    *(float4*)&efb[(size_t)p*8 + 4] = *(const float4*)&ef[(size_t)i*8 + 4];
  }
}

// ---------------- K2: FUSED edge MLP + segmented accumulate (no tpw buffer) ---------
// 4 waves/block, each wave owns one 16-edge CSR window. Two-pass accumulate
// (pass0: groups A,B use xs; pass1: groups C,D use xv) keeps VGPR low.
// Interior segments -> direct f32 store; straddling -> pbufH/T, fixed by k_fixup.
__global__ __launch_bounds__(256) void k_edge(
    const int* __restrict__ sndbuf, const int* __restrict__ rcvbuf,
    const float* __restrict__ efb, const float4* __restrict__ ybuf,
    const float* __restrict__ pA, const float* __restrict__ pB,
    const float* __restrict__ Wr1, const float* __restrict__ Wd1, const float* __restrict__ Wd2,
    const unsigned short* __restrict__ WTr2, const unsigned short* __restrict__ WTr3,
    const unsigned short* __restrict__ WTr4,
    const int* __restrict__ offsets, const uint4* __restrict__ upk4,
    float* __restrict__ msg_s, float* __restrict__ msg_v, float* __restrict__ density,
    float* __restrict__ pbufH, float* __restrict__ pbufT,
    float* __restrict__ pbufHd, float* __restrict__ pbufTd){
  __shared__ unsigned short hA[64][72];
  __shared__ unsigned short hB[64][72];
  __shared__ unsigned pv[4][16][132];   // per wave: 2 G-slices, stride 66 (2-way banks)
  __shared__ float sy[64][4];
  int tid = threadIdx.x;
  int w = tid>>6, l = tid&63, m0 = w*16, lr = l&15, lg = l>>4;
  int W = blockIdx.x*4 + w;            // global window id
  int wbase = W*WEDGE;                 // first CSR pos of this wave's window
  // metadata + ef in registers
  int pos = wbase + (l&15);
  int v_meta = 0;
  if (l < 16)      v_meta = sndbuf[pos];
  else if (l < 32) v_meta = rcvbuf[pos];
  float ra = efb[(size_t)pos*8 + (l>>4)];
  float rb = efb[(size_t)pos*8 + 4 + (l>>4)];
  if (l < 16) *(float4*)&sy[m0+l][0] = ybuf[wbase + l];
  // ---- layer1 (VALU f32) + density segment walk ----
  {
    float wr[8], wd[8];
    #pragma unroll
    for (int k=0;k<8;k++){ wr[k]=Wr1[k*64+l]; wd[k]=Wd1[k*64+l]; }
    float wd2c = Wd2[l];
    float dAcc = 0.f;
    #pragma unroll
    for (int j=0;j<16;j++){
      int sn = __shfl(v_meta, j);
      int rc = __shfl(v_meta, 16+j);
      float2 av = *(const float2*)&pA[(size_t)sn*128 + l*2];
      float2 bv = *(const float2*)&pB[(size_t)rc*128 + l*2];
      float e0=__shfl(ra,j),    e1=__shfl(ra,16+j), e2=__shfl(ra,32+j), e3=__shfl(ra,48+j);
      float e4=__shfl(rb,j),    e5=__shfl(rb,16+j), e6=__shfl(rb,32+j), e7=__shfl(rb,48+j);
      float h  = av.x + bv.x;
      float hd = av.y + bv.y;
      h  += e0*wr[0]+e1*wr[1]+e2*wr[2]+e3*wr[3]+e4*wr[4]+e5*wr[5]+e6*wr[6]+e7*wr[7];
      hd += e0*wd[0]+e1*wd[1]+e2*wd[2]+e3*wd[3]+e4*wd[4]+e5*wd[5]+e6*wd[6]+e7*wd[7];
      hA[m0+j][l] = f2bh(silu_f(h));
      float sv = silu_f(hd)*wd2c;
      #pragma unroll
      for (int m=32;m;m>>=1) sv += __shfl_xor(sv, m);
      dAcc += 1.f - 2.f/(1.f + __expf(2.f*sv*sv));   // tanh(sv^2)
      int rcn = (j<15)? __shfl(v_meta, 16+j+1) : -1;
      if (j==15 || rc != rcn){
        if (l==0){
          bool head = offsets[rc] < wbase;
          bool tail = offsets[rc+1] > wbase+WEDGE;
          if (head) pbufHd[W]=dAcc;
          if (tail) pbufTd[W]=dAcc;
          if (!head && !tail) density[rc]=dAcc;
        }
        dAcc=0.f;
      }
    }
  }
  // ---- layer2: hA -> hB (wave-private, no barriers anywhere) ----
  {
    f32x4 acc[4];
    #pragma unroll
    for (int nt=0;nt<4;nt++) acc[nt]=(f32x4)(0.f);
    #pragma unroll
    for (int kb=0;kb<2;kb++){
      bf16x8 a = *(const bf16x8*)&hA[m0+lr][kb*32 + lg*8];
      #pragma unroll
      for (int nt=0;nt<4;nt++){
        bf16x8 b = *(const bf16x8*)&WTr2[(nt*16+lr)*64 + kb*32 + lg*8];
        acc[nt] = __builtin_amdgcn_mfma_f32_16x16x32_bf16(a, b, acc[nt], 0,0,0);
      }
    }
    #pragma unroll
    for (int nt=0;nt<4;nt++)
      #pragma unroll
      for (int r=0;r<4;r++)
        hB[m0+lg*4+r][nt*16+lr] = f2bh(silu_f(acc[nt][r]));
  }
  // ---- layer3: hB -> hA ----
  {
    f32x4 acc[4];
    #pragma unroll
    for (int nt=0;nt<4;nt++) acc[nt]=(f32x4)(0.f);
    #pragma unroll
    for (int kb=0;kb<2;kb++){
      bf16x8 a = *(const bf16x8*)&hB[m0+lr][kb*32 + lg*8];
      #pragma unroll
      for (int nt=0;nt<4;nt++){
        bf16x8 b = *(const bf16x8*)&WTr3[(nt*16+lr)*64 + kb*32 + lg*8];
        acc[nt] = __builtin_amdgcn_mfma_f32_16x16x32_bf16(a, b, acc[nt], 0,0,0);
      }
    }
    #pragma unroll
    for (int nt=0;nt<4;nt++)
      #pragma unroll
      for (int r=0;r<4;r++)
        hA[m0+lg*4+r][nt*16+lr] = f2bh(silu_f(acc[nt][r]));
  }
  // ---- layer4 + accumulate, two passes ----
  #pragma unroll
  for (int pass=0; pass<2; ++pass){
    // fragments: G = pass*2 + gg  ->  pv[w][row][gg*66 + col]
    #pragma unroll
    for (int gg=0; gg<2; ++gg){
      int G = pass*2 + gg;
      #pragma unroll
      for (int nt=0; nt<4; nt++){
        f32x4 aE=(f32x4)(0.f), aO=(f32x4)(0.f);
        #pragma unroll
        for (int kb=0; kb<2; kb++){
          bf16x8 a  = *(const bf16x8*)&hA[m0+lr][kb*32 + lg*8];
          bf16x8 bE = *(const bf16x8*)&WTr4[((2*G)*64+nt*16+lr)*64 + kb*32 + lg*8];
          bf16x8 bO = *(const bf16x8*)&WTr4[((2*G+1)*64+nt*16+lr)*64 + kb*32 + lg*8];
          aE = __builtin_amdgcn_mfma_f32_16x16x32_bf16(a, bE, aE, 0,0,0);
          aO = __builtin_amdgcn_mfma_f32_16x16x32_bf16(a, bO, aO, 0,0,0);
        }
        #pragma unroll
        for (int r=0;r<4;r++)
          pv[w][lg*4+r][gg*66 + nt*16+lr] = f2b2(aE[r], aO[r]);
      }
    }
    // row walk with segment flush
    float a0=0,a1=0,b00=0,b01=0,b10=0,b11=0,b20=0,b21=0;   // 8 accumulators
    #pragma unroll
    for (int j=0;j<16;j++){
      int sn = __shfl(v_meta, j);
      int rc = __shfl(v_meta, 16+j);
      unsigned p0 = pv[w][j][l];
      unsigned p1 = pv[w][j][66+l];
      float4 y = *(const float4*)&sy[m0+j][0];
      if (pass==0){
        unsigned xs = ((const unsigned*)upk4)[((size_t)sn*64 + l)*4];
        float xs0=b2f_lo(xs), xs1=b2f_hi(xs);
        a0 += b2f_lo(p0)*xs0*y.x;  a1 += b2f_hi(p0)*xs1*y.x;
        float t0 = b2f_lo(p1)*xs0, t1 = b2f_hi(p1)*xs1;
        b00 += t0*y.y; b01 += t1*y.y;
        b10 += t0*y.z; b11 += t1*y.z;
        b20 += t0*y.w; b21 += t1*y.w;
      } else {
        uint4 uq = upk4[(size_t)sn*64 + l];
        float xv00=b2f_lo(uq.y), xv01=b2f_hi(uq.y);
        float xv10=b2f_lo(uq.z), xv11=b2f_hi(uq.z);
        float xv20=b2f_lo(uq.w), xv21=b2f_hi(uq.w);
        float c0 = b2f_lo(p0)*y.x, c1 = b2f_hi(p0)*y.x;
        b00 += c0*xv00; b01 += c1*xv01;
        b10 += c0*xv10; b11 += c1*xv11;
        b20 += c0*xv20; b21 += c1*xv21;
        float dot0 = xv00*y.y + xv10*y.z + xv20*y.w;
        float dot1 = xv01*y.y + xv11*y.z + xv21*y.w;
        a0 += b2f_lo(p1)*dot0; a1 += b2f_hi(p1)*dot1;
      }
      int rcn = (j<15)? __shfl(v_meta, 16+j+1) : -1;
      if (j==15 || rc != rcn){
        bool head = offsets[rc] < wbase;
        bool tail = offsets[rc+1] > wbase+WEDGE;
        float sA0, sA1;             // s-channel values for this pass
        if (pass==0){ sA0=a0; sA1=a1; }
        else        { sA0=a0*INV_SQRT3; sA1=a1*INV_SQRT3; }
        int soff = (pass==0)? 0 : 128;
        int voff = (pass==0)? 0 : 128;
        if (head){
          float* pb = pbufH + (size_t)W*1024;
          pb[soff+l]=sA0; pb[soff+64+l]=sA1;
          float* qb = pb + 256;
          qb[voff+l]=b00; qb[voff+64+l]=b01;
          qb[voff+256+l]=b10; qb[voff+320+l]=b11;
          qb[voff+512+l]=b20; qb[voff+576+l]=b21;
        }
        if (tail){
          float* pb = pbufT + (size_t)W*1024;
          pb[soff+l]=sA0; pb[soff+64+l]=sA1;
          float* qb = pb + 256;
          qb[voff+l]=b00; qb[voff+64+l]=b01;
          qb[voff+256+l]=b10; qb[voff+320+l]=b11;
          qb[voff+512+l]=b20; qb[voff+576+l]=b21;
        }
        if (!head && !tail){
          float* ps = msg_s + (size_t)rc*256;
          ps[soff+l]=sA0; ps[soff+64+l]=sA1;
          float* pvv = msg_v + (size_t)rc*768;
          pvv[voff+l]=b00; pvv[voff+64+l]=b01;
          pvv[voff+256+l]=b10; pvv[voff+320+l]=b11;
          pvv[voff+512+l]=b20; pvv[voff+576+l]=b21;
        }
        a0=0;a1=0;b00=0;b01=0;b10=0;b11=0;b20=0;b21=0;
      }
    }
  }
}

// ---------------- K3: chain fixup for window-straddling nodes ----------------
__global__ __launch_bounds__(256) void k_fixup(
    const int* __restrict__ offsets,
    const float* __restrict__ pbufH, const float* __restrict__ pbufT,
    const float* __restrict__ pbufHd, const float* __restrict__ pbufTd,
    float* __restrict__ msg_s, float* __restrict__ msg_v, float* __restrict__ density){
  int n = blockIdx.x*4 + (threadIdx.x>>6);
  if (n >= NN) return;
  int l = threadIdx.x & 63;
  int s0 = offsets[n], s1 = offsets[n+1];
  if (s1 <= s0) return;
  int a = s0/WEDGE, b = (s1-1)/WEDGE;
  if (a == b) return;          // interior, already stored
  for (int c=l; c<1024; c+=64){
    float v = pbufT[(size_t)a*1024 + c];
    for (int m=a+1; m<=b; ++m) v += pbufH[(size_t)m*1024 + c];
    if (c < 256) msg_s[(size_t)n*256 + c] = v;
    else         msg_v[(size_t)n*768 + (c-256)] = v;
  }
  if (l==0){
    float dv = pbufTd[a];
    for (int m=a+1; m<=b; ++m) dv += pbufHd[m];
    density[n] = dv;
  }
}

// ---------------- K4a: lin1 (f32 messages) ----------------
__global__ __launch_bounds__(256) void k_post1(
    const float* __restrict__ msg_s, const float* __restrict__ msg_v,
    const float* __restrict__ density,
    const float* __restrict__ res_s, const float* __restrict__ res_v,
    const unsigned short* __restrict__ Wl10T, const unsigned short* __restrict__ Wl11T,
    const float* __restrict__ alphap, const float* __restrict__ betap,
    unsigned short* __restrict__ scal16, unsigned short* __restrict__ gate16,
    unsigned short* __restrict__ vtmp16){
  __shared__ unsigned short sm[64][264];
  __shared__ float sden[64];
  int nb = blockIdx.x*64, y = blockIdx.y;
  int tid = threadIdx.x;
  int w = tid>>6, l = tid&63, m0 = w*16, lr = l&15, lg = l>>4;
  for (int idx=tid; idx<64*32; idx+=256){
    int row = idx>>5, s8 = idx&31;
    int n = min(nb+row, NN-1);
    const float* src = (y<2)? &msg_s[(size_t)n*256 + s8*8]
                            : &msg_v[(size_t)n*768 + (y-2)*256 + s8*8];
    float4 a0 = *(const float4*)src, a1 = *(const float4*)(src+4);
    unsigned o4[4] = { f2b2(a0.x,a0.y), f2b2(a0.z,a0.w), f2b2(a1.x,a1.y), f2b2(a1.z,a1.w) };
    *(uint4*)&sm[row][s8*8] = *(uint4*)o4;
  }
  if (tid < 64){
    int n = min(nb+tid, NN-1);
    sden[tid] = density[n]*betap[0] + alphap[0]*20.0f;
  }
  __syncthreads();
  const unsigned short* BT = (y<2)? (Wl10T + (size_t)y*128*256) : Wl11T;
  f32x4 acc[8];
  #pragma unroll
  for (int t=0;t<8;t++) acc[t]=(f32x4)(0.f);
  for (int kb=0;kb<8;kb++){
    bf16x8 a = *(const bf16x8*)&sm[m0+lr][kb*32 + lg*8];
    #pragma unroll
    for (int t=0;t<8;t++){
      bf16x8 b = *(const bf16x8*)&BT[(size_t)(t*16+lr)*256 + kb*32 + lg*8];
      acc[t] = __builtin_amdgcn_mfma_f32_16x16x32_bf16(a, b, acc[t], 0,0,0);
    }
  }
  #pragma unroll
  for (int t=0;t<8;t++){
    #pragma unroll
    for (int r=0;r<4;r++){
      int col = t*16+lr;
      int row = m0 + lg*4 + r;
      int n = nb + row;
      if (n < NN){
        float v = acc[t][r]/sden[row];
        if (y==0){
          v += res_s[(size_t)n*256 + col];
          scal16[(size_t)n*128 + col] = f2bh(silu_f(v));
        } else if (y==1){
          v += res_s[(size_t)n*256 + 128 + col];
          gate16[(size_t)n*128 + col] = f2bh(sigmoid_f(v));
        } else {
          int i = y-2;
          v += res_v[((size_t)n*3+i)*128 + col];
          vtmp16[((size_t)i*NN + n)*128 + col] = f2bh(v);
        }
      }
    }
  }
}

// ---------------- K4b: lin2 for 4 output components. grid (NB64, 4) ----------------
__global__ __launch_bounds__(256) void k_post2(
    const unsigned short* __restrict__ scal16, const unsigned short* __restrict__ gate16,
    const unsigned short* __restrict__ vtmp16,
    const unsigned short* __restrict__ Wl20T, const unsigned short* __restrict__ Wl21T,
    float* __restrict__ out_msg){
  __shared__ unsigned short sA[64][136];
  int nb = blockIdx.x*64, y = blockIdx.y;
  int tid = threadIdx.x;
  int w = tid>>6, l = tid&63, m0 = w*16, lr = l&15, lg = l>>4;
  for (int idx=tid; idx<64*16; idx+=256){
    int row = idx>>4, s8 = idx&15;
    int n = min(nb+row, NN-1);
    if (y==0){
      *(uint4*)&sA[row][s8*8] = *(const uint4*)&scal16[(size_t)n*128 + s8*8];
    } else {
      int i = y-1;
      uint4 va = *(const uint4*)&vtmp16[((size_t)i*NN + n)*128 + s8*8];
      uint4 vg = *(const uint4*)&gate16[(size_t)n*128 + s8*8];
      const unsigned short* pa = (const unsigned short*)&va;
      const unsigned short* pg = (const unsigned short*)&vg;
      unsigned short o[8];
      #pragma unroll
      for (int j=0;j<8;j++) o[j] = f2bh(b2f(pa[j])*b2f(pg[j]));
      *(uint4*)&sA[row][s8*8] = *(const uint4*)o;
    }
  }
  __syncthreads();
  const unsigned short* BT = (y==0)? Wl20T : Wl21T;
  f32x4 acc[8];
  #pragma unroll
  for (int t=0;t<8;t++) acc[t]=(f32x4)(0.f);
  #pragma unroll
  for (int kb=0;kb<4;kb++){
    bf16x8 a = *(const bf16x8*)&sA[m0+lr][kb*32 + lg*8];
    #pragma unroll
    for (int t=0;t<8;t++){
      bf16x8 b = *(const bf16x8*)&BT[(size_t)(t*16+lr)*128 + kb*32 + lg*8];
      acc[t] = __builtin_amdgcn_mfma_f32_16x16x32_bf16(a, b, acc[t], 0,0,0);
    }
  }
  #pragma unroll
  for (int t=0;t<8;t++){
    #pragma unroll
    for (int r=0;r<4;r++){
      int col = t*16+lr;
      int n = nb + m0 + lg*4 + r;
      if (n < NN) out_msg[(size_t)n*512 + col*4 + y] = acc[t][r];
    }
  }
}

extern "C" void kernel_launch(void* const* d_in, const int* in_sizes, int n_in,
                              void* d_out, int out_size, void* d_ws, size_t ws_size,
                              hipStream_t stream){
  (void)in_sizes; (void)n_in; (void)out_size; (void)ws_size;
  const float* attrs = (const float*)d_in[0];
  const float* feats = (const float*)d_in[1];
  const float* ea    = (const float*)d_in[2];
  const float* ef    = (const float*)d_in[3];
  const float* Wsrc  = (const float*)d_in[4];
  const float* Wtgt  = (const float*)d_in[5];
  const float* Wup0  = (const float*)d_in[6];
  const float* Wup1  = (const float*)d_in[7];
  const float* Wsk0  = (const float*)d_in[8];
  const float* Wsk1  = (const float*)d_in[9];
  const float* Wres0 = (const float*)d_in[10];
  const float* Wres1 = (const float*)d_in[11];
  const float* Wl10  = (const float*)d_in[12];
  const float* Wl11  = (const float*)d_in[13];
  const float* Wl20  = (const float*)d_in[14];
  const float* Wl21  = (const float*)d_in[15];
  const float* Wr1   = (const float*)d_in[16];
  const float* Wr2   = (const float*)d_in[17];
  const float* Wr3   = (const float*)d_in[18];
  const float* Wr4   = (const float*)d_in[19];
  const float* Wd1   = (const float*)d_in[20];
  const float* Wd2   = (const float*)d_in[21];
  const float* alphap= (const float*)d_in[22];
  const float* betap = (const float*)d_in[23];
  const int*   eidx  = (const int*)d_in[24];

  char* p = (char*)d_ws;
  auto alloc = [&](size_t bytes)->char*{ char* r=p; p += (bytes+255)&~(size_t)255; return r; };
  // msg_s, msg_v, density contiguous -> single memset
  float*  msg_s32 = (float*)alloc((size_t)NN*256*4);
  float*  msg_v32 = (float*)alloc((size_t)NN*768*4);
  float*  density = (float*)alloc((size_t)NN*4);
  float*  pbufH   = (float*)alloc((size_t)NWIN*1024*4);
  float*  pbufT   = (float*)alloc((size_t)NWIN*1024*4);
  float*  pbufHd  = (float*)alloc((size_t)NWIN*4);
  float*  pbufTd  = (float*)alloc((size_t)NWIN*4);
  float*  res_s   = (float*)alloc((size_t)NN*256*4);
  float*  res_v   = (float*)alloc((size_t)NN*384*4);
  float4* ybuf    = (float4*)alloc((size_t)NE*16);
  int*    sndbuf  = (int*)alloc((size_t)NE*4);
  int*    rcvbuf  = (int*)alloc((size_t)NE*4);
  float*  efb     = (float*)alloc((size_t)NE*32);
  uint4*  upk     = (uint4*)alloc((size_t)NN*64*16);
  unsigned short* fs16 = (unsigned short*)alloc((size_t)NN*128*2);
  unsigned short* fv16 = (unsigned short*)alloc((size_t)NN*384*2);
  float* pA = (float*)alloc((size_t)NN*128*4);
  float* pB = (float*)alloc((size_t)NN*128*4);
  float* Wc  = (float*)alloc(4*ADIM*64*4);
  unsigned short* gate16 = (unsigned short*)alloc((size_t)NN*128*2);
  unsigned short* WTr2 = (unsigned short*)alloc(4096*2);
  unsigned short* WTr3 = (unsigned short*)alloc(4096*2);
  unsigned short* WTr4 = (unsigned short*)alloc(32768*2);
  unsigned short* Wl10T = (unsigned short*)alloc(65536*2);
  unsigned short* Wl11T = (unsigned short*)alloc(32768*2);
  unsigned short* Wl20T = (unsigned short*)alloc(16384*2);
  unsigned short* Wl21T = (unsigned short*)alloc(16384*2);
  unsigned short* WnsT  = (unsigned short*)alloc(65536*2);
  unsigned short* WnvT  = (unsigned short*)alloc(49152*2);
  int* deg     = (int*)alloc(10240*4);
  int* cursor  = (int*)alloc(10240*4);
  int* offsets = (int*)alloc(10256*4);

  unsigned short* scal16 = fs16;   // NN*128, fs16 dead after k_node_pre2
  unsigned short* vtmp16 = fv16;   // 3*NN*128, fv16 dead after k_node_pre2

  float* out_msg = (float*)d_out;               // NN*512
  float* out_sc  = out_msg + (size_t)NN*512;    // NN*512

  hipMemsetAsync(msg_s32, 0, (size_t)NN*(256+768+1)*4, stream);
  hipMemsetAsync(deg, 0, 2*10240*sizeof(int), stream);

  k_prep<<<1121, 256, 0, stream>>>(Wr2, Wr3, Wr4, Wl10, Wl11, Wl20, Wl21,
                                   Wsk0, Wup0, Wres0, Wsk1, Wup1, Wres1,
                                   Wsrc, Wtgt, Wr1, Wd1,
                                   WTr2, WTr3, WTr4,
                                   Wl10T, Wl11T, Wl20T, Wl21T, WnsT, WnvT, Wc);
  k_nodeemb<<<(NN*64+255)/256, 256, 0, stream>>>(attrs, Wc, pA, pB);
  k_feat_prep<<<NN*512/256, 256, 0, stream>>>(feats, fs16, fv16);
  k_node_pre2<<<dim3(NB64,13), 256, 0, stream>>>(fs16, fv16, WnsT, WnvT,
                                                 out_sc, (unsigned short*)upk, res_s, res_v);
  k_deg<<<(NE+255)/256, 256, 0, stream>>>(eidx, deg);
  k_scan<<<1, 256, 0, stream>>>(deg, offsets);
  k_fill<<<(NE+255)/256, 256, 0, stream>>>(eidx, ef, ea, offsets, cursor,
                                           sndbuf, rcvbuf, ybuf, efb);

  k_edge<<<NE/64, 256, 0, stream>>>(sndbuf, rcvbuf, efb, ybuf, pA, pB,
                                    Wr1, Wd1, Wd2, WTr2, WTr3, WTr4,
                                    offsets, upk,
                                    msg_s32, msg_v32, density,
                                    pbufH, pbufT, pbufHd, pbufTd);
  k_fixup<<<(NN+3)/4, 256, 0, stream>>>(offsets, pbufH, pbufT, pbufHd, pbufTd,
                                        msg_s32, msg_v32, density);

  k_post1<<<dim3(NB64,5), 256, 0, stream>>>(msg_s32, msg_v32, density, res_s, res_v,
                                            Wl10T, Wl11T, alphap, betap,
                                            scal16, gate16, vtmp16);
  k_post2<<<dim3(NB64,4), 256, 0, stream>>>(scal16, gate16, vtmp16,
                                            Wl20T, Wl21T, out_msg);
}

// Round 12
// 439.997 us; speedup vs baseline: 1.0594x; 1.0594x over previous
//
#include <hip/hip_runtime.h>
#include <hip/hip_bf16.h>
#include <math.h>

#define NN 10000
#define NE 160000
#define MUL 128
#define ADIM 10
#define RADF 8
#define HID 64
#define INV_SQRT3 0.57735026918962576f
#define NB64 157           // ceil(NN/64)

typedef __attribute__((ext_vector_type(8))) short bf16x8;
typedef __attribute__((ext_vector_type(4))) float f32x4;

__device__ __forceinline__ float silu_f(float x){ return x / (1.0f + __expf(-x)); }
__device__ __forceinline__ float sigmoid_f(float x){ return 1.0f / (1.0f + __expf(-x)); }
// legacy manual RNE (cold prep kernels)
__device__ __forceinline__ unsigned short f2b(float f){
  union{float f; unsigned u;} v; v.f=f;
  unsigned r = (v.u + 0x7fffu + ((v.u>>16)&1u))>>16;
  return (unsigned short)r;
}
// hot-path: native HW converts
__device__ __forceinline__ unsigned short f2bh(float f){
  __hip_bfloat16 h = __float2bfloat16(f);
  union{ __hip_bfloat16 h; unsigned short u; } v; v.h=h; return v.u;
}
__device__ __forceinline__ unsigned f2b2(float lo, float hi){
  float2 t; t.x=lo; t.y=hi;
  __hip_bfloat162 h2 = __float22bfloat162_rn(t);
  union{ __hip_bfloat162 h; unsigned u; } v; v.h=h2; return v.u;
}
__device__ __forceinline__ float b2f(unsigned short h){
  union{unsigned u; float f;} v; v.u = ((unsigned)h)<<16; return v.f;
}
__device__ __forceinline__ float b2f_lo(unsigned u){
  union{unsigned u; float f;} v; v.u = u<<16; return v.f;
}
__device__ __forceinline__ float b2f_hi(unsigned u){
  union{unsigned u; float f;} v; v.u = u & 0xffff0000u; return v.f;
}

// ---------------- per-node layer1 partials, packed {rad, den} float2 ----------------
__global__ __launch_bounds__(256) void k_nodeemb(
    const float* __restrict__ attrs, const float* __restrict__ Wc,
    float* __restrict__ pA, float* __restrict__ pB){
  int idx = blockIdx.x*256 + threadIdx.x;
  if (idx >= NN*64) return;
  int n = idx>>6, c = idx&63;
  float s0=0,s1=0,s2=0,s3=0;
  #pragma unroll
  for (int a=0;a<ADIM;a++){
    float x = attrs[n*ADIM+a];
    s0 += x*Wc[(0*ADIM+a)*64+c];
    s1 += x*Wc[(1*ADIM+a)*64+c];
    s2 += x*Wc[(2*ADIM+a)*64+c];
    s3 += x*Wc[(3*ADIM+a)*64+c];
  }
  pA[(size_t)n*128 + c*2 + 0] = s0;
  pA[(size_t)n*128 + c*2 + 1] = s2;
  pB[(size_t)n*128 + c*2 + 0] = s1;
  pB[(size_t)n*128 + c*2 + 1] = s3;
}

// ---------------- feat prep ----------------
__global__ __launch_bounds__(256) void k_feat_prep(
    const float* __restrict__ feats, unsigned short* __restrict__ fs16,
    unsigned short* __restrict__ fv16){
  int idx = blockIdx.x*256 + threadIdx.x;
  int n = idx >> 9, c = idx & 511;
  float v = feats[idx];
  if (c < 128) fs16[n*128 + c] = f2bh(v);
  else {
    int q = c - 128; int u = q/3; int i = q - 3*u;
    fv16[((size_t)n*3 + i)*128 + u] = f2bh(v);
  }
}

// ---------------- weight prep: transpose + bf16 cast (+ wcomb merged) ----------------
__global__ __launch_bounds__(256) void k_prep(
    const float* __restrict__ Wr2, const float* __restrict__ Wr3,
    const float* __restrict__ Wr4,
    const float* __restrict__ Wl10, const float* __restrict__ Wl11,
    const float* __restrict__ Wl20, const float* __restrict__ Wl21,
    const float* __restrict__ Wsk0, const float* __restrict__ Wup0, const float* __restrict__ Wres0,
    const float* __restrict__ Wsk1, const float* __restrict__ Wup1, const float* __restrict__ Wres1,
    const float* __restrict__ Wsrc, const float* __restrict__ Wtgt,
    const float* __restrict__ Wr1, const float* __restrict__ Wd1,
    unsigned short* __restrict__ WTr2, unsigned short* __restrict__ WTr3,
    unsigned short* __restrict__ WTr4,
    unsigned short* __restrict__ Wl10T, unsigned short* __restrict__ Wl11T,
    unsigned short* __restrict__ Wl20T, unsigned short* __restrict__ Wl21T,
    unsigned short* __restrict__ WnsT, unsigned short* __restrict__ WnvT,
    float* __restrict__ Wc){
  int idx = blockIdx.x*256 + threadIdx.x;
  if (idx < 4096){
    int j = idx; int n=j>>6, k=j&63;
    WTr2[j] = f2b(Wr2[k*64+n]);
  } else if (idx < 8192){
    int j = idx-4096; int n=j>>6, k=j&63;
    WTr3[j] = f2b(Wr3[k*64+n]);
  } else if (idx < 40960){
    int j = idx-8192; int n=j>>6, k=j&63;
    WTr4[j] = f2b(Wr4[k*512+n]);
  } else if (idx < 106496){
    int j = idx-40960; int n=j>>8, k=j&255;
    Wl10T[j] = f2b(Wl10[k*256+n]);
  } else if (idx < 139264){
    int j = idx-106496; int n=j>>8, k=j&255;
    Wl11T[j] = f2b(Wl11[k*128+n]);
  } else if (idx < 155648){
    int j = idx-139264; int n=j>>7, k=j&127;
    Wl20T[j] = f2b(Wl20[k*128+n]);
  } else if (idx < 172032){
    int j = idx-155648; int n=j>>7, k=j&127;
    Wl21T[j] = f2b(Wl21[k*128+n]);
  } else if (idx < 237568){
    int j = idx-172032; int n=j>>7, k=j&127;
    float v;
    if (n < 128)      v = Wsk0[k*128+n];
    else if (n < 256) v = Wup0[k*128+(n-128)];
    else              v = Wres0[k*256+(n-256)];
    WnsT[j] = f2b(v);
  } else if (idx < 286720){
    int j = idx-237568; int n=j>>7, k=j&127;
    float v;
    if (n < 128)      v = Wsk1[k*128+n];
    else if (n < 256) v = Wup1[k*128+(n-128)];
    else              v = Wres1[k*128+(n-256)];
    WnvT[j] = f2b(v);
  } else if (idx < 286976){
    int j = idx - 286720;      // wcomb: Wc[m][10][64]
    int m = j>>6, c = j&63;
    const float* WA = (m&1)? Wtgt : Wsrc;
    const float* WB = (m<2)? Wr1 : Wd1;
    int koff = (m&1)? 136 : 8;
    for (int a=0;a<ADIM;a++){
      float s=0.f;
      for (int k=0;k<128;k++) s += WA[a*128+k]*WB[(koff+k)*64+c];
      Wc[(m*ADIM+a)*64+c] = s;
    }
  }
}

// ---------------- K1: per-node precompute via MFMA ----------------
__global__ __launch_bounds__(256) void k_node_pre2(
    const unsigned short* __restrict__ fs16, const unsigned short* __restrict__ fv16,
    const unsigned short* __restrict__ WnsT, const unsigned short* __restrict__ WnvT,
    float* __restrict__ out_sc,
    unsigned short* __restrict__ upk16,
    float* __restrict__ res_s, float* __restrict__ res_v){
  __shared__ unsigned short fA[64][136];
  int nb = blockIdx.x*64;
  int c = blockIdx.y;
  int g, ntc;
  if (c < 4){ g=0; ntc=c; } else { g = 1 + (c-4)/3; ntc = (c-4)%3; }
  int tid = threadIdx.x;
  int w = tid>>6, l = tid&63, m0 = w*16, lr = l&15, lg = l>>4;
  for (int idx=tid; idx<64*16; idx+=256){
    int row = idx>>4, s8 = idx&15;
    int n = min(nb+row, NN-1);
    const unsigned short* src = (g==0) ? &fs16[(size_t)n*128 + s8*8]
                                       : &fv16[((size_t)n*3 + (g-1))*128 + s8*8];
    *(uint4*)&fA[row][s8*8] = *(const uint4*)src;
  }
  __syncthreads();
  const unsigned short* WT = ((g==0)? WnsT : WnvT) + (size_t)ntc*128*128;
  f32x4 acc[8];
  #pragma unroll
  for (int t=0;t<8;t++) acc[t]=(f32x4)(0.f);
  #pragma unroll
  for (int kb=0;kb<4;kb++){
    bf16x8 a = *(const bf16x8*)&fA[m0+lr][kb*32 + lg*8];
    #pragma unroll
    for (int t=0;t<8;t++){
      bf16x8 b = *(const bf16x8*)&WT[(size_t)(t*16+lr)*128 + kb*32 + lg*8];
      acc[t] = __builtin_amdgcn_mfma_f32_16x16x32_bf16(a, b, acc[t], 0,0,0);
    }
  }
  #pragma unroll
  for (int t=0;t<8;t++){
    #pragma unroll
    for (int r=0;r<4;r++){
      int col = (ntc*8+t)*16 + lr;
      int row = m0 + lg*4 + r;
      int n = nb + row;
      if (n < NN){
        float v = acc[t][r];
        if (g==0){
          if (col < 128)      out_sc[(size_t)n*512 + col] = v;
          else if (col < 256){
            int cc = col-128;
            upk16[(size_t)n*512 + (cc&63)*8 + (cc>>6)] = f2bh(v);
          } else              res_s[(size_t)n*256 + col-256] = v;
        } else {
          int i = g-1;
          if (col < 128)      out_sc[(size_t)n*512 + 128 + col*3 + i] = v;
          else if (col < 256){
            int cc = col-128;
            upk16[(size_t)n*512 + (cc&63)*8 + (1+i)*2 + (cc>>6)] = f2bh(v);
          } else              res_v[((size_t)n*3+i)*128 + col-256] = v;
        }
      }
    }
  }
}

// ---------------- CSR build ----------------
__global__ __launch_bounds__(256) void k_deg(const int* __restrict__ eidx, int* __restrict__ deg){
  int i = blockIdx.x*256+threadIdx.x;
  if (i<NE) atomicAdd(&deg[eidx[2*i+1]],1);
}
__global__ __launch_bounds__(256) void k_scan(const int* __restrict__ deg, int* __restrict__ offsets){
  __shared__ int part[256];
  int t = threadIdx.x; int base = t*40;
  int s=0;
  for (int k=0;k<40;k++){ int idx=base+k; if (idx<NN) s+=deg[idx]; }
  part[t]=s; __syncthreads();
  if (t==0){ int run=0; for (int i=0;i<256;i++){ int v=part[i]; part[i]=run; run+=v; } }
  __syncthreads();
  int run = part[t];
  for (int k=0;k<40;k++){
    int idx=base+k;
    if (idx<=NN) offsets[idx]=run;
    if (idx<NN) run+=deg[idx];
  }
}
// fill: materialize CSR-ordered edge data
__global__ __launch_bounds__(256) void k_fill(
    const int* __restrict__ eidx, const float* __restrict__ ef, const float* __restrict__ ea,
    const int* __restrict__ offsets, int* __restrict__ cursor,
    int* __restrict__ sndbuf, int* __restrict__ rcvbuf,
    float4* __restrict__ ybuf, float* __restrict__ efb){
  int i = blockIdx.x*256+threadIdx.x;
  if (i<NE){
    int sn = eidx[2*i], rc = eidx[2*i+1];
    int p = offsets[rc] + atomicAdd(&cursor[rc],1);
    sndbuf[p]=sn; rcvbuf[p]=rc;
    ybuf[p] = ((const float4*)ea)[i];
    *(float4*)&efb[(size_t)p*8]     = *(const float4*)&ef[(size_t)i*8];
    *(float4*)&efb[(size_t)p*8 + 4] = *(const float4*)&ef[(size_t)i*8 + 4];
  }
}

// ---------------- K2: edge MLP, barrier-free, reg-staged metadata ----------------
__global__ __launch_bounds__(256) void k_tpw(
    const int* __restrict__ sndbuf, const int* __restrict__ rcvbuf,
    const float* __restrict__ efb,
    const float* __restrict__ pA, const float* __restrict__ pB,
    const float* __restrict__ Wr1, const float* __restrict__ Wd1, const float* __restrict__ Wd2,
    const unsigned short* __restrict__ WTr2, const unsigned short* __restrict__ WTr3,
    const unsigned short* __restrict__ WTr4,
    const int* __restrict__ offsets, int nstart, int nend, int cap,
    unsigned* __restrict__ tpwp, float* __restrict__ densbuf){
  __shared__ unsigned short hA[64][72];
  __shared__ unsigned short hB[64][72];
  int ebase = offsets[nstart];
  int eend  = min(offsets[nend], ebase + cap);
  int i0 = ebase + blockIdx.x*64;
  if (i0 >= eend) return;
  int nrows = min(64, eend - i0);
  int tid = threadIdx.x;
  int w = tid>>6, l = tid&63, m0 = w*16, lr = l&15, lg = l>>4;
  int wbase = i0 + m0;
  int v_meta = 0;
  {
    int pos = min(wbase + (l&15), eend-1);
    if (l < 16)      v_meta = sndbuf[pos];
    else if (l < 32) v_meta = rcvbuf[pos];
  }
  float ra, rb;
  {
    int pos = min(wbase + (l&15), eend-1);
    ra = efb[(size_t)pos*8 + (l>>4)];
    rb = efb[(size_t)pos*8 + 4 + (l>>4)];
  }
  // ---- layer1 (VALU, f32) ----
  {
    float wr[8], wd[8];
    #pragma unroll
    for (int k=0;k<8;k++){ wr[k]=Wr1[k*64+l]; wd[k]=Wd1[k*64+l]; }
    float wd2c = Wd2[l];
    #pragma unroll
    for (int j=0;j<16;j++){
      int sn = __shfl(v_meta, j);
      int rc = __shfl(v_meta, 16+j);
      float2 av = *(const float2*)&pA[(size_t)sn*128 + l*2];
      float2 bv = *(const float2*)&pB[(size_t)rc*128 + l*2];
      float e0=__shfl(ra,j),    e1=__shfl(ra,16+j), e2=__shfl(ra,32+j), e3=__shfl(ra,48+j);
      float e4=__shfl(rb,j),    e5=__shfl(rb,16+j), e6=__shfl(rb,32+j), e7=__shfl(rb,48+j);
      float h  = av.x + bv.x;
      float hd = av.y + bv.y;
      h  += e0*wr[0]+e1*wr[1]+e2*wr[2]+e3*wr[3]+e4*wr[4]+e5*wr[5]+e6*wr[6]+e7*wr[7];
      hd += e0*wd[0]+e1*wd[1]+e2*wd[2]+e3*wd[3]+e4*wd[4]+e5*wd[5]+e6*wd[6]+e7*wd[7];
      hA[m0+j][l] = f2bh(silu_f(h));
      float sv = silu_f(hd)*wd2c;
      #pragma unroll
      for (int m=32;m;m>>=1) sv += __shfl_xor(sv, m);
      if (l==0 && m0+j < nrows) densbuf[wbase + j] = tanhf(sv*sv);
    }
  }
  // ---- layer2: hA -> hB (wave-private rows, no barrier) ----
  f32x4 acc[4];
  #pragma unroll
  for (int nt=0;nt<4;nt++) acc[nt]=(f32x4)(0.f);
  #pragma unroll
  for (int kb=0;kb<2;kb++){
    bf16x8 a = *(const bf16x8*)&hA[m0+lr][kb*32 + lg*8];
    #pragma unroll
    for (int nt=0;nt<4;nt++){
      bf16x8 b = *(const bf16x8*)&WTr2[(nt*16+lr)*64 + kb*32 + lg*8];
      acc[nt] = __builtin_amdgcn_mfma_f32_16x16x32_bf16(a, b, acc[nt], 0,0,0);
    }
  }
  #pragma unroll
  for (int nt=0;nt<4;nt++)
    #pragma unroll
    for (int r=0;r<4;r++)
      hB[m0+lg*4+r][nt*16+lr] = f2bh(silu_f(acc[nt][r]));
  // ---- layer3: hB -> hA ----
  #pragma unroll
  for (int nt=0;nt<4;nt++) acc[nt]=(f32x4)(0.f);
  #pragma unroll
  for (int kb=0;kb<2;kb++){
    bf16x8 a = *(const bf16x8*)&hB[m0+lr][kb*32 + lg*8];
    #pragma unroll
    for (int nt=0;nt<4;nt++){
      bf16x8 b = *(const bf16x8*)&WTr3[(nt*16+lr)*64 + kb*32 + lg*8];
      acc[nt] = __builtin_amdgcn_mfma_f32_16x16x32_bf16(a, b, acc[nt], 0,0,0);
    }
  }
  #pragma unroll
  for (int nt=0;nt<4;nt++)
    #pragma unroll
    for (int r=0;r<4;r++)
      hA[m0+lg*4+r][nt*16+lr] = f2bh(silu_f(acc[nt][r]));
  // ---- layer4: direct reg->global, [edge][lane c][G] packed u32, 16B stores ----
  int erow0 = i0 - ebase;
  #pragma unroll
  for (int nt=0; nt<4; nt++){
    unsigned pvv[4][4];   // [r][G]
    #pragma unroll
    for (int G=0; G<4; G++){
      f32x4 aE=(f32x4)(0.f), aO=(f32x4)(0.f);
      #pragma unroll
      for (int kb=0; kb<2; kb++){
        bf16x8 a  = *(const bf16x8*)&hA[m0+lr][kb*32 + lg*8];
        bf16x8 bE = *(const bf16x8*)&WTr4[((2*G)*64+nt*16+lr)*64 + kb*32 + lg*8];
        bf16x8 bO = *(const bf16x8*)&WTr4[((2*G+1)*64+nt*16+lr)*64 + kb*32 + lg*8];
        aE = __builtin_amdgcn_mfma_f32_16x16x32_bf16(a, bE, aE, 0,0,0);
        aO = __builtin_amdgcn_mfma_f32_16x16x32_bf16(a, bO, aO, 0,0,0);
      }
      #pragma unroll
      for (int r=0;r<4;r++)
        pvv[r][G] = f2b2(aE[r], aO[r]);
    }
    #pragma unroll
    for (int r=0;r<4;r++){
      int row = m0 + lg*4 + r;
      if (row < nrows)
        *(uint4*)&tpwp[(size_t)(erow0+row)*256 + (nt*16+lr)*4] = *(uint4*)&pvv[r][0];
    }
  }
}

// ---------------- K3: CSR gather — 4 waves per node (1 block/node), LDS combine ------
__global__ __launch_bounds__(256) void k_gather(
    const unsigned* __restrict__ tpwp, const float4* __restrict__ ybuf,
    const int* __restrict__ sndbuf, const float* __restrict__ densbuf,
    const uint4* __restrict__ upk4,
    const int* __restrict__ offsets, int nstart,
    unsigned short* __restrict__ msg_s16, unsigned short* __restrict__ msg_v16,
    float* __restrict__ density){
  __shared__ float part[3][1024];
  __shared__ float pden[3];
  int w = threadIdx.x>>6, l = threadIdx.x&63;
  int n = nstart + blockIdx.x;
  int ebase = offsets[nstart];
  int s0 = offsets[n], s1 = offsets[n+1];
  float mA0=0,mA1=0,mD0=0,mD1=0;
  float mB00=0,mB01=0,mB10=0,mB11=0,mB20=0,mB21=0;
  float mC00=0,mC01=0,mC10=0,mC11=0,mC20=0,mC21=0;
  float dsum=0;
  #pragma unroll 2
  for (int i=s0+w; i<s1; i+=4){
    int li = i - ebase;
    int sn = sndbuf[i];
    float4 y = ybuf[i];
    dsum += densbuf[i];
    uint4 tq = *(const uint4*)&tpwp[(size_t)li*256 + l*4];
    uint4 uq = upk4[(size_t)sn*64 + l];
    float wA0=b2f_lo(tq.x), wA1=b2f_hi(tq.x);
    float wB0=b2f_lo(tq.y), wB1=b2f_hi(tq.y);
    float wC0=b2f_lo(tq.z), wC1=b2f_hi(tq.z);
    float wD0=b2f_lo(tq.w), wD1=b2f_hi(tq.w);
    float xs0=b2f_lo(uq.x), xs1=b2f_hi(uq.x);
    float xv00=b2f_lo(uq.y), xv01=b2f_hi(uq.y);
    float xv10=b2f_lo(uq.z), xv11=b2f_hi(uq.z);
    float xv20=b2f_lo(uq.w), xv21=b2f_hi(uq.w);
    mA0 += wA0*xs0*y.x; mA1 += wA1*xs1*y.x;
    float dot0 = xv00*y.y + xv10*y.z + xv20*y.w;
    float dot1 = xv01*y.y + xv11*y.z + xv21*y.w;
    mD0 += wD0*dot0; mD1 += wD1*dot1;
    float b0 = wB0*xs0, b1 = wB1*xs1;
    mB00 += b0*y.y; mB01 += b1*y.y;
    mB10 += b0*y.z; mB11 += b1*y.z;
    mB20 += b0*y.w; mB21 += b1*y.w;
    float c0 = wC0*y.x, c1 = wC1*y.x;
    mC00 += c0*xv00; mC01 += c1*xv01;
    mC10 += c0*xv10; mC11 += c1*xv11;
    mC20 += c0*xv20; mC21 += c1*xv21;
  }
  if (w){
    float* P = part[w-1];
    P[0*64+l]=mA0;  P[1*64+l]=mA1;  P[2*64+l]=mD0;  P[3*64+l]=mD1;
    P[4*64+l]=mB00; P[5*64+l]=mB01; P[6*64+l]=mB10; P[7*64+l]=mB11;
    P[8*64+l]=mB20; P[9*64+l]=mB21; P[10*64+l]=mC00; P[11*64+l]=mC01;
    P[12*64+l]=mC10; P[13*64+l]=mC11; P[14*64+l]=mC20; P[15*64+l]=mC21;
    if (l==0) pden[w-1]=dsum;
  }
  __syncthreads();
  if (w==0){
    #pragma unroll
    for (int q=0;q<3;q++){
      const float* P = part[q];
      mA0+=P[0*64+l];  mA1+=P[1*64+l];  mD0+=P[2*64+l];  mD1+=P[3*64+l];
      mB00+=P[4*64+l]; mB01+=P[5*64+l]; mB10+=P[6*64+l]; mB11+=P[7*64+l];
      mB20+=P[8*64+l]; mB21+=P[9*64+l]; mC00+=P[10*64+l]; mC01+=P[11*64+l];
      mC10+=P[12*64+l]; mC11+=P[13*64+l]; mC20+=P[14*64+l]; mC21+=P[15*64+l];
    }
    dsum += pden[0]+pden[1]+pden[2];
    unsigned short* ms = msg_s16 + (size_t)n*256;
    ms[l]=f2bh(mA0); ms[64+l]=f2bh(mA1);
    ms[128+l]=f2bh(mD0*INV_SQRT3); ms[192+l]=f2bh(mD1*INV_SQRT3);
    unsigned short* mv = msg_v16 + (size_t)n*768;
    mv[l]=f2bh(mB00);     mv[64+l]=f2bh(mB01);  mv[128+l]=f2bh(mC00); mv[192+l]=f2bh(mC01);
    mv[256+l]=f2bh(mB10); mv[320+l]=f2bh(mB11); mv[384+l]=f2bh(mC10); mv[448+l]=f2bh(mC11);
    mv[512+l]=f2bh(mB20); mv[576+l]=f2bh(mB21); mv[640+l]=f2bh(mC20); mv[704+l]=f2bh(mC21);
    if (l==0) density[n]=dsum;
  }
}

// ---------------- K4a: lin1 for all 5 N=128 chunks. grid (NB64, 5) ----------------
__global__ __launch_bounds__(256) void k_post1(
    const unsigned short* __restrict__ msg_s16, const unsigned short* __restrict__ msg_v16,
    const float* __restrict__ density,
    const float* __restrict__ res_s, const float* __restrict__ res_v,
    const unsigned short* __restrict__ Wl10T, const unsigned short* __restrict__ Wl11T,
    const float* __restrict__ alphap, const float* __restrict__ betap,
    unsigned short* __restrict__ scal16, unsigned short* __restrict__ gate16,
    unsigned short* __restrict__ vtmp16){
  __shared__ unsigned short sm[64][264];
  __shared__ float sden[64];
  int nb = blockIdx.x*64, y = blockIdx.y;
  int tid = threadIdx.x;
  int w = tid>>6, l = tid&63, m0 = w*16, lr = l&15, lg = l>>4;
  for (int idx=tid; idx<64*32; idx+=256){
    int row = idx>>5, s8 = idx&31;
    int n = min(nb+row, NN-1);
    const unsigned short* src = (y<2)? &msg_s16[(size_t)n*256 + s8*8]
                                     : &msg_v16[(size_t)n*768 + (y-2)*256 + s8*8];
    *(uint4*)&sm[row][s8*8] = *(const uint4*)src;
  }
  if (tid < 64){
    int n = min(nb+tid, NN-1);
    sden[tid] = density[n]*betap[0] + alphap[0]*20.0f;
  }
  __syncthreads();
  const unsigned short* BT = (y<2)? (Wl10T + (size_t)y*128*256) : Wl11T;
  f32x4 acc[8];
  #pragma unroll
  for (int t=0;t<8;t++) acc[t]=(f32x4)(0.f);
  for (int kb=0;kb<8;kb++){
    bf16x8 a = *(const bf16x8*)&sm[m0+lr][kb*32 + lg*8];
    #pragma unroll
    for (int t=0;t<8;t++){
      bf16x8 b = *(const bf16x8*)&BT[(size_t)(t*16+lr)*256 + kb*32 + lg*8];
      acc[t] = __builtin_amdgcn_mfma_f32_16x16x32_bf16(a, b, acc[t], 0,0,0);
    }
  }
  #pragma unroll
  for (int t=0;t<8;t++){
    #pragma unroll
    for (int r=0;r<4;r++){
      int col = t*16+lr;
      int row = m0 + lg*4 + r;
      int n = nb + row;
      if (n < NN){
        float v = acc[t][r]/sden[row];
        if (y==0){
          v += res_s[(size_t)n*256 + col];
          scal16[(size_t)n*128 + col] = f2bh(silu_f(v));
        } else if (y==1){
          v += res_s[(size_t)n*256 + 128 + col];
          gate16[(size_t)n*128 + col] = f2bh(sigmoid_f(v));
        } else {
          int i = y-2;
          v += res_v[((size_t)n*3+i)*128 + col];
          vtmp16[((size_t)i*NN + n)*128 + col] = f2bh(v);
        }
      }
    }
  }
}

// ---------------- K4b: lin2 for 4 output components. grid (NB64, 4) ----------------
__global__ __launch_bounds__(256) void k_post2(
    const unsigned short* __restrict__ scal16, const unsigned short* __restrict__ gate16,
    const unsigned short* __restrict__ vtmp16,
    const unsigned short* __restrict__ Wl20T, const unsigned short* __restrict__ Wl21T,
    float* __restrict__ out_msg){
  __shared__ unsigned short sA[64][136];
  int nb = blockIdx.x*64, y = blockIdx.y;
  int tid = threadIdx.x;
  int w = tid>>6, l = tid&63, m0 = w*16, lr = l&15, lg = l>>4;
  for (int idx=tid; idx<64*16; idx+=256){
    int row = idx>>4, s8 = idx&15;
    int n = min(nb+row, NN-1);
    if (y==0){
      *(uint4*)&sA[row][s8*8] = *(const uint4*)&scal16[(size_t)n*128 + s8*8];
    } else {
      int i = y-1;
      uint4 va = *(const uint4*)&vtmp16[((size_t)i*NN + n)*128 + s8*8];
      uint4 vg = *(const uint4*)&gate16[(size_t)n*128 + s8*8];
      const unsigned short* pa = (const unsigned short*)&va;
      const unsigned short* pg = (const unsigned short*)&vg;
      unsigned short o[8];
      #pragma unroll
      for (int j=0;j<8;j++) o[j] = f2bh(b2f(pa[j])*b2f(pg[j]));
      *(uint4*)&sA[row][s8*8] = *(const uint4*)o;
    }
  }
  __syncthreads();
  const unsigned short* BT = (y==0)? Wl20T : Wl21T;
  f32x4 acc[8];
  #pragma unroll
  for (int t=0;t<8;t++) acc[t]=(f32x4)(0.f);
  #pragma unroll
  for (int kb=0;kb<4;kb++){
    bf16x8 a = *(const bf16x8*)&sA[m0+lr][kb*32 + lg*8];
    #pragma unroll
    for (int t=0;t<8;t++){
      bf16x8 b = *(const bf16x8*)&BT[(size_t)(t*16+lr)*128 + kb*32 + lg*8];
      acc[t] = __builtin_amdgcn_mfma_f32_16x16x32_bf16(a, b, acc[t], 0,0,0);
    }
  }
  #pragma unroll
  for (int t=0;t<8;t++){
    #pragma unroll
    for (int r=0;r<4;r++){
      int col = t*16+lr;
      int n = nb + m0 + lg*4 + r;
      if (n < NN) out_msg[(size_t)n*512 + col*4 + y] = acc[t][r];
    }
  }
}

extern "C" void kernel_launch(void* const* d_in, const int* in_sizes, int n_in,
                              void* d_out, int out_size, void* d_ws, size_t ws_size,
                              hipStream_t stream){
  (void)in_sizes; (void)n_in; (void)out_size;
  const float* attrs = (const float*)d_in[0];
  const float* feats = (const float*)d_in[1];
  const float* ea    = (const float*)d_in[2];
  const float* ef    = (const float*)d_in[3];
  const float* Wsrc  = (const float*)d_in[4];
  const float* Wtgt  = (const float*)d_in[5];
  const float* Wup0  = (const float*)d_in[6];
  const float* Wup1  = (const float*)d_in[7];
  const float* Wsk0  = (const float*)d_in[8];
  const float* Wsk1  = (const float*)d_in[9];
  const float* Wres0 = (const float*)d_in[10];
  const float* Wres1 = (const float*)d_in[11];
  const float* Wl10  = (const float*)d_in[12];
  const float* Wl11  = (const float*)d_in[13];
  const float* Wl20  = (const float*)d_in[14];
  const float* Wl21  = (const float*)d_in[15];
  const float* Wr1   = (const float*)d_in[16];
  const float* Wr2   = (const float*)d_in[17];
  const float* Wr3   = (const float*)d_in[18];
  const float* Wr4   = (const float*)d_in[19];
  const float* Wd1   = (const float*)d_in[20];
  const float* Wd2   = (const float*)d_in[21];
  const float* alphap= (const float*)d_in[22];
  const float* betap = (const float*)d_in[23];
  const int*   eidx  = (const int*)d_in[24];

  const size_t fixed_bytes =
      (size_t)NN*(512 + 1536 + 1024 + 1536 + 4 + 1024 + 256 + 768 + 512 + 512 + 256) +
      (size_t)NE*60 +
      (size_t)286976*2 + 4*ADIM*64*4 +
      (10240+10240+10256)*4 + 64*256;
  int nchunk, npc, cap;
  if (fixed_bytes + (size_t)NE*1024 + 65536 <= ws_size){ nchunk=1; npc=NN;   cap=NE;    }
  else if (fixed_bytes + 81920ULL*1024 + 65536 <= ws_size){ nchunk=2; npc=5000; cap=81920; }
  else { nchunk=4; npc=2500; cap=44032; }

  char* p = (char*)d_ws;
  auto alloc = [&](size_t bytes)->char*{ char* r=p; p += (bytes+255)&~(size_t)255; return r; };
  unsigned* tpwp  = (unsigned*)alloc((size_t)cap*256*4);
  unsigned short* msg_s16 = (unsigned short*)alloc((size_t)NN*256*2);
  unsigned short* msg_v16 = (unsigned short*)alloc((size_t)NN*768*2);
  float*  res_s   = (float*)alloc((size_t)NN*256*4);
  float*  res_v   = (float*)alloc((size_t)NN*384*4);
  float*  density = (float*)alloc((size_t)NN*4);
  float4* ybuf    = (float4*)alloc((size_t)NE*16);
  float*  densbuf = (float*)alloc((size_t)NE*4);
  int*    sndbuf  = (int*)alloc((size_t)NE*4);
  int*    rcvbuf  = (int*)alloc((size_t)NE*4);
  float*  efb     = (float*)alloc((size_t)NE*32);
  uint4*  upk     = (uint4*)alloc((size_t)NN*64*16);
  unsigned short* fs16 = (unsigned short*)alloc((size_t)NN*128*2);
  unsigned short* fv16 = (unsigned short*)alloc((size_t)NN*384*2);
  float* pA = (float*)alloc((size_t)NN*128*4);
  float* pB = (float*)alloc((size_t)NN*128*4);
  float* Wc  = (float*)alloc(4*ADIM*64*4);
  unsigned short* gate16 = (unsigned short*)alloc((size_t)NN*128*2);
  unsigned short* WTr2 = (unsigned short*)alloc(4096*2);
  unsigned short* WTr3 = (unsigned short*)alloc(4096*2);
  unsigned short* WTr4 = (unsigned short*)alloc(32768*2);
  unsigned short* Wl10T = (unsigned short*)alloc(65536*2);
  unsigned short* Wl11T = (unsigned short*)alloc(32768*2);
  unsigned short* Wl20T = (unsigned short*)alloc(16384*2);
  unsigned short* Wl21T = (unsigned short*)alloc(16384*2);
  unsigned short* WnsT  = (unsigned short*)alloc(65536*2);
  unsigned short* WnvT  = (unsigned short*)alloc(49152*2);
  int* deg     = (int*)alloc(10240*4);
  int* cursor  = (int*)alloc(10240*4);
  int* offsets = (int*)alloc(10256*4);

  unsigned short* scal16 = fs16;   // NN*128, fs16 dead after k_node_pre2
  unsigned short* vtmp16 = fv16;   // 3*NN*128, fv16 dead after k_node_pre2

  float* out_msg = (float*)d_out;               // NN*512
  float* out_sc  = out_msg + (size_t)NN*512;    // NN*512

  hipMemsetAsync(deg, 0, 2*10240*sizeof(int), stream);

  k_prep<<<1121, 256, 0, stream>>>(Wr2, Wr3, Wr4, Wl10, Wl11, Wl20, Wl21,
                                   Wsk0, Wup0, Wres0, Wsk1, Wup1, Wres1,
                                   Wsrc, Wtgt, Wr1, Wd1,
                                   WTr2, WTr3, WTr4,
                                   Wl10T, Wl11T, Wl20T, Wl21T, WnsT, WnvT, Wc);
  k_nodeemb<<<(NN*64+255)/256, 256, 0, stream>>>(attrs, Wc, pA, pB);
  k_feat_prep<<<NN*512/256, 256, 0, stream>>>(feats, fs16, fv16);
  k_node_pre2<<<dim3(NB64,13), 256, 0, stream>>>(fs16, fv16, WnsT, WnvT,
                                                 out_sc, (unsigned short*)upk, res_s, res_v);
  k_deg<<<(NE+255)/256, 256, 0, stream>>>(eidx, deg);
  k_scan<<<1, 256, 0, stream>>>(deg, offsets);
  k_fill<<<(NE+255)/256, 256, 0, stream>>>(eidx, ef, ea, offsets, cursor,
                                           sndbuf, rcvbuf, ybuf, efb);

  int tpw_blocks = (cap+63)/64;
  for (int c=0; c<nchunk; ++c){
    k_tpw<<<tpw_blocks, 256, 0, stream>>>(sndbuf, rcvbuf, efb, pA, pB,
                                          Wr1, Wd1, Wd2, WTr2, WTr3, WTr4,
                                          offsets, c*npc, (c+1)*npc, cap,
                                          tpwp, densbuf);
    k_gather<<<npc, 256, 0, stream>>>(tpwp, ybuf, sndbuf, densbuf, upk,
                                      offsets, c*npc, msg_s16, msg_v16, density);
  }

  k_post1<<<dim3(NB64,5), 256, 0, stream>>>(msg_s16, msg_v16, density, res_s, res_v,
                                            Wl10T, Wl11T, alphap, betap,
                                            scal16, gate16, vtmp16);
  k_post2<<<dim3(NB64,4), 256, 0, stream>>>(scal16, gate16, vtmp16,
                                            Wl20T, Wl21T, out_msg);
}

// Round 13
// 419.896 us; speedup vs baseline: 1.1101x; 1.0479x over previous
//
#include <hip/hip_runtime.h>
#include <hip/hip_bf16.h>
#include <math.h>

#define NN 10000
#define NE 160000
#define MUL 128
#define ADIM 10
#define RADF 8
#define HID 64
#define INV_SQRT3 0.57735026918962576f
#define NB64 157           // ceil(NN/64)

typedef __attribute__((ext_vector_type(8))) short bf16x8;
typedef __attribute__((ext_vector_type(4))) float f32x4;

__device__ __forceinline__ float silu_f(float x){ return x / (1.0f + __expf(-x)); }
__device__ __forceinline__ float sigmoid_f(float x){ return 1.0f / (1.0f + __expf(-x)); }
// legacy manual RNE (cold prep kernels)
__device__ __forceinline__ unsigned short f2b(float f){
  union{float f; unsigned u;} v; v.f=f;
  unsigned r = (v.u + 0x7fffu + ((v.u>>16)&1u))>>16;
  return (unsigned short)r;
}
// hot-path: native HW converts
__device__ __forceinline__ unsigned short f2bh(float f){
  __hip_bfloat16 h = __float2bfloat16(f);
  union{ __hip_bfloat16 h; unsigned short u; } v; v.h=h; return v.u;
}
__device__ __forceinline__ unsigned f2b2(float lo, float hi){
  float2 t; t.x=lo; t.y=hi;
  __hip_bfloat162 h2 = __float22bfloat162_rn(t);
  union{ __hip_bfloat162 h; unsigned u; } v; v.h=h2; return v.u;
}
__device__ __forceinline__ float b2f(unsigned short h){
  union{unsigned u; float f;} v; v.u = ((unsigned)h)<<16; return v.f;
}
__device__ __forceinline__ float b2f_lo(unsigned u){
  union{unsigned u; float f;} v; v.u = u<<16; return v.f;
}
__device__ __forceinline__ float b2f_hi(unsigned u){
  union{unsigned u; float f;} v; v.u = u & 0xffff0000u; return v.f;
}

// ---------------- per-node layer1 partials, packed {rad, den} float2 ----------------
__global__ __launch_bounds__(256) void k_nodeemb(
    const float* __restrict__ attrs, const float* __restrict__ Wc,
    float* __restrict__ pA, float* __restrict__ pB){
  int idx = blockIdx.x*256 + threadIdx.x;
  if (idx >= NN*64) return;
  int n = idx>>6, c = idx&63;
  float s0=0,s1=0,s2=0,s3=0;
  #pragma unroll
  for (int a=0;a<ADIM;a++){
    float x = attrs[n*ADIM+a];
    s0 += x*Wc[(0*ADIM+a)*64+c];
    s1 += x*Wc[(1*ADIM+a)*64+c];
    s2 += x*Wc[(2*ADIM+a)*64+c];
    s3 += x*Wc[(3*ADIM+a)*64+c];
  }
  pA[(size_t)n*128 + c*2 + 0] = s0;
  pA[(size_t)n*128 + c*2 + 1] = s2;
  pB[(size_t)n*128 + c*2 + 0] = s1;
  pB[(size_t)n*128 + c*2 + 1] = s3;
}

// ---------------- feat prep ----------------
__global__ __launch_bounds__(256) void k_feat_prep(
    const float* __restrict__ feats, unsigned short* __restrict__ fs16,
    unsigned short* __restrict__ fv16){
  int idx = blockIdx.x*256 + threadIdx.x;
  int n = idx >> 9, c = idx & 511;
  float v = feats[idx];
  if (c < 128) fs16[n*128 + c] = f2bh(v);
  else {
    int q = c - 128; int u = q/3; int i = q - 3*u;
    fv16[((size_t)n*3 + i)*128 + u] = f2bh(v);
  }
}

// ---------------- weight prep: transpose + bf16 cast (+ wcomb merged) ----------------
__global__ __launch_bounds__(256) void k_prep(
    const float* __restrict__ Wr2, const float* __restrict__ Wr3,
    const float* __restrict__ Wr4,
    const float* __restrict__ Wl10, const float* __restrict__ Wl11,
    const float* __restrict__ Wl20, const float* __restrict__ Wl21,
    const float* __restrict__ Wsk0, const float* __restrict__ Wup0, const float* __restrict__ Wres0,
    const float* __restrict__ Wsk1, const float* __restrict__ Wup1, const float* __restrict__ Wres1,
    const float* __restrict__ Wsrc, const float* __restrict__ Wtgt,
    const float* __restrict__ Wr1, const float* __restrict__ Wd1,
    unsigned short* __restrict__ WTr2, unsigned short* __restrict__ WTr3,
    unsigned short* __restrict__ WTr4,
    unsigned short* __restrict__ Wl10T, unsigned short* __restrict__ Wl11T,
    unsigned short* __restrict__ Wl20T, unsigned short* __restrict__ Wl21T,
    unsigned short* __restrict__ WnsT, unsigned short* __restrict__ WnvT,
    float* __restrict__ Wc){
  int idx = blockIdx.x*256 + threadIdx.x;
  if (idx < 4096){
    int j = idx; int n=j>>6, k=j&63;
    WTr2[j] = f2b(Wr2[k*64+n]);
  } else if (idx < 8192){
    int j = idx-4096; int n=j>>6, k=j&63;
    WTr3[j] = f2b(Wr3[k*64+n]);
  } else if (idx < 40960){
    int j = idx-8192; int n=j>>6, k=j&63;
    WTr4[j] = f2b(Wr4[k*512+n]);
  } else if (idx < 106496){
    int j = idx-40960; int n=j>>8, k=j&255;
    Wl10T[j] = f2b(Wl10[k*256+n]);
  } else if (idx < 139264){
    int j = idx-106496; int n=j>>8, k=j&255;
    Wl11T[j] = f2b(Wl11[k*128+n]);
  } else if (idx < 155648){
    int j = idx-139264; int n=j>>7, k=j&127;
    Wl20T[j] = f2b(Wl20[k*128+n]);
  } else if (idx < 172032){
    int j = idx-155648; int n=j>>7, k=j&127;
    Wl21T[j] = f2b(Wl21[k*128+n]);
  } else if (idx < 237568){
    int j = idx-172032; int n=j>>7, k=j&127;
    float v;
    if (n < 128)      v = Wsk0[k*128+n];
    else if (n < 256) v = Wup0[k*128+(n-128)];
    else              v = Wres0[k*256+(n-256)];
    WnsT[j] = f2b(v);
  } else if (idx < 286720){
    int j = idx-237568; int n=j>>7, k=j&127;
    float v;
    if (n < 128)      v = Wsk1[k*128+n];
    else if (n < 256) v = Wup1[k*128+(n-128)];
    else              v = Wres1[k*128+(n-256)];
    WnvT[j] = f2b(v);
  } else if (idx < 286976){
    int j = idx - 286720;      // wcomb: Wc[m][10][64]
    int m = j>>6, c = j&63;
    const float* WA = (m&1)? Wtgt : Wsrc;
    const float* WB = (m<2)? Wr1 : Wd1;
    int koff = (m&1)? 136 : 8;
    for (int a=0;a<ADIM;a++){
      float s=0.f;
      for (int k=0;k<128;k++) s += WA[a*128+k]*WB[(koff+k)*64+c];
      Wc[(m*ADIM+a)*64+c] = s;
    }
  }
}

// ---------------- K1: per-node precompute via MFMA ----------------
__global__ __launch_bounds__(256) void k_node_pre2(
    const unsigned short* __restrict__ fs16, const unsigned short* __restrict__ fv16,
    const unsigned short* __restrict__ WnsT, const unsigned short* __restrict__ WnvT,
    float* __restrict__ out_sc,
    unsigned short* __restrict__ upk16,
    float* __restrict__ res_s, float* __restrict__ res_v){
  __shared__ unsigned short fA[64][136];
  int nb = blockIdx.x*64;
  int c = blockIdx.y;
  int g, ntc;
  if (c < 4){ g=0; ntc=c; } else { g = 1 + (c-4)/3; ntc = (c-4)%3; }
  int tid = threadIdx.x;
  int w = tid>>6, l = tid&63, m0 = w*16, lr = l&15, lg = l>>4;
  for (int idx=tid; idx<64*16; idx+=256){
    int row = idx>>4, s8 = idx&15;
    int n = min(nb+row, NN-1);
    const unsigned short* src = (g==0) ? &fs16[(size_t)n*128 + s8*8]
                                       : &fv16[((size_t)n*3 + (g-1))*128 + s8*8];
    *(uint4*)&fA[row][s8*8] = *(const uint4*)src;
  }
  __syncthreads();
  const unsigned short* WT = ((g==0)? WnsT : WnvT) + (size_t)ntc*128*128;
  f32x4 acc[8];
  #pragma unroll
  for (int t=0;t<8;t++) acc[t]=(f32x4)(0.f);
  #pragma unroll
  for (int kb=0;kb<4;kb++){
    bf16x8 a = *(const bf16x8*)&fA[m0+lr][kb*32 + lg*8];
    #pragma unroll
    for (int t=0;t<8;t++){
      bf16x8 b = *(const bf16x8*)&WT[(size_t)(t*16+lr)*128 + kb*32 + lg*8];
      acc[t] = __builtin_amdgcn_mfma_f32_16x16x32_bf16(a, b, acc[t], 0,0,0);
    }
  }
  #pragma unroll
  for (int t=0;t<8;t++){
    #pragma unroll
    for (int r=0;r<4;r++){
      int col = (ntc*8+t)*16 + lr;
      int row = m0 + lg*4 + r;
      int n = nb + row;
      if (n < NN){
        float v = acc[t][r];
        if (g==0){
          if (col < 128)      out_sc[(size_t)n*512 + col] = v;
          else if (col < 256){
            int cc = col-128;
            upk16[(size_t)n*512 + (cc&63)*8 + (cc>>6)] = f2bh(v);
          } else              res_s[(size_t)n*256 + col-256] = v;
        } else {
          int i = g-1;
          if (col < 128)      out_sc[(size_t)n*512 + 128 + col*3 + i] = v;
          else if (col < 256){
            int cc = col-128;
            upk16[(size_t)n*512 + (cc&63)*8 + (1+i)*2 + (cc>>6)] = f2bh(v);
          } else              res_v[((size_t)n*3+i)*128 + col-256] = v;
        }
      }
    }
  }
}

// ---------------- CSR build ----------------
__global__ __launch_bounds__(256) void k_deg(const int* __restrict__ eidx, int* __restrict__ deg){
  int i = blockIdx.x*256+threadIdx.x;
  if (i<NE) atomicAdd(&deg[eidx[2*i+1]],1);
}
__global__ __launch_bounds__(256) void k_scan(const int* __restrict__ deg, int* __restrict__ offsets){
  __shared__ int part[256];
  int t = threadIdx.x; int base = t*40;
  int s=0;
  for (int k=0;k<40;k++){ int idx=base+k; if (idx<NN) s+=deg[idx]; }
  part[t]=s; __syncthreads();
  if (t==0){ int run=0; for (int i=0;i<256;i++){ int v=part[i]; part[i]=run; run+=v; } }
  __syncthreads();
  int run = part[t];
  for (int k=0;k<40;k++){
    int idx=base+k;
    if (idx<=NN) offsets[idx]=run;
    if (idx<NN) run+=deg[idx];
  }
}
// fill: materialize CSR-ordered edge data
__global__ __launch_bounds__(256) void k_fill(
    const int* __restrict__ eidx, const float* __restrict__ ef, const float* __restrict__ ea,
    const int* __restrict__ offsets, int* __restrict__ cursor,
    int* __restrict__ sndbuf, int* __restrict__ rcvbuf,
    float4* __restrict__ ybuf, float* __restrict__ efb){
  int i = blockIdx.x*256+threadIdx.x;
  if (i<NE){
    int sn = eidx[2*i], rc = eidx[2*i+1];
    int p = offsets[rc] + atomicAdd(&cursor[rc],1);
    sndbuf[p]=sn; rcvbuf[p]=rc;
    ybuf[p] = ((const float4*)ea)[i];
    *(float4*)&efb[(size_t)p*8]     = *(const float4*)&ef[(size_t)i*8];
    *(float4*)&efb[(size_t)p*8 + 4] = *(const float4*)&ef[(size_t)i*8 + 4];
  }
}

// ---------------- K2: edge MLP, 32 edges/wave, A-hoisted, B-reused ----------------
__global__ __launch_bounds__(256) void k_tpw(
    const int* __restrict__ sndbuf, const int* __restrict__ rcvbuf,
    const float* __restrict__ efb,
    const float* __restrict__ pA, const float* __restrict__ pB,
    const float* __restrict__ Wr1, const float* __restrict__ Wd1, const float* __restrict__ Wd2,
    const unsigned short* __restrict__ WTr2, const unsigned short* __restrict__ WTr3,
    const unsigned short* __restrict__ WTr4,
    const int* __restrict__ offsets, int nstart, int nend, int cap,
    unsigned* __restrict__ tpwp, float* __restrict__ densbuf){
  __shared__ unsigned short hA[128][72];
  __shared__ unsigned short hB[128][72];
  int ebase = offsets[nstart];
  int eend  = min(offsets[nend], ebase + cap);
  int i0 = ebase + blockIdx.x*128;
  if (i0 >= eend) return;
  int nrows = min(128, eend - i0);
  int tid = threadIdx.x;
  int w = tid>>6, l = tid&63, m0 = w*32, lr = l&15, lg = l>>4;
  int wbase = i0 + m0;
  // metadata: lane l<32 snd, l>=32 rcv (32 edges)
  int v_meta;
  {
    int pos = min(wbase + (l&31), eend-1);
    v_meta = (l < 32) ? sndbuf[pos] : rcvbuf[pos];
  }
  // ef regs: rq holds ef[edge=l&31][k = 2q + (l>>5)]
  float r0,r1,r2,r3;
  {
    int pos = min(wbase + (l&31), eend-1);
    int hi = l>>5;
    r0 = efb[(size_t)pos*8 + 0 + hi];
    r1 = efb[(size_t)pos*8 + 2 + hi];
    r2 = efb[(size_t)pos*8 + 4 + hi];
    r3 = efb[(size_t)pos*8 + 6 + hi];
  }
  // ---- layer1 (VALU, f32), 32 rows ----
  {
    float wr[8], wd[8];
    #pragma unroll
    for (int k=0;k<8;k++){ wr[k]=Wr1[k*64+l]; wd[k]=Wd1[k*64+l]; }
    float wd2c = Wd2[l];
    #pragma unroll
    for (int j=0;j<32;j++){
      int sn = __shfl(v_meta, j);
      int rc = __shfl(v_meta, 32+j);
      float2 av = *(const float2*)&pA[(size_t)sn*128 + l*2];
      float2 bv = *(const float2*)&pB[(size_t)rc*128 + l*2];
      float e0=__shfl(r0,j), e1=__shfl(r0,32+j);
      float e2=__shfl(r1,j), e3=__shfl(r1,32+j);
      float e4=__shfl(r2,j), e5=__shfl(r2,32+j);
      float e6=__shfl(r3,j), e7=__shfl(r3,32+j);
      float h  = av.x + bv.x;
      float hd = av.y + bv.y;
      h  += e0*wr[0]+e1*wr[1]+e2*wr[2]+e3*wr[3]+e4*wr[4]+e5*wr[5]+e6*wr[6]+e7*wr[7];
      hd += e0*wd[0]+e1*wd[1]+e2*wd[2]+e3*wd[3]+e4*wd[4]+e5*wd[5]+e6*wd[6]+e7*wd[7];
      hA[m0+j][l] = f2bh(silu_f(h));
      float sv = silu_f(hd)*wd2c;
      #pragma unroll
      for (int m=32;m;m>>=1) sv += __shfl_xor(sv, m);
      if (l==0 && m0+j < nrows) densbuf[wbase + j] = tanhf(sv*sv);
    }
  }
  // ---- layer2: hA -> hB (two 16-row batches, B reused) ----
  {
    bf16x8 a0[2], a1[2];
    #pragma unroll
    for (int kb=0;kb<2;kb++){
      a0[kb] = *(const bf16x8*)&hA[m0+lr][kb*32 + lg*8];
      a1[kb] = *(const bf16x8*)&hA[m0+16+lr][kb*32 + lg*8];
    }
    #pragma unroll
    for (int nt=0;nt<4;nt++){
      f32x4 c0=(f32x4)(0.f), c1=(f32x4)(0.f);
      #pragma unroll
      for (int kb=0;kb<2;kb++){
        bf16x8 b = *(const bf16x8*)&WTr2[(nt*16+lr)*64 + kb*32 + lg*8];
        c0 = __builtin_amdgcn_mfma_f32_16x16x32_bf16(a0[kb], b, c0, 0,0,0);
        c1 = __builtin_amdgcn_mfma_f32_16x16x32_bf16(a1[kb], b, c1, 0,0,0);
      }
      #pragma unroll
      for (int r=0;r<4;r++){
        hB[m0+lg*4+r][nt*16+lr]    = f2bh(silu_f(c0[r]));
        hB[m0+16+lg*4+r][nt*16+lr] = f2bh(silu_f(c1[r]));
      }
    }
  }
  // ---- layer3: hB -> hA ----
  {
    bf16x8 a0[2], a1[2];
    #pragma unroll
    for (int kb=0;kb<2;kb++){
      a0[kb] = *(const bf16x8*)&hB[m0+lr][kb*32 + lg*8];
      a1[kb] = *(const bf16x8*)&hB[m0+16+lr][kb*32 + lg*8];
    }
    #pragma unroll
    for (int nt=0;nt<4;nt++){
      f32x4 c0=(f32x4)(0.f), c1=(f32x4)(0.f);
      #pragma unroll
      for (int kb=0;kb<2;kb++){
        bf16x8 b = *(const bf16x8*)&WTr3[(nt*16+lr)*64 + kb*32 + lg*8];
        c0 = __builtin_amdgcn_mfma_f32_16x16x32_bf16(a0[kb], b, c0, 0,0,0);
        c1 = __builtin_amdgcn_mfma_f32_16x16x32_bf16(a1[kb], b, c1, 0,0,0);
      }
      #pragma unroll
      for (int r=0;r<4;r++){
        hA[m0+lg*4+r][nt*16+lr]    = f2bh(silu_f(c0[r]));
        hA[m0+16+lg*4+r][nt*16+lr] = f2bh(silu_f(c1[r]));
      }
    }
  }
  // ---- layer4: A-hoisted, B reused across the two batches, packed u32 out ----
  {
    bf16x8 a0[2], a1[2];
    #pragma unroll
    for (int kb=0;kb<2;kb++){
      a0[kb] = *(const bf16x8*)&hA[m0+lr][kb*32 + lg*8];
      a1[kb] = *(const bf16x8*)&hA[m0+16+lr][kb*32 + lg*8];
    }
    int erow0 = i0 - ebase;
    #pragma unroll
    for (int nt=0; nt<4; nt++){
      unsigned pv0[4][4], pv1[4][4];   // [r][G]
      #pragma unroll
      for (int G=0; G<4; G++){
        f32x4 e0=(f32x4)(0.f), o0=(f32x4)(0.f), e1=(f32x4)(0.f), o1=(f32x4)(0.f);
        #pragma unroll
        for (int kb=0; kb<2; kb++){
          bf16x8 bE = *(const bf16x8*)&WTr4[((2*G)*64+nt*16+lr)*64 + kb*32 + lg*8];
          bf16x8 bO = *(const bf16x8*)&WTr4[((2*G+1)*64+nt*16+lr)*64 + kb*32 + lg*8];
          e0 = __builtin_amdgcn_mfma_f32_16x16x32_bf16(a0[kb], bE, e0, 0,0,0);
          o0 = __builtin_amdgcn_mfma_f32_16x16x32_bf16(a0[kb], bO, o0, 0,0,0);
          e1 = __builtin_amdgcn_mfma_f32_16x16x32_bf16(a1[kb], bE, e1, 0,0,0);
          o1 = __builtin_amdgcn_mfma_f32_16x16x32_bf16(a1[kb], bO, o1, 0,0,0);
        }
        #pragma unroll
        for (int r=0;r<4;r++){
          pv0[r][G] = f2b2(e0[r], o0[r]);
          pv1[r][G] = f2b2(e1[r], o1[r]);
        }
      }
      #pragma unroll
      for (int r=0;r<4;r++){
        int row0 = m0 + lg*4 + r;
        int row1 = m0 + 16 + lg*4 + r;
        if (row0 < nrows)
          *(uint4*)&tpwp[(size_t)(erow0+row0)*256 + (nt*16+lr)*4] = *(uint4*)&pv0[r][0];
        if (row1 < nrows)
          *(uint4*)&tpwp[(size_t)(erow0+row1)*256 + (nt*16+lr)*4] = *(uint4*)&pv1[r][0];
      }
    }
  }
}

// ---------------- K3: CSR gather — 4 waves per node (1 block/node), LDS combine ------
__global__ __launch_bounds__(256) void k_gather(
    const unsigned* __restrict__ tpwp, const float4* __restrict__ ybuf,
    const int* __restrict__ sndbuf, const float* __restrict__ densbuf,
    const uint4* __restrict__ upk4,
    const int* __restrict__ offsets, int nstart,
    unsigned short* __restrict__ msg_s16, unsigned short* __restrict__ msg_v16,
    float* __restrict__ density){
  __shared__ float part[3][1024];
  __shared__ float pden[3];
  int w = threadIdx.x>>6, l = threadIdx.x&63;
  int n = nstart + blockIdx.x;
  int ebase = offsets[nstart];
  int s0 = offsets[n], s1 = offsets[n+1];
  float mA0=0,mA1=0,mD0=0,mD1=0;
  float mB00=0,mB01=0,mB10=0,mB11=0,mB20=0,mB21=0;
  float mC00=0,mC01=0,mC10=0,mC11=0,mC20=0,mC21=0;
  float dsum=0;
  #pragma unroll 2
  for (int i=s0+w; i<s1; i+=4){
    int li = i - ebase;
    int sn = sndbuf[i];
    float4 y = ybuf[i];
    dsum += densbuf[i];
    uint4 tq = *(const uint4*)&tpwp[(size_t)li*256 + l*4];
    uint4 uq = upk4[(size_t)sn*64 + l];
    float wA0=b2f_lo(tq.x), wA1=b2f_hi(tq.x);
    float wB0=b2f_lo(tq.y), wB1=b2f_hi(tq.y);
    float wC0=b2f_lo(tq.z), wC1=b2f_hi(tq.z);
    float wD0=b2f_lo(tq.w), wD1=b2f_hi(tq.w);
    float xs0=b2f_lo(uq.x), xs1=b2f_hi(uq.x);
    float xv00=b2f_lo(uq.y), xv01=b2f_hi(uq.y);
    float xv10=b2f_lo(uq.z), xv11=b2f_hi(uq.z);
    float xv20=b2f_lo(uq.w), xv21=b2f_hi(uq.w);
    mA0 += wA0*xs0*y.x; mA1 += wA1*xs1*y.x;
    float dot0 = xv00*y.y + xv10*y.z + xv20*y.w;
    float dot1 = xv01*y.y + xv11*y.z + xv21*y.w;
    mD0 += wD0*dot0; mD1 += wD1*dot1;
    float b0 = wB0*xs0, b1 = wB1*xs1;
    mB00 += b0*y.y; mB01 += b1*y.y;
    mB10 += b0*y.z; mB11 += b1*y.z;
    mB20 += b0*y.w; mB21 += b1*y.w;
    float c0 = wC0*y.x, c1 = wC1*y.x;
    mC00 += c0*xv00; mC01 += c1*xv01;
    mC10 += c0*xv10; mC11 += c1*xv11;
    mC20 += c0*xv20; mC21 += c1*xv21;
  }
  if (w){
    float* P = part[w-1];
    P[0*64+l]=mA0;  P[1*64+l]=mA1;  P[2*64+l]=mD0;  P[3*64+l]=mD1;
    P[4*64+l]=mB00; P[5*64+l]=mB01; P[6*64+l]=mB10; P[7*64+l]=mB11;
    P[8*64+l]=mB20; P[9*64+l]=mB21; P[10*64+l]=mC00; P[11*64+l]=mC01;
    P[12*64+l]=mC10; P[13*64+l]=mC11; P[14*64+l]=mC20; P[15*64+l]=mC21;
    if (l==0) pden[w-1]=dsum;
  }
  __syncthreads();
  if (w==0){
    #pragma unroll
    for (int q=0;q<3;q++){
      const float* P = part[q];
      mA0+=P[0*64+l];  mA1+=P[1*64+l];  mD0+=P[2*64+l];  mD1+=P[3*64+l];
      mB00+=P[4*64+l]; mB01+=P[5*64+l]; mB10+=P[6*64+l]; mB11+=P[7*64+l];
      mB20+=P[8*64+l]; mB21+=P[9*64+l]; mC00+=P[10*64+l]; mC01+=P[11*64+l];
      mC10+=P[12*64+l]; mC11+=P[13*64+l]; mC20+=P[14*64+l]; mC21+=P[15*64+l];
    }
    dsum += pden[0]+pden[1]+pden[2];
    unsigned short* ms = msg_s16 + (size_t)n*256;
    ms[l]=f2bh(mA0); ms[64+l]=f2bh(mA1);
    ms[128+l]=f2bh(mD0*INV_SQRT3); ms[192+l]=f2bh(mD1*INV_SQRT3);
    unsigned short* mv = msg_v16 + (size_t)n*768;
    mv[l]=f2bh(mB00);     mv[64+l]=f2bh(mB01);  mv[128+l]=f2bh(mC00); mv[192+l]=f2bh(mC01);
    mv[256+l]=f2bh(mB10); mv[320+l]=f2bh(mB11); mv[384+l]=f2bh(mC10); mv[448+l]=f2bh(mC11);
    mv[512+l]=f2bh(mB20); mv[576+l]=f2bh(mB21); mv[640+l]=f2bh(mC20); mv[704+l]=f2bh(mC21);
    if (l==0) density[n]=dsum;
  }
}

// ---------------- K4a: lin1 for all 5 N=128 chunks. grid (NB64, 5) ----------------
__global__ __launch_bounds__(256) void k_post1(
    const unsigned short* __restrict__ msg_s16, const unsigned short* __restrict__ msg_v16,
    const float* __restrict__ density,
    const float* __restrict__ res_s, const float* __restrict__ res_v,
    const unsigned short* __restrict__ Wl10T, const unsigned short* __restrict__ Wl11T,
    const float* __restrict__ alphap, const float* __restrict__ betap,
    unsigned short* __restrict__ scal16, unsigned short* __restrict__ gate16,
    unsigned short* __restrict__ vtmp16){
  __shared__ unsigned short sm[64][264];
  __shared__ float sden[64];
  int nb = blockIdx.x*64, y = blockIdx.y;
  int tid = threadIdx.x;
  int w = tid>>6, l = tid&63, m0 = w*16, lr = l&15, lg = l>>4;
  for (int idx=tid; idx<64*32; idx+=256){
    int row = idx>>5, s8 = idx&31;
    int n = min(nb+row, NN-1);
    const unsigned short* src = (y<2)? &msg_s16[(size_t)n*256 + s8*8]
                                     : &msg_v16[(size_t)n*768 + (y-2)*256 + s8*8];
    *(uint4*)&sm[row][s8*8] = *(const uint4*)src;
  }
  if (tid < 64){
    int n = min(nb+tid, NN-1);
    sden[tid] = density[n]*betap[0] + alphap[0]*20.0f;
  }
  __syncthreads();
  const unsigned short* BT = (y<2)? (Wl10T + (size_t)y*128*256) : Wl11T;
  f32x4 acc[8];
  #pragma unroll
  for (int t=0;t<8;t++) acc[t]=(f32x4)(0.f);
  for (int kb=0;kb<8;kb++){
    bf16x8 a = *(const bf16x8*)&sm[m0+lr][kb*32 + lg*8];
    #pragma unroll
    for (int t=0;t<8;t++){
      bf16x8 b = *(const bf16x8*)&BT[(size_t)(t*16+lr)*256 + kb*32 + lg*8];
      acc[t] = __builtin_amdgcn_mfma_f32_16x16x32_bf16(a, b, acc[t], 0,0,0);
    }
  }
  #pragma unroll
  for (int t=0;t<8;t++){
    #pragma unroll
    for (int r=0;r<4;r++){
      int col = t*16+lr;
      int row = m0 + lg*4 + r;
      int n = nb + row;
      if (n < NN){
        float v = acc[t][r]/sden[row];
        if (y==0){
          v += res_s[(size_t)n*256 + col];
          scal16[(size_t)n*128 + col] = f2bh(silu_f(v));
        } else if (y==1){
          v += res_s[(size_t)n*256 + 128 + col];
          gate16[(size_t)n*128 + col] = f2bh(sigmoid_f(v));
        } else {
          int i = y-2;
          v += res_v[((size_t)n*3+i)*128 + col];
          vtmp16[((size_t)i*NN + n)*128 + col] = f2bh(v);
        }
      }
    }
  }
}

// ---------------- K4b: lin2 for 4 output components. grid (NB64, 4) ----------------
__global__ __launch_bounds__(256) void k_post2(
    const unsigned short* __restrict__ scal16, const unsigned short* __restrict__ gate16,
    const unsigned short* __restrict__ vtmp16,
    const unsigned short* __restrict__ Wl20T, const unsigned short* __restrict__ Wl21T,
    float* __restrict__ out_msg){
  __shared__ unsigned short sA[64][136];
  int nb = blockIdx.x*64, y = blockIdx.y;
  int tid = threadIdx.x;
  int w = tid>>6, l = tid&63, m0 = w*16, lr = l&15, lg = l>>4;
  for (int idx=tid; idx<64*16; idx+=256){
    int row = idx>>4, s8 = idx&15;
    int n = min(nb+row, NN-1);
    if (y==0){
      *(uint4*)&sA[row][s8*8] = *(const uint4*)&scal16[(size_t)n*128 + s8*8];
    } else {
      int i = y-1;
      uint4 va = *(const uint4*)&vtmp16[((size_t)i*NN + n)*128 + s8*8];
      uint4 vg = *(const uint4*)&gate16[(size_t)n*128 + s8*8];
      const unsigned short* pa = (const unsigned short*)&va;
      const unsigned short* pg = (const unsigned short*)&vg;
      unsigned short o[8];
      #pragma unroll
      for (int j=0;j<8;j++) o[j] = f2bh(b2f(pa[j])*b2f(pg[j]));
      *(uint4*)&sA[row][s8*8] = *(const uint4*)o;
    }
  }
  __syncthreads();
  const unsigned short* BT = (y==0)? Wl20T : Wl21T;
  f32x4 acc[8];
  #pragma unroll
  for (int t=0;t<8;t++) acc[t]=(f32x4)(0.f);
  #pragma unroll
  for (int kb=0;kb<4;kb++){
    bf16x8 a = *(const bf16x8*)&sA[m0+lr][kb*32 + lg*8];
    #pragma unroll
    for (int t=0;t<8;t++){
      bf16x8 b = *(const bf16x8*)&BT[(size_t)(t*16+lr)*128 + kb*32 + lg*8];
      acc[t] = __builtin_amdgcn_mfma_f32_16x16x32_bf16(a, b, acc[t], 0,0,0);
    }
  }
  #pragma unroll
  for (int t=0;t<8;t++){
    #pragma unroll
    for (int r=0;r<4;r++){
      int col = t*16+lr;
      int n = nb + m0 + lg*4 + r;
      if (n < NN) out_msg[(size_t)n*512 + col*4 + y] = acc[t][r];
    }
  }
}

extern "C" void kernel_launch(void* const* d_in, const int* in_sizes, int n_in,
                              void* d_out, int out_size, void* d_ws, size_t ws_size,
                              hipStream_t stream){
  (void)in_sizes; (void)n_in; (void)out_size;
  const float* attrs = (const float*)d_in[0];
  const float* feats = (const float*)d_in[1];
  const float* ea    = (const float*)d_in[2];
  const float* ef    = (const float*)d_in[3];
  const float* Wsrc  = (const float*)d_in[4];
  const float* Wtgt  = (const float*)d_in[5];
  const float* Wup0  = (const float*)d_in[6];
  const float* Wup1  = (const float*)d_in[7];
  const float* Wsk0  = (const float*)d_in[8];
  const float* Wsk1  = (const float*)d_in[9];
  const float* Wres0 = (const float*)d_in[10];
  const float* Wres1 = (const float*)d_in[11];
  const float* Wl10  = (const float*)d_in[12];
  const float* Wl11  = (const float*)d_in[13];
  const float* Wl20  = (const float*)d_in[14];
  const float* Wl21  = (const float*)d_in[15];
  const float* Wr1   = (const float*)d_in[16];
  const float* Wr2   = (const float*)d_in[17];
  const float* Wr3   = (const float*)d_in[18];
  const float* Wr4   = (const float*)d_in[19];
  const float* Wd1   = (const float*)d_in[20];
  const float* Wd2   = (const float*)d_in[21];
  const float* alphap= (const float*)d_in[22];
  const float* betap = (const float*)d_in[23];
  const int*   eidx  = (const int*)d_in[24];

  const size_t fixed_bytes =
      (size_t)NN*(512 + 1536 + 1024 + 1536 + 4 + 1024 + 256 + 768 + 512 + 512 + 256) +
      (size_t)NE*60 +
      (size_t)286976*2 + 4*ADIM*64*4 +
      (10240+10240+10256)*4 + 64*256;
  int nchunk, npc, cap;
  if (fixed_bytes + (size_t)NE*1024 + 65536 <= ws_size){ nchunk=1; npc=NN;   cap=NE;    }
  else if (fixed_bytes + 81920ULL*1024 + 65536 <= ws_size){ nchunk=2; npc=5000; cap=81920; }
  else { nchunk=4; npc=2500; cap=44032; }

  char* p = (char*)d_ws;
  auto alloc = [&](size_t bytes)->char*{ char* r=p; p += (bytes+255)&~(size_t)255; return r; };
  unsigned* tpwp  = (unsigned*)alloc((size_t)cap*256*4);
  unsigned short* msg_s16 = (unsigned short*)alloc((size_t)NN*256*2);
  unsigned short* msg_v16 = (unsigned short*)alloc((size_t)NN*768*2);
  float*  res_s   = (float*)alloc((size_t)NN*256*4);
  float*  res_v   = (float*)alloc((size_t)NN*384*4);
  float*  density = (float*)alloc((size_t)NN*4);
  float4* ybuf    = (float4*)alloc((size_t)NE*16);
  float*  densbuf = (float*)alloc((size_t)NE*4);
  int*    sndbuf  = (int*)alloc((size_t)NE*4);
  int*    rcvbuf  = (int*)alloc((size_t)NE*4);
  float*  efb     = (float*)alloc((size_t)NE*32);
  uint4*  upk     = (uint4*)alloc((size_t)NN*64*16);
  unsigned short* fs16 = (unsigned short*)alloc((size_t)NN*128*2);
  unsigned short* fv16 = (unsigned short*)alloc((size_t)NN*384*2);
  float* pA = (float*)alloc((size_t)NN*128*4);
  float* pB = (float*)alloc((size_t)NN*128*4);
  float* Wc  = (float*)alloc(4*ADIM*64*4);
  unsigned short* gate16 = (unsigned short*)alloc((size_t)NN*128*2);
  unsigned short* WTr2 = (unsigned short*)alloc(4096*2);
  unsigned short* WTr3 = (unsigned short*)alloc(4096*2);
  unsigned short* WTr4 = (unsigned short*)alloc(32768*2);
  unsigned short* Wl10T = (unsigned short*)alloc(65536*2);
  unsigned short* Wl11T = (unsigned short*)alloc(32768*2);
  unsigned short* Wl20T = (unsigned short*)alloc(16384*2);
  unsigned short* Wl21T = (unsigned short*)alloc(16384*2);
  unsigned short* WnsT  = (unsigned short*)alloc(65536*2);
  unsigned short* WnvT  = (unsigned short*)alloc(49152*2);
  int* deg     = (int*)alloc(10240*4);
  int* cursor  = (int*)alloc(10240*4);
  int* offsets = (int*)alloc(10256*4);

  unsigned short* scal16 = fs16;   // NN*128, fs16 dead after k_node_pre2
  unsigned short* vtmp16 = fv16;   // 3*NN*128, fv16 dead after k_node_pre2

  float* out_msg = (float*)d_out;               // NN*512
  float* out_sc  = out_msg + (size_t)NN*512;    // NN*512

  hipMemsetAsync(deg, 0, 2*10240*sizeof(int), stream);

  k_prep<<<1121, 256, 0, stream>>>(Wr2, Wr3, Wr4, Wl10, Wl11, Wl20, Wl21,
                                   Wsk0, Wup0, Wres0, Wsk1, Wup1, Wres1,
                                   Wsrc, Wtgt, Wr1, Wd1,
                                   WTr2, WTr3, WTr4,
                                   Wl10T, Wl11T, Wl20T, Wl21T, WnsT, WnvT, Wc);
  k_nodeemb<<<(NN*64+255)/256, 256, 0, stream>>>(attrs, Wc, pA, pB);
  k_feat_prep<<<NN*512/256, 256, 0, stream>>>(feats, fs16, fv16);
  k_node_pre2<<<dim3(NB64,13), 256, 0, stream>>>(fs16, fv16, WnsT, WnvT,
                                                 out_sc, (unsigned short*)upk, res_s, res_v);
  k_deg<<<(NE+255)/256, 256, 0, stream>>>(eidx, deg);
  k_scan<<<1, 256, 0, stream>>>(deg, offsets);
  k_fill<<<(NE+255)/256, 256, 0, stream>>>(eidx, ef, ea, offsets, cursor,
                                           sndbuf, rcvbuf, ybuf, efb);

  int tpw_blocks = (cap+127)/128;
  for (int c=0; c<nchunk; ++c){
    k_tpw<<<tpw_blocks, 256, 0, stream>>>(sndbuf, rcvbuf, efb, pA, pB,
                                          Wr1, Wd1, Wd2, WTr2, WTr3, WTr4,
                                          offsets, c*npc, (c+1)*npc, cap,
                                          tpwp, densbuf);
    k_gather<<<npc, 256, 0, stream>>>(tpwp, ybuf, sndbuf, densbuf, upk,
                                      offsets, c*npc, msg_s16, msg_v16, density);
  }

  k_post1<<<dim3(NB64,5), 256, 0, stream>>>(msg_s16, msg_v16, density, res_s, res_v,
                                            Wl10T, Wl11T, alphap, betap,
                                            scal16, gate16, vtmp16);
  k_post2<<<dim3(NB64,4), 256, 0, stream>>>(scal16, gate16, vtmp16,
                                            Wl20T, Wl21T, out_msg);
}

// Round 14
// 418.928 us; speedup vs baseline: 1.1127x; 1.0023x over previous
//
#include <hip/hip_runtime.h>
#include <hip/hip_bf16.h>
#include <math.h>

#define NN 10000
#define NE 160000
#define MUL 128
#define ADIM 10
#define RADF 8
#define HID 64
#define INV_SQRT3 0.57735026918962576f
#define NB64 157           // ceil(NN/64)

typedef __attribute__((ext_vector_type(8))) short bf16x8;
typedef __attribute__((ext_vector_type(4))) float f32x4;

__device__ __forceinline__ float silu_f(float x){ return x / (1.0f + __expf(-x)); }
__device__ __forceinline__ float sigmoid_f(float x){ return 1.0f / (1.0f + __expf(-x)); }
// legacy manual RNE (cold prep kernels)
__device__ __forceinline__ unsigned short f2b(float f){
  union{float f; unsigned u;} v; v.f=f;
  unsigned r = (v.u + 0x7fffu + ((v.u>>16)&1u))>>16;
  return (unsigned short)r;
}
// hot-path: native HW converts
__device__ __forceinline__ unsigned short f2bh(float f){
  __hip_bfloat16 h = __float2bfloat16(f);
  union{ __hip_bfloat16 h; unsigned short u; } v; v.h=h; return v.u;
}
__device__ __forceinline__ unsigned f2b2(float lo, float hi){
  float2 t; t.x=lo; t.y=hi;
  __hip_bfloat162 h2 = __float22bfloat162_rn(t);
  union{ __hip_bfloat162 h; unsigned u; } v; v.h=h2; return v.u;
}
__device__ __forceinline__ float b2f(unsigned short h){
  union{unsigned u; float f;} v; v.u = ((unsigned)h)<<16; return v.f;
}
__device__ __forceinline__ float b2f_lo(unsigned u){
  union{unsigned u; float f;} v; v.u = u<<16; return v.f;
}
__device__ __forceinline__ float b2f_hi(unsigned u){
  union{unsigned u; float f;} v; v.u = u & 0xffff0000u; return v.f;
}

// ---------------- per-node layer1 partials, packed {rad, den} float2 ----------------
__global__ __launch_bounds__(256) void k_nodeemb(
    const float* __restrict__ attrs, const float* __restrict__ Wc,
    float* __restrict__ pA, float* __restrict__ pB){
  int idx = blockIdx.x*256 + threadIdx.x;
  if (idx >= NN*64) return;
  int n = idx>>6, c = idx&63;
  float s0=0,s1=0,s2=0,s3=0;
  #pragma unroll
  for (int a=0;a<ADIM;a++){
    float x = attrs[n*ADIM+a];
    s0 += x*Wc[(0*ADIM+a)*64+c];
    s1 += x*Wc[(1*ADIM+a)*64+c];
    s2 += x*Wc[(2*ADIM+a)*64+c];
    s3 += x*Wc[(3*ADIM+a)*64+c];
  }
  pA[(size_t)n*128 + c*2 + 0] = s0;
  pA[(size_t)n*128 + c*2 + 1] = s2;
  pB[(size_t)n*128 + c*2 + 0] = s1;
  pB[(size_t)n*128 + c*2 + 1] = s3;
}

// ---------------- feat prep ----------------
__global__ __launch_bounds__(256) void k_feat_prep(
    const float* __restrict__ feats, unsigned short* __restrict__ fs16,
    unsigned short* __restrict__ fv16){
  int idx = blockIdx.x*256 + threadIdx.x;
  int n = idx >> 9, c = idx & 511;
  float v = feats[idx];
  if (c < 128) fs16[n*128 + c] = f2bh(v);
  else {
    int q = c - 128; int u = q/3; int i = q - 3*u;
    fv16[((size_t)n*3 + i)*128 + u] = f2bh(v);
  }
}

// ---------------- weight prep: transpose + bf16 cast (+ wcomb merged) ----------------
__global__ __launch_bounds__(256) void k_prep(
    const float* __restrict__ Wr2, const float* __restrict__ Wr3,
    const float* __restrict__ Wr4,
    const float* __restrict__ Wl10, const float* __restrict__ Wl11,
    const float* __restrict__ Wl20, const float* __restrict__ Wl21,
    const float* __restrict__ Wsk0, const float* __restrict__ Wup0, const float* __restrict__ Wres0,
    const float* __restrict__ Wsk1, const float* __restrict__ Wup1, const float* __restrict__ Wres1,
    const float* __restrict__ Wsrc, const float* __restrict__ Wtgt,
    const float* __restrict__ Wr1, const float* __restrict__ Wd1,
    unsigned short* __restrict__ WTr2, unsigned short* __restrict__ WTr3,
    unsigned short* __restrict__ WTr4,
    unsigned short* __restrict__ Wl10T, unsigned short* __restrict__ Wl11T,
    unsigned short* __restrict__ Wl20T, unsigned short* __restrict__ Wl21T,
    unsigned short* __restrict__ WnsT, unsigned short* __restrict__ WnvT,
    float* __restrict__ Wc){
  int idx = blockIdx.x*256 + threadIdx.x;
  if (idx < 4096){
    int j = idx; int n=j>>6, k=j&63;
    WTr2[j] = f2b(Wr2[k*64+n]);
  } else if (idx < 8192){
    int j = idx-4096; int n=j>>6, k=j&63;
    WTr3[j] = f2b(Wr3[k*64+n]);
  } else if (idx < 40960){
    int j = idx-8192; int n=j>>6, k=j&63;
    WTr4[j] = f2b(Wr4[k*512+n]);
  } else if (idx < 106496){
    int j = idx-40960; int n=j>>8, k=j&255;
    Wl10T[j] = f2b(Wl10[k*256+n]);
  } else if (idx < 139264){
    int j = idx-106496; int n=j>>8, k=j&255;
    Wl11T[j] = f2b(Wl11[k*128+n]);
  } else if (idx < 155648){
    int j = idx-139264; int n=j>>7, k=j&127;
    Wl20T[j] = f2b(Wl20[k*128+n]);
  } else if (idx < 172032){
    int j = idx-155648; int n=j>>7, k=j&127;
    Wl21T[j] = f2b(Wl21[k*128+n]);
  } else if (idx < 237568){
    int j = idx-172032; int n=j>>7, k=j&127;
    float v;
    if (n < 128)      v = Wsk0[k*128+n];
    else if (n < 256) v = Wup0[k*128+(n-128)];
    else              v = Wres0[k*256+(n-256)];
    WnsT[j] = f2b(v);
  } else if (idx < 286720){
    int j = idx-237568; int n=j>>7, k=j&127;
    float v;
    if (n < 128)      v = Wsk1[k*128+n];
    else if (n < 256) v = Wup1[k*128+(n-128)];
    else              v = Wres1[k*128+(n-256)];
    WnvT[j] = f2b(v);
  } else if (idx < 286976){
    int j = idx - 286720;      // wcomb: Wc[m][10][64]
    int m = j>>6, c = j&63;
    const float* WA = (m&1)? Wtgt : Wsrc;
    const float* WB = (m<2)? Wr1 : Wd1;
    int koff = (m&1)? 136 : 8;
    for (int a=0;a<ADIM;a++){
      float s=0.f;
      for (int k=0;k<128;k++) s += WA[a*128+k]*WB[(koff+k)*64+c];
      Wc[(m*ADIM+a)*64+c] = s;
    }
  }
}

// ---------------- K1: per-node precompute via MFMA ----------------
__global__ __launch_bounds__(256) void k_node_pre2(
    const unsigned short* __restrict__ fs16, const unsigned short* __restrict__ fv16,
    const unsigned short* __restrict__ WnsT, const unsigned short* __restrict__ WnvT,
    float* __restrict__ out_sc,
    unsigned short* __restrict__ upk16,
    float* __restrict__ res_s, float* __restrict__ res_v){
  __shared__ unsigned short fA[64][136];
  int nb = blockIdx.x*64;
  int c = blockIdx.y;
  int g, ntc;
  if (c < 4){ g=0; ntc=c; } else { g = 1 + (c-4)/3; ntc = (c-4)%3; }
  int tid = threadIdx.x;
  int w = tid>>6, l = tid&63, m0 = w*16, lr = l&15, lg = l>>4;
  for (int idx=tid; idx<64*16; idx+=256){
    int row = idx>>4, s8 = idx&15;
    int n = min(nb+row, NN-1);
    const unsigned short* src = (g==0) ? &fs16[(size_t)n*128 + s8*8]
                                       : &fv16[((size_t)n*3 + (g-1))*128 + s8*8];
    *(uint4*)&fA[row][s8*8] = *(const uint4*)src;
  }
  __syncthreads();
  const unsigned short* WT = ((g==0)? WnsT : WnvT) + (size_t)ntc*128*128;
  f32x4 acc[8];
  #pragma unroll
  for (int t=0;t<8;t++) acc[t]=(f32x4)(0.f);
  #pragma unroll
  for (int kb=0;kb<4;kb++){
    bf16x8 a = *(const bf16x8*)&fA[m0+lr][kb*32 + lg*8];
    #pragma unroll
    for (int t=0;t<8;t++){
      bf16x8 b = *(const bf16x8*)&WT[(size_t)(t*16+lr)*128 + kb*32 + lg*8];
      acc[t] = __builtin_amdgcn_mfma_f32_16x16x32_bf16(a, b, acc[t], 0,0,0);
    }
  }
  #pragma unroll
  for (int t=0;t<8;t++){
    #pragma unroll
    for (int r=0;r<4;r++){
      int col = (ntc*8+t)*16 + lr;
      int row = m0 + lg*4 + r;
      int n = nb + row;
      if (n < NN){
        float v = acc[t][r];
        if (g==0){
          if (col < 128)      out_sc[(size_t)n*512 + col] = v;
          else if (col < 256){
            int cc = col-128;
            upk16[(size_t)n*512 + (cc&63)*8 + (cc>>6)] = f2bh(v);
          } else              res_s[(size_t)n*256 + col-256] = v;
        } else {
          int i = g-1;
          if (col < 128)      out_sc[(size_t)n*512 + 128 + col*3 + i] = v;
          else if (col < 256){
            int cc = col-128;
            upk16[(size_t)n*512 + (cc&63)*8 + (1+i)*2 + (cc>>6)] = f2bh(v);
          } else              res_v[((size_t)n*3+i)*128 + col-256] = v;
        }
      }
    }
  }
}

// ---------------- CSR build ----------------
__global__ __launch_bounds__(256) void k_deg(const int* __restrict__ eidx, int* __restrict__ deg){
  int i = blockIdx.x*256+threadIdx.x;
  if (i<NE) atomicAdd(&deg[eidx[2*i+1]],1);
}
__global__ __launch_bounds__(256) void k_scan(const int* __restrict__ deg, int* __restrict__ offsets){
  __shared__ int part[256];
  int t = threadIdx.x; int base = t*40;
  int s=0;
  for (int k=0;k<40;k++){ int idx=base+k; if (idx<NN) s+=deg[idx]; }
  part[t]=s; __syncthreads();
  if (t==0){ int run=0; for (int i=0;i<256;i++){ int v=part[i]; part[i]=run; run+=v; } }
  __syncthreads();
  int run = part[t];
  for (int k=0;k<40;k++){
    int idx=base+k;
    if (idx<=NN) offsets[idx]=run;
    if (idx<NN) run+=deg[idx];
  }
}
// fill: materialize CSR-ordered edge data
__global__ __launch_bounds__(256) void k_fill(
    const int* __restrict__ eidx, const float* __restrict__ ef, const float* __restrict__ ea,
    const int* __restrict__ offsets, int* __restrict__ cursor,
    int* __restrict__ sndbuf, int* __restrict__ rcvbuf,
    float4* __restrict__ ybuf, float* __restrict__ efb){
  int i = blockIdx.x*256+threadIdx.x;
  if (i<NE){
    int sn = eidx[2*i], rc = eidx[2*i+1];
    int p = offsets[rc] + atomicAdd(&cursor[rc],1);
    sndbuf[p]=sn; rcvbuf[p]=rc;
    ybuf[p] = ((const float4*)ea)[i];
    *(float4*)&efb[(size_t)p*8]     = *(const float4*)&ef[(size_t)i*8];
    *(float4*)&efb[(size_t)p*8 + 4] = *(const float4*)&ef[(size_t)i*8 + 4];
  }
}

// ---------------- K2: edge MLP, 32 edges/wave, single LDS buffer (in-place layers) ---
__global__ __launch_bounds__(256) void k_tpw(
    const int* __restrict__ sndbuf, const int* __restrict__ rcvbuf,
    const float* __restrict__ efb,
    const float* __restrict__ pA, const float* __restrict__ pB,
    const float* __restrict__ Wr1, const float* __restrict__ Wd1, const float* __restrict__ Wd2,
    const unsigned short* __restrict__ WTr2, const unsigned short* __restrict__ WTr3,
    const unsigned short* __restrict__ WTr4,
    const int* __restrict__ offsets, int nstart, int nend, int cap,
    unsigned* __restrict__ tpwp, float* __restrict__ densbuf){
  __shared__ unsigned short hS[128][72];   // single buffer: layers run in place
  int ebase = offsets[nstart];
  int eend  = min(offsets[nend], ebase + cap);
  int i0 = ebase + blockIdx.x*128;
  if (i0 >= eend) return;
  int nrows = min(128, eend - i0);
  int tid = threadIdx.x;
  int w = tid>>6, l = tid&63, m0 = w*32, lr = l&15, lg = l>>4;
  int wbase = i0 + m0;
  // metadata: lane l<32 snd, l>=32 rcv (32 edges)
  int v_meta;
  {
    int pos = min(wbase + (l&31), eend-1);
    v_meta = (l < 32) ? sndbuf[pos] : rcvbuf[pos];
  }
  // ef regs: rq holds ef[edge=l&31][k = 2q + (l>>5)]
  float r0,r1,r2,r3;
  {
    int pos = min(wbase + (l&31), eend-1);
    int hi = l>>5;
    r0 = efb[(size_t)pos*8 + 0 + hi];
    r1 = efb[(size_t)pos*8 + 2 + hi];
    r2 = efb[(size_t)pos*8 + 4 + hi];
    r3 = efb[(size_t)pos*8 + 6 + hi];
  }
  // ---- layer1 (VALU, f32), 32 rows ----
  {
    float wr[8], wd[8];
    #pragma unroll
    for (int k=0;k<8;k++){ wr[k]=Wr1[k*64+l]; wd[k]=Wd1[k*64+l]; }
    float wd2c = Wd2[l];
    #pragma unroll
    for (int j=0;j<32;j++){
      int sn = __shfl(v_meta, j);
      int rc = __shfl(v_meta, 32+j);
      float2 av = *(const float2*)&pA[(size_t)sn*128 + l*2];
      float2 bv = *(const float2*)&pB[(size_t)rc*128 + l*2];
      float e0=__shfl(r0,j), e1=__shfl(r0,32+j);
      float e2=__shfl(r1,j), e3=__shfl(r1,32+j);
      float e4=__shfl(r2,j), e5=__shfl(r2,32+j);
      float e6=__shfl(r3,j), e7=__shfl(r3,32+j);
      float h  = av.x + bv.x;
      float hd = av.y + bv.y;
      h  += e0*wr[0]+e1*wr[1]+e2*wr[2]+e3*wr[3]+e4*wr[4]+e5*wr[5]+e6*wr[6]+e7*wr[7];
      hd += e0*wd[0]+e1*wd[1]+e2*wd[2]+e3*wd[3]+e4*wd[4]+e5*wd[5]+e6*wd[6]+e7*wd[7];
      hS[m0+j][l] = f2bh(silu_f(h));
      float sv = silu_f(hd)*wd2c;
      #pragma unroll
      for (int m=32;m;m>>=1) sv += __shfl_xor(sv, m);
      if (l==0 && m0+j < nrows) densbuf[wbase + j] = tanhf(sv*sv);
    }
  }
  // ---- layer2: in-place (A hoisted to regs first; wave-private rows) ----
  {
    bf16x8 a0[2], a1[2];
    #pragma unroll
    for (int kb=0;kb<2;kb++){
      a0[kb] = *(const bf16x8*)&hS[m0+lr][kb*32 + lg*8];
      a1[kb] = *(const bf16x8*)&hS[m0+16+lr][kb*32 + lg*8];
    }
    #pragma unroll
    for (int nt=0;nt<4;nt++){
      f32x4 c0=(f32x4)(0.f), c1=(f32x4)(0.f);
      #pragma unroll
      for (int kb=0;kb<2;kb++){
        bf16x8 b = *(const bf16x8*)&WTr2[(nt*16+lr)*64 + kb*32 + lg*8];
        c0 = __builtin_amdgcn_mfma_f32_16x16x32_bf16(a0[kb], b, c0, 0,0,0);
        c1 = __builtin_amdgcn_mfma_f32_16x16x32_bf16(a1[kb], b, c1, 0,0,0);
      }
      #pragma unroll
      for (int r=0;r<4;r++){
        hS[m0+lg*4+r][nt*16+lr]    = f2bh(silu_f(c0[r]));
        hS[m0+16+lg*4+r][nt*16+lr] = f2bh(silu_f(c1[r]));
      }
    }
  }
  // ---- layer3: in-place ----
  {
    bf16x8 a0[2], a1[2];
    #pragma unroll
    for (int kb=0;kb<2;kb++){
      a0[kb] = *(const bf16x8*)&hS[m0+lr][kb*32 + lg*8];
      a1[kb] = *(const bf16x8*)&hS[m0+16+lr][kb*32 + lg*8];
    }
    #pragma unroll
    for (int nt=0;nt<4;nt++){
      f32x4 c0=(f32x4)(0.f), c1=(f32x4)(0.f);
      #pragma unroll
      for (int kb=0;kb<2;kb++){
        bf16x8 b = *(const bf16x8*)&WTr3[(nt*16+lr)*64 + kb*32 + lg*8];
        c0 = __builtin_amdgcn_mfma_f32_16x16x32_bf16(a0[kb], b, c0, 0,0,0);
        c1 = __builtin_amdgcn_mfma_f32_16x16x32_bf16(a1[kb], b, c1, 0,0,0);
      }
      #pragma unroll
      for (int r=0;r<4;r++){
        hS[m0+lg*4+r][nt*16+lr]    = f2bh(silu_f(c0[r]));
        hS[m0+16+lg*4+r][nt*16+lr] = f2bh(silu_f(c1[r]));
      }
    }
  }
  // ---- layer4: A-hoisted, B reused across the two batches, packed u32 out ----
  {
    bf16x8 a0[2], a1[2];
    #pragma unroll
    for (int kb=0;kb<2;kb++){
      a0[kb] = *(const bf16x8*)&hS[m0+lr][kb*32 + lg*8];
      a1[kb] = *(const bf16x8*)&hS[m0+16+lr][kb*32 + lg*8];
    }
    int erow0 = i0 - ebase;
    #pragma unroll
    for (int nt=0; nt<4; nt++){
      unsigned pv0[4][4], pv1[4][4];   // [r][G]
      #pragma unroll
      for (int G=0; G<4; G++){
        f32x4 e0=(f32x4)(0.f), o0=(f32x4)(0.f), e1=(f32x4)(0.f), o1=(f32x4)(0.f);
        #pragma unroll
        for (int kb=0; kb<2; kb++){
          bf16x8 bE = *(const bf16x8*)&WTr4[((2*G)*64+nt*16+lr)*64 + kb*32 + lg*8];
          bf16x8 bO = *(const bf16x8*)&WTr4[((2*G+1)*64+nt*16+lr)*64 + kb*32 + lg*8];
          e0 = __builtin_amdgcn_mfma_f32_16x16x32_bf16(a0[kb], bE, e0, 0,0,0);
          o0 = __builtin_amdgcn_mfma_f32_16x16x32_bf16(a0[kb], bO, o0, 0,0,0);
          e1 = __builtin_amdgcn_mfma_f32_16x16x32_bf16(a1[kb], bE, e1, 0,0,0);
          o1 = __builtin_amdgcn_mfma_f32_16x16x32_bf16(a1[kb], bO, o1, 0,0,0);
        }
        #pragma unroll
        for (int r=0;r<4;r++){
          pv0[r][G] = f2b2(e0[r], o0[r]);
          pv1[r][G] = f2b2(e1[r], o1[r]);
        }
      }
      #pragma unroll
      for (int r=0;r<4;r++){
        int row0 = m0 + lg*4 + r;
        int row1 = m0 + 16 + lg*4 + r;
        if (row0 < nrows)
          *(uint4*)&tpwp[(size_t)(erow0+row0)*256 + (nt*16+lr)*4] = *(uint4*)&pv0[r][0];
        if (row1 < nrows)
          *(uint4*)&tpwp[(size_t)(erow0+row1)*256 + (nt*16+lr)*4] = *(uint4*)&pv1[r][0];
      }
    }
  }
}

// ---------------- K3: CSR gather — 4 waves per node (1 block/node), LDS combine ------
__global__ __launch_bounds__(256) void k_gather(
    const unsigned* __restrict__ tpwp, const float4* __restrict__ ybuf,
    const int* __restrict__ sndbuf, const float* __restrict__ densbuf,
    const uint4* __restrict__ upk4,
    const int* __restrict__ offsets, int nstart,
    unsigned short* __restrict__ msg_s16, unsigned short* __restrict__ msg_v16,
    float* __restrict__ density){
  __shared__ float part[3][1024];
  __shared__ float pden[3];
  int w = threadIdx.x>>6, l = threadIdx.x&63;
  int n = nstart + blockIdx.x;
  int ebase = offsets[nstart];
  int s0 = offsets[n], s1 = offsets[n+1];
  float mA0=0,mA1=0,mD0=0,mD1=0;
  float mB00=0,mB01=0,mB10=0,mB11=0,mB20=0,mB21=0;
  float mC00=0,mC01=0,mC10=0,mC11=0,mC20=0,mC21=0;
  float dsum=0;
  #pragma unroll 2
  for (int i=s0+w; i<s1; i+=4){
    int li = i - ebase;
    int sn = sndbuf[i];
    float4 y = ybuf[i];
    dsum += densbuf[i];
    uint4 tq = *(const uint4*)&tpwp[(size_t)li*256 + l*4];
    uint4 uq = upk4[(size_t)sn*64 + l];
    float wA0=b2f_lo(tq.x), wA1=b2f_hi(tq.x);
    float wB0=b2f_lo(tq.y), wB1=b2f_hi(tq.y);
    float wC0=b2f_lo(tq.z), wC1=b2f_hi(tq.z);
    float wD0=b2f_lo(tq.w), wD1=b2f_hi(tq.w);
    float xs0=b2f_lo(uq.x), xs1=b2f_hi(uq.x);
    float xv00=b2f_lo(uq.y), xv01=b2f_hi(uq.y);
    float xv10=b2f_lo(uq.z), xv11=b2f_hi(uq.z);
    float xv20=b2f_lo(uq.w), xv21=b2f_hi(uq.w);
    mA0 += wA0*xs0*y.x; mA1 += wA1*xs1*y.x;
    float dot0 = xv00*y.y + xv10*y.z + xv20*y.w;
    float dot1 = xv01*y.y + xv11*y.z + xv21*y.w;
    mD0 += wD0*dot0; mD1 += wD1*dot1;
    float b0 = wB0*xs0, b1 = wB1*xs1;
    mB00 += b0*y.y; mB01 += b1*y.y;
    mB10 += b0*y.z; mB11 += b1*y.z;
    mB20 += b0*y.w; mB21 += b1*y.w;
    float c0 = wC0*y.x, c1 = wC1*y.x;
    mC00 += c0*xv00; mC01 += c1*xv01;
    mC10 += c0*xv10; mC11 += c1*xv11;
    mC20 += c0*xv20; mC21 += c1*xv21;
  }
  if (w){
    float* P = part[w-1];
    P[0*64+l]=mA0;  P[1*64+l]=mA1;  P[2*64+l]=mD0;  P[3*64+l]=mD1;
    P[4*64+l]=mB00; P[5*64+l]=mB01; P[6*64+l]=mB10; P[7*64+l]=mB11;
    P[8*64+l]=mB20; P[9*64+l]=mB21; P[10*64+l]=mC00; P[11*64+l]=mC01;
    P[12*64+l]=mC10; P[13*64+l]=mC11; P[14*64+l]=mC20; P[15*64+l]=mC21;
    if (l==0) pden[w-1]=dsum;
  }
  __syncthreads();
  if (w==0){
    #pragma unroll
    for (int q=0;q<3;q++){
      const float* P = part[q];
      mA0+=P[0*64+l];  mA1+=P[1*64+l];  mD0+=P[2*64+l];  mD1+=P[3*64+l];
      mB00+=P[4*64+l]; mB01+=P[5*64+l]; mB10+=P[6*64+l]; mB11+=P[7*64+l];
      mB20+=P[8*64+l]; mB21+=P[9*64+l]; mC00+=P[10*64+l]; mC01+=P[11*64+l];
      mC10+=P[12*64+l]; mC11+=P[13*64+l]; mC20+=P[14*64+l]; mC21+=P[15*64+l];
    }
    dsum += pden[0]+pden[1]+pden[2];
    unsigned short* ms = msg_s16 + (size_t)n*256;
    ms[l]=f2bh(mA0); ms[64+l]=f2bh(mA1);
    ms[128+l]=f2bh(mD0*INV_SQRT3); ms[192+l]=f2bh(mD1*INV_SQRT3);
    unsigned short* mv = msg_v16 + (size_t)n*768;
    mv[l]=f2bh(mB00);     mv[64+l]=f2bh(mB01);  mv[128+l]=f2bh(mC00); mv[192+l]=f2bh(mC01);
    mv[256+l]=f2bh(mB10); mv[320+l]=f2bh(mB11); mv[384+l]=f2bh(mC10); mv[448+l]=f2bh(mC11);
    mv[512+l]=f2bh(mB20); mv[576+l]=f2bh(mB21); mv[640+l]=f2bh(mC20); mv[704+l]=f2bh(mC21);
    if (l==0) density[n]=dsum;
  }
}

// ---------------- K4a: lin1 for all 5 N=128 chunks. grid (NB64, 5) ----------------
__global__ __launch_bounds__(256) void k_post1(
    const unsigned short* __restrict__ msg_s16, const unsigned short* __restrict__ msg_v16,
    const float* __restrict__ density,
    const float* __restrict__ res_s, const float* __restrict__ res_v,
    const unsigned short* __restrict__ Wl10T, const unsigned short* __restrict__ Wl11T,
    const float* __restrict__ alphap, const float* __restrict__ betap,
    unsigned short* __restrict__ scal16, unsigned short* __restrict__ gate16,
    unsigned short* __restrict__ vtmp16){
  __shared__ unsigned short sm[64][264];
  __shared__ float sden[64];
  int nb = blockIdx.x*64, y = blockIdx.y;
  int tid = threadIdx.x;
  int w = tid>>6, l = tid&63, m0 = w*16, lr = l&15, lg = l>>4;
  for (int idx=tid; idx<64*32; idx+=256){
    int row = idx>>5, s8 = idx&31;
    int n = min(nb+row, NN-1);
    const unsigned short* src = (y<2)? &msg_s16[(size_t)n*256 + s8*8]
                                     : &msg_v16[(size_t)n*768 + (y-2)*256 + s8*8];
    *(uint4*)&sm[row][s8*8] = *(const uint4*)src;
  }
  if (tid < 64){
    int n = min(nb+tid, NN-1);
    sden[tid] = density[n]*betap[0] + alphap[0]*20.0f;
  }
  __syncthreads();
  const unsigned short* BT = (y<2)? (Wl10T + (size_t)y*128*256) : Wl11T;
  f32x4 acc[8];
  #pragma unroll
  for (int t=0;t<8;t++) acc[t]=(f32x4)(0.f);
  for (int kb=0;kb<8;kb++){
    bf16x8 a = *(const bf16x8*)&sm[m0+lr][kb*32 + lg*8];
    #pragma unroll
    for (int t=0;t<8;t++){
      bf16x8 b = *(const bf16x8*)&BT[(size_t)(t*16+lr)*256 + kb*32 + lg*8];
      acc[t] = __builtin_amdgcn_mfma_f32_16x16x32_bf16(a, b, acc[t], 0,0,0);
    }
  }
  #pragma unroll
  for (int t=0;t<8;t++){
    #pragma unroll
    for (int r=0;r<4;r++){
      int col = t*16+lr;
      int row = m0 + lg*4 + r;
      int n = nb + row;
      if (n < NN){
        float v = acc[t][r]/sden[row];
        if (y==0){
          v += res_s[(size_t)n*256 + col];
          scal16[(size_t)n*128 + col] = f2bh(silu_f(v));
        } else if (y==1){
          v += res_s[(size_t)n*256 + 128 + col];
          gate16[(size_t)n*128 + col] = f2bh(sigmoid_f(v));
        } else {
          int i = y-2;
          v += res_v[((size_t)n*3+i)*128 + col];
          vtmp16[((size_t)i*NN + n)*128 + col] = f2bh(v);
        }
      }
    }
  }
}

// ---------------- K4b: lin2 for 4 output components. grid (NB64, 4) ----------------
__global__ __launch_bounds__(256) void k_post2(
    const unsigned short* __restrict__ scal16, const unsigned short* __restrict__ gate16,
    const unsigned short* __restrict__ vtmp16,
    const unsigned short* __restrict__ Wl20T, const unsigned short* __restrict__ Wl21T,
    float* __restrict__ out_msg){
  __shared__ unsigned short sA[64][136];
  int nb = blockIdx.x*64, y = blockIdx.y;
  int tid = threadIdx.x;
  int w = tid>>6, l = tid&63, m0 = w*16, lr = l&15, lg = l>>4;
  for (int idx=tid; idx<64*16; idx+=256){
    int row = idx>>4, s8 = idx&15;
    int n = min(nb+row, NN-1);
    if (y==0){
      *(uint4*)&sA[row][s8*8] = *(const uint4*)&scal16[(size_t)n*128 + s8*8];
    } else {
      int i = y-1;
      uint4 va = *(const uint4*)&vtmp16[((size_t)i*NN + n)*128 + s8*8];
      uint4 vg = *(const uint4*)&gate16[(size_t)n*128 + s8*8];
      const unsigned short* pa = (const unsigned short*)&va;
      const unsigned short* pg = (const unsigned short*)&vg;
      unsigned short o[8];
      #pragma unroll
      for (int j=0;j<8;j++) o[j] = f2bh(b2f(pa[j])*b2f(pg[j]));
      *(uint4*)&sA[row][s8*8] = *(const uint4*)o;
    }
  }
  __syncthreads();
  const unsigned short* BT = (y==0)? Wl20T : Wl21T;
  f32x4 acc[8];
  #pragma unroll
  for (int t=0;t<8;t++) acc[t]=(f32x4)(0.f);
  #pragma unroll
  for (int kb=0;kb<4;kb++){
    bf16x8 a = *(const bf16x8*)&sA[m0+lr][kb*32 + lg*8];
    #pragma unroll
    for (int t=0;t<8;t++){
      bf16x8 b = *(const bf16x8*)&BT[(size_t)(t*16+lr)*128 + kb*32 + lg*8];
      acc[t] = __builtin_amdgcn_mfma_f32_16x16x32_bf16(a, b, acc[t], 0,0,0);
    }
  }
  #pragma unroll
  for (int t=0;t<8;t++){
    #pragma unroll
    for (int r=0;r<4;r++){
      int col = t*16+lr;
      int n = nb + m0 + lg*4 + r;
      if (n < NN) out_msg[(size_t)n*512 + col*4 + y] = acc[t][r];
    }
  }
}

extern "C" void kernel_launch(void* const* d_in, const int* in_sizes, int n_in,
                              void* d_out, int out_size, void* d_ws, size_t ws_size,
                              hipStream_t stream){
  (void)in_sizes; (void)n_in; (void)out_size;
  const float* attrs = (const float*)d_in[0];
  const float* feats = (const float*)d_in[1];
  const float* ea    = (const float*)d_in[2];
  const float* ef    = (const float*)d_in[3];
  const float* Wsrc  = (const float*)d_in[4];
  const float* Wtgt  = (const float*)d_in[5];
  const float* Wup0  = (const float*)d_in[6];
  const float* Wup1  = (const float*)d_in[7];
  const float* Wsk0  = (const float*)d_in[8];
  const float* Wsk1  = (const float*)d_in[9];
  const float* Wres0 = (const float*)d_in[10];
  const float* Wres1 = (const float*)d_in[11];
  const float* Wl10  = (const float*)d_in[12];
  const float* Wl11  = (const float*)d_in[13];
  const float* Wl20  = (const float*)d_in[14];
  const float* Wl21  = (const float*)d_in[15];
  const float* Wr1   = (const float*)d_in[16];
  const float* Wr2   = (const float*)d_in[17];
  const float* Wr3   = (const float*)d_in[18];
  const float* Wr4   = (const float*)d_in[19];
  const float* Wd1   = (const float*)d_in[20];
  const float* Wd2   = (const float*)d_in[21];
  const float* alphap= (const float*)d_in[22];
  const float* betap = (const float*)d_in[23];
  const int*   eidx  = (const int*)d_in[24];

  const size_t fixed_bytes =
      (size_t)NN*(512 + 1536 + 1024 + 1536 + 4 + 1024 + 256 + 768 + 512 + 512 + 256) +
      (size_t)NE*60 +
      (size_t)286976*2 + 4*ADIM*64*4 +
      (10240+10240+10256)*4 + 64*256;
  int nchunk, npc, cap;
  if (fixed_bytes + (size_t)NE*1024 + 65536 <= ws_size){ nchunk=1; npc=NN;   cap=NE;    }
  else if (fixed_bytes + 81920ULL*1024 + 65536 <= ws_size){ nchunk=2; npc=5000; cap=81920; }
  else { nchunk=4; npc=2500; cap=44032; }

  char* p = (char*)d_ws;
  auto alloc = [&](size_t bytes)->char*{ char* r=p; p += (bytes+255)&~(size_t)255; return r; };
  unsigned* tpwp  = (unsigned*)alloc((size_t)cap*256*4);
  unsigned short* msg_s16 = (unsigned short*)alloc((size_t)NN*256*2);
  unsigned short* msg_v16 = (unsigned short*)alloc((size_t)NN*768*2);
  float*  res_s   = (float*)alloc((size_t)NN*256*4);
  float*  res_v   = (float*)alloc((size_t)NN*384*4);
  float*  density = (float*)alloc((size_t)NN*4);
  float4* ybuf    = (float4*)alloc((size_t)NE*16);
  float*  densbuf = (float*)alloc((size_t)NE*4);
  int*    sndbuf  = (int*)alloc((size_t)NE*4);
  int*    rcvbuf  = (int*)alloc((size_t)NE*4);
  float*  efb     = (float*)alloc((size_t)NE*32);
  uint4*  upk     = (uint4*)alloc((size_t)NN*64*16);
  unsigned short* fs16 = (unsigned short*)alloc((size_t)NN*128*2);
  unsigned short* fv16 = (unsigned short*)alloc((size_t)NN*384*2);
  float* pA = (float*)alloc((size_t)NN*128*4);
  float* pB = (float*)alloc((size_t)NN*128*4);
  float* Wc  = (float*)alloc(4*ADIM*64*4);
  unsigned short* gate16 = (unsigned short*)alloc((size_t)NN*128*2);
  unsigned short* WTr2 = (unsigned short*)alloc(4096*2);
  unsigned short* WTr3 = (unsigned short*)alloc(4096*2);
  unsigned short* WTr4 = (unsigned short*)alloc(32768*2);
  unsigned short* Wl10T = (unsigned short*)alloc(65536*2);
  unsigned short* Wl11T = (unsigned short*)alloc(32768*2);
  unsigned short* Wl20T = (unsigned short*)alloc(16384*2);
  unsigned short* Wl21T = (unsigned short*)alloc(16384*2);
  unsigned short* WnsT  = (unsigned short*)alloc(65536*2);
  unsigned short* WnvT  = (unsigned short*)alloc(49152*2);
  int* deg     = (int*)alloc(10240*4);
  int* cursor  = (int*)alloc(10240*4);
  int* offsets = (int*)alloc(10256*4);

  unsigned short* scal16 = fs16;   // NN*128, fs16 dead after k_node_pre2
  unsigned short* vtmp16 = fv16;   // 3*NN*128, fv16 dead after k_node_pre2

  float* out_msg = (float*)d_out;               // NN*512
  float* out_sc  = out_msg + (size_t)NN*512;    // NN*512

  hipMemsetAsync(deg, 0, 2*10240*sizeof(int), stream);

  k_prep<<<1121, 256, 0, stream>>>(Wr2, Wr3, Wr4, Wl10, Wl11, Wl20, Wl21,
                                   Wsk0, Wup0, Wres0, Wsk1, Wup1, Wres1,
                                   Wsrc, Wtgt, Wr1, Wd1,
                                   WTr2, WTr3, WTr4,
                                   Wl10T, Wl11T, Wl20T, Wl21T, WnsT, WnvT, Wc);
  k_nodeemb<<<(NN*64+255)/256, 256, 0, stream>>>(attrs, Wc, pA, pB);
  k_feat_prep<<<NN*512/256, 256, 0, stream>>>(feats, fs16, fv16);
  k_node_pre2<<<dim3(NB64,13), 256, 0, stream>>>(fs16, fv16, WnsT, WnvT,
                                                 out_sc, (unsigned short*)upk, res_s, res_v);
  k_deg<<<(NE+255)/256, 256, 0, stream>>>(eidx, deg);
  k_scan<<<1, 256, 0, stream>>>(deg, offsets);
  k_fill<<<(NE+255)/256, 256, 0, stream>>>(eidx, ef, ea, offsets, cursor,
                                           sndbuf, rcvbuf, ybuf, efb);

  int tpw_blocks = (cap+127)/128;
  for (int c=0; c<nchunk; ++c){
    k_tpw<<<tpw_blocks, 256, 0, stream>>>(sndbuf, rcvbuf, efb, pA, pB,
                                          Wr1, Wd1, Wd2, WTr2, WTr3, WTr4,
                                          offsets, c*npc, (c+1)*npc, cap,
                                          tpwp, densbuf);
    k_gather<<<npc, 256, 0, stream>>>(tpwp, ybuf, sndbuf, densbuf, upk,
                                      offsets, c*npc, msg_s16, msg_v16, density);
  }

  k_post1<<<dim3(NB64,5), 256, 0, stream>>>(msg_s16, msg_v16, density, res_s, res_v,
                                            Wl10T, Wl11T, alphap, betap,
                                            scal16, gate16, vtmp16);
  k_post2<<<dim3(NB64,4), 256, 0, stream>>>(scal16, gate16, vtmp16,
                                            Wl20T, Wl21T, out_msg);
}

// Round 15
// 416.955 us; speedup vs baseline: 1.1180x; 1.0047x over previous
//
#include <hip/hip_runtime.h>
#include <hip/hip_bf16.h>
#include <math.h>

#define NN 10000
#define NE 160000
#define MUL 128
#define ADIM 10
#define RADF 8
#define HID 64
#define INV_SQRT3 0.57735026918962576f
#define NB64 157           // ceil(NN/64)

typedef __attribute__((ext_vector_type(8))) short bf16x8;
typedef __attribute__((ext_vector_type(4))) float f32x4;

__device__ __forceinline__ float silu_f(float x){ return x / (1.0f + __expf(-x)); }
__device__ __forceinline__ float sigmoid_f(float x){ return 1.0f / (1.0f + __expf(-x)); }
// legacy manual RNE (cold prep kernels)
__device__ __forceinline__ unsigned short f2b(float f){
  union{float f; unsigned u;} v; v.f=f;
  unsigned r = (v.u + 0x7fffu + ((v.u>>16)&1u))>>16;
  return (unsigned short)r;
}
// hot-path: native HW converts
__device__ __forceinline__ unsigned short f2bh(float f){
  __hip_bfloat16 h = __float2bfloat16(f);
  union{ __hip_bfloat16 h; unsigned short u; } v; v.h=h; return v.u;
}
__device__ __forceinline__ unsigned f2b2(float lo, float hi){
  float2 t; t.x=lo; t.y=hi;
  __hip_bfloat162 h2 = __float22bfloat162_rn(t);
  union{ __hip_bfloat162 h; unsigned u; } v; v.h=h2; return v.u;
}
__device__ __forceinline__ float b2f(unsigned short h){
  union{unsigned u; float f;} v; v.u = ((unsigned)h)<<16; return v.f;
}
__device__ __forceinline__ float b2f_lo(unsigned u){
  union{unsigned u; float f;} v; v.u = u<<16; return v.f;
}
__device__ __forceinline__ float b2f_hi(unsigned u){
  union{unsigned u; float f;} v; v.u = u & 0xffff0000u; return v.f;
}

// ---------------- per-node layer1 partials, packed {rad, den} float2 ----------------
__global__ __launch_bounds__(256) void k_nodeemb(
    const float* __restrict__ attrs, const float* __restrict__ Wc,
    float* __restrict__ pA, float* __restrict__ pB){
  int idx = blockIdx.x*256 + threadIdx.x;
  if (idx >= NN*64) return;
  int n = idx>>6, c = idx&63;
  float s0=0,s1=0,s2=0,s3=0;
  #pragma unroll
  for (int a=0;a<ADIM;a++){
    float x = attrs[n*ADIM+a];
    s0 += x*Wc[(0*ADIM+a)*64+c];
    s1 += x*Wc[(1*ADIM+a)*64+c];
    s2 += x*Wc[(2*ADIM+a)*64+c];
    s3 += x*Wc[(3*ADIM+a)*64+c];
  }
  pA[(size_t)n*128 + c*2 + 0] = s0;
  pA[(size_t)n*128 + c*2 + 1] = s2;
  pB[(size_t)n*128 + c*2 + 0] = s1;
  pB[(size_t)n*128 + c*2 + 1] = s3;
}

// ---------------- feat prep ----------------
__global__ __launch_bounds__(256) void k_feat_prep(
    const float* __restrict__ feats, unsigned short* __restrict__ fs16,
    unsigned short* __restrict__ fv16){
  int idx = blockIdx.x*256 + threadIdx.x;
  int n = idx >> 9, c = idx & 511;
  float v = feats[idx];
  if (c < 128) fs16[n*128 + c] = f2bh(v);
  else {
    int q = c - 128; int u = q/3; int i = q - 3*u;
    fv16[((size_t)n*3 + i)*128 + u] = f2bh(v);
  }
}

// ---------------- weight prep: transpose + bf16 cast (+ wcomb merged) ----------------
__global__ __launch_bounds__(256) void k_prep(
    const float* __restrict__ Wr2, const float* __restrict__ Wr3,
    const float* __restrict__ Wr4,
    const float* __restrict__ Wl10, const float* __restrict__ Wl11,
    const float* __restrict__ Wl20, const float* __restrict__ Wl21,
    const float* __restrict__ Wsk0, const float* __restrict__ Wup0, const float* __restrict__ Wres0,
    const float* __restrict__ Wsk1, const float* __restrict__ Wup1, const float* __restrict__ Wres1,
    const float* __restrict__ Wsrc, const float* __restrict__ Wtgt,
    const float* __restrict__ Wr1, const float* __restrict__ Wd1,
    unsigned short* __restrict__ WTr2, unsigned short* __restrict__ WTr3,
    unsigned short* __restrict__ WTr4,
    unsigned short* __restrict__ Wl10T, unsigned short* __restrict__ Wl11T,
    unsigned short* __restrict__ Wl20T, unsigned short* __restrict__ Wl21T,
    unsigned short* __restrict__ WnsT, unsigned short* __restrict__ WnvT,
    float* __restrict__ Wc){
  int idx = blockIdx.x*256 + threadIdx.x;
  if (idx < 4096){
    int j = idx; int n=j>>6, k=j&63;
    WTr2[j] = f2b(Wr2[k*64+n]);
  } else if (idx < 8192){
    int j = idx-4096; int n=j>>6, k=j&63;
    WTr3[j] = f2b(Wr3[k*64+n]);
  } else if (idx < 40960){
    int j = idx-8192; int n=j>>6, k=j&63;
    WTr4[j] = f2b(Wr4[k*512+n]);
  } else if (idx < 106496){
    int j = idx-40960; int n=j>>8, k=j&255;
    Wl10T[j] = f2b(Wl10[k*256+n]);
  } else if (idx < 139264){
    int j = idx-106496; int n=j>>8, k=j&255;
    Wl11T[j] = f2b(Wl11[k*128+n]);
  } else if (idx < 155648){
    int j = idx-139264; int n=j>>7, k=j&127;
    Wl20T[j] = f2b(Wl20[k*128+n]);
  } else if (idx < 172032){
    int j = idx-155648; int n=j>>7, k=j&127;
    Wl21T[j] = f2b(Wl21[k*128+n]);
  } else if (idx < 237568){
    int j = idx-172032; int n=j>>7, k=j&127;
    float v;
    if (n < 128)      v = Wsk0[k*128+n];
    else if (n < 256) v = Wup0[k*128+(n-128)];
    else              v = Wres0[k*256+(n-256)];
    WnsT[j] = f2b(v);
  } else if (idx < 286720){
    int j = idx-237568; int n=j>>7, k=j&127;
    float v;
    if (n < 128)      v = Wsk1[k*128+n];
    else if (n < 256) v = Wup1[k*128+(n-128)];
    else              v = Wres1[k*128+(n-256)];
    WnvT[j] = f2b(v);
  } else if (idx < 286976){
    int j = idx - 286720;      // wcomb: Wc[m][10][64]
    int m = j>>6, c = j&63;
    const float* WA = (m&1)? Wtgt : Wsrc;
    const float* WB = (m<2)? Wr1 : Wd1;
    int koff = (m&1)? 136 : 8;
    for (int a=0;a<ADIM;a++){
      float s=0.f;
      for (int k=0;k<128;k++) s += WA[a*128+k]*WB[(koff+k)*64+c];
      Wc[(m*ADIM+a)*64+c] = s;
    }
  }
}

// ---------------- K1: per-node precompute via MFMA ----------------
__global__ __launch_bounds__(256) void k_node_pre2(
    const unsigned short* __restrict__ fs16, const unsigned short* __restrict__ fv16,
    const unsigned short* __restrict__ WnsT, const unsigned short* __restrict__ WnvT,
    float* __restrict__ out_sc,
    unsigned short* __restrict__ upk16,
    float* __restrict__ res_s, float* __restrict__ res_v){
  __shared__ unsigned short fA[64][136];
  int nb = blockIdx.x*64;
  int c = blockIdx.y;
  int g, ntc;
  if (c < 4){ g=0; ntc=c; } else { g = 1 + (c-4)/3; ntc = (c-4)%3; }
  int tid = threadIdx.x;
  int w = tid>>6, l = tid&63, m0 = w*16, lr = l&15, lg = l>>4;
  for (int idx=tid; idx<64*16; idx+=256){
    int row = idx>>4, s8 = idx&15;
    int n = min(nb+row, NN-1);
    const unsigned short* src = (g==0) ? &fs16[(size_t)n*128 + s8*8]
                                       : &fv16[((size_t)n*3 + (g-1))*128 + s8*8];
    *(uint4*)&fA[row][s8*8] = *(const uint4*)src;
  }
  __syncthreads();
  const unsigned short* WT = ((g==0)? WnsT : WnvT) + (size_t)ntc*128*128;
  f32x4 acc[8];
  #pragma unroll
  for (int t=0;t<8;t++) acc[t]=(f32x4)(0.f);
  #pragma unroll
  for (int kb=0;kb<4;kb++){
    bf16x8 a = *(const bf16x8*)&fA[m0+lr][kb*32 + lg*8];
    #pragma unroll
    for (int t=0;t<8;t++){
      bf16x8 b = *(const bf16x8*)&WT[(size_t)(t*16+lr)*128 + kb*32 + lg*8];
      acc[t] = __builtin_amdgcn_mfma_f32_16x16x32_bf16(a, b, acc[t], 0,0,0);
    }
  }
  #pragma unroll
  for (int t=0;t<8;t++){
    #pragma unroll
    for (int r=0;r<4;r++){
      int col = (ntc*8+t)*16 + lr;
      int row = m0 + lg*4 + r;
      int n = nb + row;
      if (n < NN){
        float v = acc[t][r];
        if (g==0){
          if (col < 128)      out_sc[(size_t)n*512 + col] = v;
          else if (col < 256){
            int cc = col-128;
            upk16[(size_t)n*512 + (cc&63)*8 + (cc>>6)] = f2bh(v);
          } else              res_s[(size_t)n*256 + col-256] = v;
        } else {
          int i = g-1;
          if (col < 128)      out_sc[(size_t)n*512 + 128 + col*3 + i] = v;
          else if (col < 256){
            int cc = col-128;
            upk16[(size_t)n*512 + (cc&63)*8 + (1+i)*2 + (cc>>6)] = f2bh(v);
          } else              res_v[((size_t)n*3+i)*128 + col-256] = v;
        }
      }
    }
  }
}

// ---------------- CSR build ----------------
__global__ __launch_bounds__(256) void k_deg(const int* __restrict__ eidx, int* __restrict__ deg){
  int i = blockIdx.x*256+threadIdx.x;
  if (i<NE) atomicAdd(&deg[eidx[2*i+1]],1);
}
__global__ __launch_bounds__(256) void k_scan(const int* __restrict__ deg, int* __restrict__ offsets){
  __shared__ int part[256];
  int t = threadIdx.x; int base = t*40;
  int s=0;
  for (int k=0;k<40;k++){ int idx=base+k; if (idx<NN) s+=deg[idx]; }
  part[t]=s; __syncthreads();
  if (t==0){ int run=0; for (int i=0;i<256;i++){ int v=part[i]; part[i]=run; run+=v; } }
  __syncthreads();
  int run = part[t];
  for (int k=0;k<40;k++){
    int idx=base+k;
    if (idx<=NN) offsets[idx]=run;
    if (idx<NN) run+=deg[idx];
  }
}
// fill: materialize CSR-ordered edge data
__global__ __launch_bounds__(256) void k_fill(
    const int* __restrict__ eidx, const float* __restrict__ ef, const float* __restrict__ ea,
    const int* __restrict__ offsets, int* __restrict__ cursor,
    int* __restrict__ sndbuf, int* __restrict__ rcvbuf,
    float4* __restrict__ ybuf, float* __restrict__ efb){
  int i = blockIdx.x*256+threadIdx.x;
  if (i<NE){
    int sn = eidx[2*i], rc = eidx[2*i+1];
    int p = offsets[rc] + atomicAdd(&cursor[rc],1);
    sndbuf[p]=sn; rcvbuf[p]=rc;
    ybuf[p] = ((const float4*)ea)[i];
    *(float4*)&efb[(size_t)p*8]     = *(const float4*)&ef[(size_t)i*8];
    *(float4*)&efb[(size_t)p*8 + 4] = *(const float4*)&ef[(size_t)i*8 + 4];
  }
}

// ---------------- K2: edge MLP, 32 edges/wave, 2-wave blocks (64 edges/block) --------
__global__ __launch_bounds__(128) void k_tpw(
    const int* __restrict__ sndbuf, const int* __restrict__ rcvbuf,
    const float* __restrict__ efb,
    const float* __restrict__ pA, const float* __restrict__ pB,
    const float* __restrict__ Wr1, const float* __restrict__ Wd1, const float* __restrict__ Wd2,
    const unsigned short* __restrict__ WTr2, const unsigned short* __restrict__ WTr3,
    const unsigned short* __restrict__ WTr4,
    const int* __restrict__ offsets, int nstart, int nend, int cap,
    unsigned* __restrict__ tpwp, float* __restrict__ densbuf){
  __shared__ unsigned short hS[64][72];   // single buffer: layers run in place
  int ebase = offsets[nstart];
  int eend  = min(offsets[nend], ebase + cap);
  int i0 = ebase + blockIdx.x*64;
  if (i0 >= eend) return;
  int nrows = min(64, eend - i0);
  int tid = threadIdx.x;
  int w = tid>>6, l = tid&63, m0 = w*32, lr = l&15, lg = l>>4;
  int wbase = i0 + m0;
  // metadata: lane l<32 snd, l>=32 rcv (32 edges)
  int v_meta;
  {
    int pos = min(wbase + (l&31), eend-1);
    v_meta = (l < 32) ? sndbuf[pos] : rcvbuf[pos];
  }
  // ef regs: rq holds ef[edge=l&31][k = 2q + (l>>5)]
  float r0,r1,r2,r3;
  {
    int pos = min(wbase + (l&31), eend-1);
    int hi = l>>5;
    r0 = efb[(size_t)pos*8 + 0 + hi];
    r1 = efb[(size_t)pos*8 + 2 + hi];
    r2 = efb[(size_t)pos*8 + 4 + hi];
    r3 = efb[(size_t)pos*8 + 6 + hi];
  }
  // ---- layer1 (VALU, f32), 32 rows ----
  {
    float wr[8], wd[8];
    #pragma unroll
    for (int k=0;k<8;k++){ wr[k]=Wr1[k*64+l]; wd[k]=Wd1[k*64+l]; }
    float wd2c = Wd2[l];
    #pragma unroll
    for (int j=0;j<32;j++){
      int sn = __shfl(v_meta, j);
      int rc = __shfl(v_meta, 32+j);
      float2 av = *(const float2*)&pA[(size_t)sn*128 + l*2];
      float2 bv = *(const float2*)&pB[(size_t)rc*128 + l*2];
      float e0=__shfl(r0,j), e1=__shfl(r0,32+j);
      float e2=__shfl(r1,j), e3=__shfl(r1,32+j);
      float e4=__shfl(r2,j), e5=__shfl(r2,32+j);
      float e6=__shfl(r3,j), e7=__shfl(r3,32+j);
      float h  = av.x + bv.x;
      float hd = av.y + bv.y;
      h  += e0*wr[0]+e1*wr[1]+e2*wr[2]+e3*wr[3]+e4*wr[4]+e5*wr[5]+e6*wr[6]+e7*wr[7];
      hd += e0*wd[0]+e1*wd[1]+e2*wd[2]+e3*wd[3]+e4*wd[4]+e5*wd[5]+e6*wd[6]+e7*wd[7];
      hS[m0+j][l] = f2bh(silu_f(h));
      float sv = silu_f(hd)*wd2c;
      #pragma unroll
      for (int m=32;m;m>>=1) sv += __shfl_xor(sv, m);
      if (l==0 && m0+j < nrows) densbuf[wbase + j] = tanhf(sv*sv);
    }
  }
  // ---- layer2: in-place (A hoisted to regs first; wave-private rows) ----
  {
    bf16x8 a0[2], a1[2];
    #pragma unroll
    for (int kb=0;kb<2;kb++){
      a0[kb] = *(const bf16x8*)&hS[m0+lr][kb*32 + lg*8];
      a1[kb] = *(const bf16x8*)&hS[m0+16+lr][kb*32 + lg*8];
    }
    #pragma unroll
    for (int nt=0;nt<4;nt++){
      f32x4 c0=(f32x4)(0.f), c1=(f32x4)(0.f);
      #pragma unroll
      for (int kb=0;kb<2;kb++){
        bf16x8 b = *(const bf16x8*)&WTr2[(nt*16+lr)*64 + kb*32 + lg*8];
        c0 = __builtin_amdgcn_mfma_f32_16x16x32_bf16(a0[kb], b, c0, 0,0,0);
        c1 = __builtin_amdgcn_mfma_f32_16x16x32_bf16(a1[kb], b, c1, 0,0,0);
      }
      #pragma unroll
      for (int r=0;r<4;r++){
        hS[m0+lg*4+r][nt*16+lr]    = f2bh(silu_f(c0[r]));
        hS[m0+16+lg*4+r][nt*16+lr] = f2bh(silu_f(c1[r]));
      }
    }
  }
  // ---- layer3: in-place ----
  {
    bf16x8 a0[2], a1[2];
    #pragma unroll
    for (int kb=0;kb<2;kb++){
      a0[kb] = *(const bf16x8*)&hS[m0+lr][kb*32 + lg*8];
      a1[kb] = *(const bf16x8*)&hS[m0+16+lr][kb*32 + lg*8];
    }
    #pragma unroll
    for (int nt=0;nt<4;nt++){
      f32x4 c0=(f32x4)(0.f), c1=(f32x4)(0.f);
      #pragma unroll
      for (int kb=0;kb<2;kb++){
        bf16x8 b = *(const bf16x8*)&WTr3[(nt*16+lr)*64 + kb*32 + lg*8];
        c0 = __builtin_amdgcn_mfma_f32_16x16x32_bf16(a0[kb], b, c0, 0,0,0);
        c1 = __builtin_amdgcn_mfma_f32_16x16x32_bf16(a1[kb], b, c1, 0,0,0);
      }
      #pragma unroll
      for (int r=0;r<4;r++){
        hS[m0+lg*4+r][nt*16+lr]    = f2bh(silu_f(c0[r]));
        hS[m0+16+lg*4+r][nt*16+lr] = f2bh(silu_f(c1[r]));
      }
    }
  }
  // ---- layer4: A-hoisted, B reused across the two batches, packed u32 out ----
  {
    bf16x8 a0[2], a1[2];
    #pragma unroll
    for (int kb=0;kb<2;kb++){
      a0[kb] = *(const bf16x8*)&hS[m0+lr][kb*32 + lg*8];
      a1[kb] = *(const bf16x8*)&hS[m0+16+lr][kb*32 + lg*8];
    }
    int erow0 = i0 - ebase;
    #pragma unroll
    for (int nt=0; nt<4; nt++){
      unsigned pv0[4][4], pv1[4][4];   // [r][G]
      #pragma unroll
      for (int G=0; G<4; G++){
        f32x4 e0=(f32x4)(0.f), o0=(f32x4)(0.f), e1=(f32x4)(0.f), o1=(f32x4)(0.f);
        #pragma unroll
        for (int kb=0; kb<2; kb++){
          bf16x8 bE = *(const bf16x8*)&WTr4[((2*G)*64+nt*16+lr)*64 + kb*32 + lg*8];
          bf16x8 bO = *(const bf16x8*)&WTr4[((2*G+1)*64+nt*16+lr)*64 + kb*32 + lg*8];
          e0 = __builtin_amdgcn_mfma_f32_16x16x32_bf16(a0[kb], bE, e0, 0,0,0);
          o0 = __builtin_amdgcn_mfma_f32_16x16x32_bf16(a0[kb], bO, o0, 0,0,0);
          e1 = __builtin_amdgcn_mfma_f32_16x16x32_bf16(a1[kb], bE, e1, 0,0,0);
          o1 = __builtin_amdgcn_mfma_f32_16x16x32_bf16(a1[kb], bO, o1, 0,0,0);
        }
        #pragma unroll
        for (int r=0;r<4;r++){
          pv0[r][G] = f2b2(e0[r], o0[r]);
          pv1[r][G] = f2b2(e1[r], o1[r]);
        }
      }
      #pragma unroll
      for (int r=0;r<4;r++){
        int row0 = m0 + lg*4 + r;
        int row1 = m0 + 16 + lg*4 + r;
        if (row0 < nrows)
          *(uint4*)&tpwp[(size_t)(erow0+row0)*256 + (nt*16+lr)*4] = *(uint4*)&pv0[r][0];
        if (row1 < nrows)
          *(uint4*)&tpwp[(size_t)(erow0+row1)*256 + (nt*16+lr)*4] = *(uint4*)&pv1[r][0];
      }
    }
  }
}

// ---------------- K3: CSR gather — 4 waves per node (1 block/node), LDS combine ------
__global__ __launch_bounds__(256) void k_gather(
    const unsigned* __restrict__ tpwp, const float4* __restrict__ ybuf,
    const int* __restrict__ sndbuf, const float* __restrict__ densbuf,
    const uint4* __restrict__ upk4,
    const int* __restrict__ offsets, int nstart,
    unsigned short* __restrict__ msg_s16, unsigned short* __restrict__ msg_v16,
    float* __restrict__ density){
  __shared__ float part[3][1024];
  __shared__ float pden[3];
  int w = threadIdx.x>>6, l = threadIdx.x&63;
  int n = nstart + blockIdx.x;
  int ebase = offsets[nstart];
  int s0 = offsets[n], s1 = offsets[n+1];
  float mA0=0,mA1=0,mD0=0,mD1=0;
  float mB00=0,mB01=0,mB10=0,mB11=0,mB20=0,mB21=0;
  float mC00=0,mC01=0,mC10=0,mC11=0,mC20=0,mC21=0;
  float dsum=0;
  #pragma unroll 2
  for (int i=s0+w; i<s1; i+=4){
    int li = i - ebase;
    int sn = sndbuf[i];
    float4 y = ybuf[i];
    dsum += densbuf[i];
    uint4 tq = *(const uint4*)&tpwp[(size_t)li*256 + l*4];
    uint4 uq = upk4[(size_t)sn*64 + l];
    float wA0=b2f_lo(tq.x), wA1=b2f_hi(tq.x);
    float wB0=b2f_lo(tq.y), wB1=b2f_hi(tq.y);
    float wC0=b2f_lo(tq.z), wC1=b2f_hi(tq.z);
    float wD0=b2f_lo(tq.w), wD1=b2f_hi(tq.w);
    float xs0=b2f_lo(uq.x), xs1=b2f_hi(uq.x);
    float xv00=b2f_lo(uq.y), xv01=b2f_hi(uq.y);
    float xv10=b2f_lo(uq.z), xv11=b2f_hi(uq.z);
    float xv20=b2f_lo(uq.w), xv21=b2f_hi(uq.w);
    mA0 += wA0*xs0*y.x; mA1 += wA1*xs1*y.x;
    float dot0 = xv00*y.y + xv10*y.z + xv20*y.w;
    float dot1 = xv01*y.y + xv11*y.z + xv21*y.w;
    mD0 += wD0*dot0; mD1 += wD1*dot1;
    float b0 = wB0*xs0, b1 = wB1*xs1;
    mB00 += b0*y.y; mB01 += b1*y.y;
    mB10 += b0*y.z; mB11 += b1*y.z;
    mB20 += b0*y.w; mB21 += b1*y.w;
    float c0 = wC0*y.x, c1 = wC1*y.x;
    mC00 += c0*xv00; mC01 += c1*xv01;
    mC10 += c0*xv10; mC11 += c1*xv11;
    mC20 += c0*xv20; mC21 += c1*xv21;
  }
  if (w){
    float* P = part[w-1];
    P[0*64+l]=mA0;  P[1*64+l]=mA1;  P[2*64+l]=mD0;  P[3*64+l]=mD1;
    P[4*64+l]=mB00; P[5*64+l]=mB01; P[6*64+l]=mB10; P[7*64+l]=mB11;
    P[8*64+l]=mB20; P[9*64+l]=mB21; P[10*64+l]=mC00; P[11*64+l]=mC01;
    P[12*64+l]=mC10; P[13*64+l]=mC11; P[14*64+l]=mC20; P[15*64+l]=mC21;
    if (l==0) pden[w-1]=dsum;
  }
  __syncthreads();
  if (w==0){
    #pragma unroll
    for (int q=0;q<3;q++){
      const float* P = part[q];
      mA0+=P[0*64+l];  mA1+=P[1*64+l];  mD0+=P[2*64+l];  mD1+=P[3*64+l];
      mB00+=P[4*64+l]; mB01+=P[5*64+l]; mB10+=P[6*64+l]; mB11+=P[7*64+l];
      mB20+=P[8*64+l]; mB21+=P[9*64+l]; mC00+=P[10*64+l]; mC01+=P[11*64+l];
      mC10+=P[12*64+l]; mC11+=P[13*64+l]; mC20+=P[14*64+l]; mC21+=P[15*64+l];
    }
    dsum += pden[0]+pden[1]+pden[2];
    unsigned short* ms = msg_s16 + (size_t)n*256;
    ms[l]=f2bh(mA0); ms[64+l]=f2bh(mA1);
    ms[128+l]=f2bh(mD0*INV_SQRT3); ms[192+l]=f2bh(mD1*INV_SQRT3);
    unsigned short* mv = msg_v16 + (size_t)n*768;
    mv[l]=f2bh(mB00);     mv[64+l]=f2bh(mB01);  mv[128+l]=f2bh(mC00); mv[192+l]=f2bh(mC01);
    mv[256+l]=f2bh(mB10); mv[320+l]=f2bh(mB11); mv[384+l]=f2bh(mC10); mv[448+l]=f2bh(mC11);
    mv[512+l]=f2bh(mB20); mv[576+l]=f2bh(mB21); mv[640+l]=f2bh(mC20); mv[704+l]=f2bh(mC21);
    if (l==0) density[n]=dsum;
  }
}

// ---------------- K4a: lin1 for all 5 N=128 chunks. grid (NB64, 5) ----------------
__global__ __launch_bounds__(256) void k_post1(
    const unsigned short* __restrict__ msg_s16, const unsigned short* __restrict__ msg_v16,
    const float* __restrict__ density,
    const float* __restrict__ res_s, const float* __restrict__ res_v,
    const unsigned short* __restrict__ Wl10T, const unsigned short* __restrict__ Wl11T,
    const float* __restrict__ alphap, const float* __restrict__ betap,
    unsigned short* __restrict__ scal16, unsigned short* __restrict__ gate16,
    unsigned short* __restrict__ vtmp16){
  __shared__ unsigned short sm[64][264];
  __shared__ float sden[64];
  int nb = blockIdx.x*64, y = blockIdx.y;
  int tid = threadIdx.x;
  int w = tid>>6, l = tid&63, m0 = w*16, lr = l&15, lg = l>>4;
  for (int idx=tid; idx<64*32; idx+=256){
    int row = idx>>5, s8 = idx&31;
    int n = min(nb+row, NN-1);
    const unsigned short* src = (y<2)? &msg_s16[(size_t)n*256 + s8*8]
                                     : &msg_v16[(size_t)n*768 + (y-2)*256 + s8*8];
    *(uint4*)&sm[row][s8*8] = *(const uint4*)src;
  }
  if (tid < 64){
    int n = min(nb+tid, NN-1);
    sden[tid] = density[n]*betap[0] + alphap[0]*20.0f;
  }
  __syncthreads();
  const unsigned short* BT = (y<2)? (Wl10T + (size_t)y*128*256) : Wl11T;
  f32x4 acc[8];
  #pragma unroll
  for (int t=0;t<8;t++) acc[t]=(f32x4)(0.f);
  for (int kb=0;kb<8;kb++){
    bf16x8 a = *(const bf16x8*)&sm[m0+lr][kb*32 + lg*8];
    #pragma unroll
    for (int t=0;t<8;t++){
      bf16x8 b = *(const bf16x8*)&BT[(size_t)(t*16+lr)*256 + kb*32 + lg*8];
      acc[t] = __builtin_amdgcn_mfma_f32_16x16x32_bf16(a, b, acc[t], 0,0,0);
    }
  }
  #pragma unroll
  for (int t=0;t<8;t++){
    #pragma unroll
    for (int r=0;r<4;r++){
      int col = t*16+lr;
      int row = m0 + lg*4 + r;
      int n = nb + row;
      if (n < NN){
        float v = acc[t][r]/sden[row];
        if (y==0){
          v += res_s[(size_t)n*256 + col];
          scal16[(size_t)n*128 + col] = f2bh(silu_f(v));
        } else if (y==1){
          v += res_s[(size_t)n*256 + 128 + col];
          gate16[(size_t)n*128 + col] = f2bh(sigmoid_f(v));
        } else {
          int i = y-2;
          v += res_v[((size_t)n*3+i)*128 + col];
          vtmp16[((size_t)i*NN + n)*128 + col] = f2bh(v);
        }
      }
    }
  }
}

// ---------------- K4b: lin2 for 4 output components. grid (NB64, 4) ----------------
__global__ __launch_bounds__(256) void k_post2(
    const unsigned short* __restrict__ scal16, const unsigned short* __restrict__ gate16,
    const unsigned short* __restrict__ vtmp16,
    const unsigned short* __restrict__ Wl20T, const unsigned short* __restrict__ Wl21T,
    float* __restrict__ out_msg){
  __shared__ unsigned short sA[64][136];
  int nb = blockIdx.x*64, y = blockIdx.y;
  int tid = threadIdx.x;
  int w = tid>>6, l = tid&63, m0 = w*16, lr = l&15, lg = l>>4;
  for (int idx=tid; idx<64*16; idx+=256){
    int row = idx>>4, s8 = idx&15;
    int n = min(nb+row, NN-1);
    if (y==0){
      *(uint4*)&sA[row][s8*8] = *(const uint4*)&scal16[(size_t)n*128 + s8*8];
    } else {
      int i = y-1;
      uint4 va = *(const uint4*)&vtmp16[((size_t)i*NN + n)*128 + s8*8];
      uint4 vg = *(const uint4*)&gate16[(size_t)n*128 + s8*8];
      const unsigned short* pa = (const unsigned short*)&va;
      const unsigned short* pg = (const unsigned short*)&vg;
      unsigned short o[8];
      #pragma unroll
      for (int j=0;j<8;j++) o[j] = f2bh(b2f(pa[j])*b2f(pg[j]));
      *(uint4*)&sA[row][s8*8] = *(const uint4*)o;
    }
  }
  __syncthreads();
  const unsigned short* BT = (y==0)? Wl20T : Wl21T;
  f32x4 acc[8];
  #pragma unroll
  for (int t=0;t<8;t++) acc[t]=(f32x4)(0.f);
  #pragma unroll
  for (int kb=0;kb<4;kb++){
    bf16x8 a = *(const bf16x8*)&sA[m0+lr][kb*32 + lg*8];
    #pragma unroll
    for (int t=0;t<8;t++){
      bf16x8 b = *(const bf16x8*)&BT[(size_t)(t*16+lr)*128 + kb*32 + lg*8];
      acc[t] = __builtin_amdgcn_mfma_f32_16x16x32_bf16(a, b, acc[t], 0,0,0);
    }
  }
  #pragma unroll
  for (int t=0;t<8;t++){
    #pragma unroll
    for (int r=0;r<4;r++){
      int col = t*16+lr;
      int n = nb + m0 + lg*4 + r;
      if (n < NN) out_msg[(size_t)n*512 + col*4 + y] = acc[t][r];
    }
  }
}

extern "C" void kernel_launch(void* const* d_in, const int* in_sizes, int n_in,
                              void* d_out, int out_size, void* d_ws, size_t ws_size,
                              hipStream_t stream){
  (void)in_sizes; (void)n_in; (void)out_size;
  const float* attrs = (const float*)d_in[0];
  const float* feats = (const float*)d_in[1];
  const float* ea    = (const float*)d_in[2];
  const float* ef    = (const float*)d_in[3];
  const float* Wsrc  = (const float*)d_in[4];
  const float* Wtgt  = (const float*)d_in[5];
  const float* Wup0  = (const float*)d_in[6];
  const float* Wup1  = (const float*)d_in[7];
  const float* Wsk0  = (const float*)d_in[8];
  const float* Wsk1  = (const float*)d_in[9];
  const float* Wres0 = (const float*)d_in[10];
  const float* Wres1 = (const float*)d_in[11];
  const float* Wl10  = (const float*)d_in[12];
  const float* Wl11  = (const float*)d_in[13];
  const float* Wl20  = (const float*)d_in[14];
  const float* Wl21  = (const float*)d_in[15];
  const float* Wr1   = (const float*)d_in[16];
  const float* Wr2   = (const float*)d_in[17];
  const float* Wr3   = (const float*)d_in[18];
  const float* Wr4   = (const float*)d_in[19];
  const float* Wd1   = (const float*)d_in[20];
  const float* Wd2   = (const float*)d_in[21];
  const float* alphap= (const float*)d_in[22];
  const float* betap = (const float*)d_in[23];
  const int*   eidx  = (const int*)d_in[24];

  const size_t fixed_bytes =
      (size_t)NN*(512 + 1536 + 1024 + 1536 + 4 + 1024 + 256 + 768 + 512 + 512 + 256) +
      (size_t)NE*60 +
      (size_t)286976*2 + 4*ADIM*64*4 +
      (10240+10240+10256)*4 + 64*256;
  int nchunk, npc, cap;
  if (fixed_bytes + (size_t)NE*1024 + 65536 <= ws_size){ nchunk=1; npc=NN;   cap=NE;    }
  else if (fixed_bytes + 81920ULL*1024 + 65536 <= ws_size){ nchunk=2; npc=5000; cap=81920; }
  else { nchunk=4; npc=2500; cap=44032; }

  char* p = (char*)d_ws;
  auto alloc = [&](size_t bytes)->char*{ char* r=p; p += (bytes+255)&~(size_t)255; return r; };
  unsigned* tpwp  = (unsigned*)alloc((size_t)cap*256*4);
  unsigned short* msg_s16 = (unsigned short*)alloc((size_t)NN*256*2);
  unsigned short* msg_v16 = (unsigned short*)alloc((size_t)NN*768*2);
  float*  res_s   = (float*)alloc((size_t)NN*256*4);
  float*  res_v   = (float*)alloc((size_t)NN*384*4);
  float*  density = (float*)alloc((size_t)NN*4);
  float4* ybuf    = (float4*)alloc((size_t)NE*16);
  float*  densbuf = (float*)alloc((size_t)NE*4);
  int*    sndbuf  = (int*)alloc((size_t)NE*4);
  int*    rcvbuf  = (int*)alloc((size_t)NE*4);
  float*  efb     = (float*)alloc((size_t)NE*32);
  uint4*  upk     = (uint4*)alloc((size_t)NN*64*16);
  unsigned short* fs16 = (unsigned short*)alloc((size_t)NN*128*2);
  unsigned short* fv16 = (unsigned short*)alloc((size_t)NN*384*2);
  float* pA = (float*)alloc((size_t)NN*128*4);
  float* pB = (float*)alloc((size_t)NN*128*4);
  float* Wc  = (float*)alloc(4*ADIM*64*4);
  unsigned short* gate16 = (unsigned short*)alloc((size_t)NN*128*2);
  unsigned short* WTr2 = (unsigned short*)alloc(4096*2);
  unsigned short* WTr3 = (unsigned short*)alloc(4096*2);
  unsigned short* WTr4 = (unsigned short*)alloc(32768*2);
  unsigned short* Wl10T = (unsigned short*)alloc(65536*2);
  unsigned short* Wl11T = (unsigned short*)alloc(32768*2);
  unsigned short* Wl20T = (unsigned short*)alloc(16384*2);
  unsigned short* Wl21T = (unsigned short*)alloc(16384*2);
  unsigned short* WnsT  = (unsigned short*)alloc(65536*2);
  unsigned short* WnvT  = (unsigned short*)alloc(49152*2);
  int* deg     = (int*)alloc(10240*4);
  int* cursor  = (int*)alloc(10240*4);
  int* offsets = (int*)alloc(10256*4);

  unsigned short* scal16 = fs16;   // NN*128, fs16 dead after k_node_pre2
  unsigned short* vtmp16 = fv16;   // 3*NN*128, fv16 dead after k_node_pre2

  float* out_msg = (float*)d_out;               // NN*512
  float* out_sc  = out_msg + (size_t)NN*512;    // NN*512

  hipMemsetAsync(deg, 0, 2*10240*sizeof(int), stream);

  k_prep<<<1121, 256, 0, stream>>>(Wr2, Wr3, Wr4, Wl10, Wl11, Wl20, Wl21,
                                   Wsk0, Wup0, Wres0, Wsk1, Wup1, Wres1,
                                   Wsrc, Wtgt, Wr1, Wd1,
                                   WTr2, WTr3, WTr4,
                                   Wl10T, Wl11T, Wl20T, Wl21T, WnsT, WnvT, Wc);
  k_nodeemb<<<(NN*64+255)/256, 256, 0, stream>>>(attrs, Wc, pA, pB);
  k_feat_prep<<<NN*512/256, 256, 0, stream>>>(feats, fs16, fv16);
  k_node_pre2<<<dim3(NB64,13), 256, 0, stream>>>(fs16, fv16, WnsT, WnvT,
                                                 out_sc, (unsigned short*)upk, res_s, res_v);
  k_deg<<<(NE+255)/256, 256, 0, stream>>>(eidx, deg);
  k_scan<<<1, 256, 0, stream>>>(deg, offsets);
  k_fill<<<(NE+255)/256, 256, 0, stream>>>(eidx, ef, ea, offsets, cursor,
                                           sndbuf, rcvbuf, ybuf, efb);

  int tpw_blocks = (cap+63)/64;
  for (int c=0; c<nchunk; ++c){
    k_tpw<<<tpw_blocks, 128, 0, stream>>>(sndbuf, rcvbuf, efb, pA, pB,
                                          Wr1, Wd1, Wd2, WTr2, WTr3, WTr4,
                                          offsets, c*npc, (c+1)*npc, cap,
                                          tpwp, densbuf);
    k_gather<<<npc, 256, 0, stream>>>(tpwp, ybuf, sndbuf, densbuf, upk,
                                      offsets, c*npc, msg_s16, msg_v16, density);
  }

  k_post1<<<dim3(NB64,5), 256, 0, stream>>>(msg_s16, msg_v16, density, res_s, res_v,
                                            Wl10T, Wl11T, alphap, betap,
                                            scal16, gate16, vtmp16);
  k_post2<<<dim3(NB64,4), 256, 0, stream>>>(scal16, gate16, vtmp16,
                                            Wl20T, Wl21T, out_msg);
}

// Round 16
// 407.290 us; speedup vs baseline: 1.1445x; 1.0237x over previous
//
#include <hip/hip_runtime.h>
#include <hip/hip_bf16.h>
#include <math.h>

#define NN 10000
#define NE 160000
#define MUL 128
#define ADIM 10
#define RADF 8
#define HID 64
#define INV_SQRT3 0.57735026918962576f
#define NB64 157           // ceil(NN/64)

typedef __attribute__((ext_vector_type(8))) short bf16x8;
typedef __attribute__((ext_vector_type(4))) float f32x4;

__device__ __forceinline__ float silu_f(float x){ return x / (1.0f + __expf(-x)); }
__device__ __forceinline__ float sigmoid_f(float x){ return 1.0f / (1.0f + __expf(-x)); }
// legacy manual RNE (cold prep kernels)
__device__ __forceinline__ unsigned short f2b(float f){
  union{float f; unsigned u;} v; v.f=f;
  unsigned r = (v.u + 0x7fffu + ((v.u>>16)&1u))>>16;
  return (unsigned short)r;
}
// hot-path: native HW converts
__device__ __forceinline__ unsigned short f2bh(float f){
  __hip_bfloat16 h = __float2bfloat16(f);
  union{ __hip_bfloat16 h; unsigned short u; } v; v.h=h; return v.u;
}
__device__ __forceinline__ unsigned f2b2(float lo, float hi){
  float2 t; t.x=lo; t.y=hi;
  __hip_bfloat162 h2 = __float22bfloat162_rn(t);
  union{ __hip_bfloat162 h; unsigned u; } v; v.h=h2; return v.u;
}
__device__ __forceinline__ float b2f(unsigned short h){
  union{unsigned u; float f;} v; v.u = ((unsigned)h)<<16; return v.f;
}
__device__ __forceinline__ float b2f_lo(unsigned u){
  union{unsigned u; float f;} v; v.u = u<<16; return v.f;
}
__device__ __forceinline__ float b2f_hi(unsigned u){
  union{unsigned u; float f;} v; v.u = u & 0xffff0000u; return v.f;
}

// ---------------- merged: per-node layer1 partials + feat prep ----------------
__global__ __launch_bounds__(256) void k_nf(
    const float* __restrict__ attrs, const float* __restrict__ Wc,
    float* __restrict__ pA, float* __restrict__ pB,
    const float* __restrict__ feats, unsigned short* __restrict__ fs16,
    unsigned short* __restrict__ fv16){
  int b = blockIdx.x;
  if (b < 2500){
    int idx = b*256 + threadIdx.x;
    if (idx >= NN*64) return;
    int n = idx>>6, c = idx&63;
    float s0=0,s1=0,s2=0,s3=0;
    #pragma unroll
    for (int a=0;a<ADIM;a++){
      float x = attrs[n*ADIM+a];
      s0 += x*Wc[(0*ADIM+a)*64+c];
      s1 += x*Wc[(1*ADIM+a)*64+c];
      s2 += x*Wc[(2*ADIM+a)*64+c];
      s3 += x*Wc[(3*ADIM+a)*64+c];
    }
    pA[(size_t)n*128 + c*2 + 0] = s0;
    pA[(size_t)n*128 + c*2 + 1] = s2;
    pB[(size_t)n*128 + c*2 + 0] = s1;
    pB[(size_t)n*128 + c*2 + 1] = s3;
  } else {
    int idx = (b-2500)*256 + threadIdx.x;   // over NN*512
    int n = idx >> 9, c = idx & 511;
    float v = feats[idx];
    if (c < 128) fs16[n*128 + c] = f2bh(v);
    else {
      int q = c - 128; int u = q/3; int i = q - 3*u;
      fv16[((size_t)n*3 + i)*128 + u] = f2bh(v);
    }
  }
}

// ---------------- weight prep: transpose + bf16 cast (+ wcomb merged) ----------------
__global__ __launch_bounds__(256) void k_prep(
    const float* __restrict__ Wr2, const float* __restrict__ Wr3,
    const float* __restrict__ Wr4,
    const float* __restrict__ Wl10, const float* __restrict__ Wl11,
    const float* __restrict__ Wl20, const float* __restrict__ Wl21,
    const float* __restrict__ Wsk0, const float* __restrict__ Wup0, const float* __restrict__ Wres0,
    const float* __restrict__ Wsk1, const float* __restrict__ Wup1, const float* __restrict__ Wres1,
    const float* __restrict__ Wsrc, const float* __restrict__ Wtgt,
    const float* __restrict__ Wr1, const float* __restrict__ Wd1,
    unsigned short* __restrict__ WTr2, unsigned short* __restrict__ WTr3,
    unsigned short* __restrict__ WTr4,
    unsigned short* __restrict__ Wl10T, unsigned short* __restrict__ Wl11T,
    unsigned short* __restrict__ Wl20T, unsigned short* __restrict__ Wl21T,
    unsigned short* __restrict__ WnsT, unsigned short* __restrict__ WnvT,
    float* __restrict__ Wc){
  int idx = blockIdx.x*256 + threadIdx.x;
  if (idx < 4096){
    int j = idx; int n=j>>6, k=j&63;
    WTr2[j] = f2b(Wr2[k*64+n]);
  } else if (idx < 8192){
    int j = idx-4096; int n=j>>6, k=j&63;
    WTr3[j] = f2b(Wr3[k*64+n]);
  } else if (idx < 40960){
    int j = idx-8192; int n=j>>6, k=j&63;
    WTr4[j] = f2b(Wr4[k*512+n]);
  } else if (idx < 106496){
    int j = idx-40960; int n=j>>8, k=j&255;
    Wl10T[j] = f2b(Wl10[k*256+n]);
  } else if (idx < 139264){
    int j = idx-106496; int n=j>>8, k=j&255;
    Wl11T[j] = f2b(Wl11[k*128+n]);
  } else if (idx < 155648){
    int j = idx-139264; int n=j>>7, k=j&127;
    Wl20T[j] = f2b(Wl20[k*128+n]);
  } else if (idx < 172032){
    int j = idx-155648; int n=j>>7, k=j&127;
    Wl21T[j] = f2b(Wl21[k*128+n]);
  } else if (idx < 237568){
    int j = idx-172032; int n=j>>7, k=j&127;
    float v;
    if (n < 128)      v = Wsk0[k*128+n];
    else if (n < 256) v = Wup0[k*128+(n-128)];
    else              v = Wres0[k*256+(n-256)];
    WnsT[j] = f2b(v);
  } else if (idx < 286720){
    int j = idx-237568; int n=j>>7, k=j&127;
    float v;
    if (n < 128)      v = Wsk1[k*128+n];
    else if (n < 256) v = Wup1[k*128+(n-128)];
    else              v = Wres1[k*128+(n-256)];
    WnvT[j] = f2b(v);
  } else if (idx < 286976){
    int j = idx - 286720;      // wcomb: Wc[m][10][64]
    int m = j>>6, c = j&63;
    const float* WA = (m&1)? Wtgt : Wsrc;
    const float* WB = (m<2)? Wr1 : Wd1;
    int koff = (m&1)? 136 : 8;
    for (int a=0;a<ADIM;a++){
      float s=0.f;
      for (int k=0;k<128;k++) s += WA[a*128+k]*WB[(koff+k)*64+c];
      Wc[(m*ADIM+a)*64+c] = s;
    }
  }
}

// ---------------- K1: per-node precompute via MFMA ----------------
__global__ __launch_bounds__(256) void k_node_pre2(
    const unsigned short* __restrict__ fs16, const unsigned short* __restrict__ fv16,
    const unsigned short* __restrict__ WnsT, const unsigned short* __restrict__ WnvT,
    float* __restrict__ out_sc,
    unsigned short* __restrict__ upk16,
    float* __restrict__ res_s, float* __restrict__ res_v){
  __shared__ unsigned short fA[64][136];
  int nb = blockIdx.x*64;
  int c = blockIdx.y;
  int g, ntc;
  if (c < 4){ g=0; ntc=c; } else { g = 1 + (c-4)/3; ntc = (c-4)%3; }
  int tid = threadIdx.x;
  int w = tid>>6, l = tid&63, m0 = w*16, lr = l&15, lg = l>>4;
  for (int idx=tid; idx<64*16; idx+=256){
    int row = idx>>4, s8 = idx&15;
    int n = min(nb+row, NN-1);
    const unsigned short* src = (g==0) ? &fs16[(size_t)n*128 + s8*8]
                                       : &fv16[((size_t)n*3 + (g-1))*128 + s8*8];
    *(uint4*)&fA[row][s8*8] = *(const uint4*)src;
  }
  __syncthreads();
  const unsigned short* WT = ((g==0)? WnsT : WnvT) + (size_t)ntc*128*128;
  f32x4 acc[8];
  #pragma unroll
  for (int t=0;t<8;t++) acc[t]=(f32x4)(0.f);
  #pragma unroll
  for (int kb=0;kb<4;kb++){
    bf16x8 a = *(const bf16x8*)&fA[m0+lr][kb*32 + lg*8];
    #pragma unroll
    for (int t=0;t<8;t++){
      bf16x8 b = *(const bf16x8*)&WT[(size_t)(t*16+lr)*128 + kb*32 + lg*8];
      acc[t] = __builtin_amdgcn_mfma_f32_16x16x32_bf16(a, b, acc[t], 0,0,0);
    }
  }
  #pragma unroll
  for (int t=0;t<8;t++){
    #pragma unroll
    for (int r=0;r<4;r++){
      int col = (ntc*8+t)*16 + lr;
      int row = m0 + lg*4 + r;
      int n = nb + row;
      if (n < NN){
        float v = acc[t][r];
        if (g==0){
          if (col < 128)      out_sc[(size_t)n*512 + col] = v;
          else if (col < 256){
            int cc = col-128;
            upk16[(size_t)n*512 + (cc&63)*8 + (cc>>6)] = f2bh(v);
          } else              res_s[(size_t)n*256 + col-256] = v;
        } else {
          int i = g-1;
          if (col < 128)      out_sc[(size_t)n*512 + 128 + col*3 + i] = v;
          else if (col < 256){
            int cc = col-128;
            upk16[(size_t)n*512 + (cc&63)*8 + (1+i)*2 + (cc>>6)] = f2bh(v);
          } else              res_v[((size_t)n*3+i)*128 + col-256] = v;
        }
      }
    }
  }
}

// ---------------- CSR build ----------------
__global__ __launch_bounds__(256) void k_deg(const int* __restrict__ eidx, int* __restrict__ deg){
  int i = blockIdx.x*256+threadIdx.x;
  if (i<NE) atomicAdd(&deg[eidx[2*i+1]],1);
}
__global__ __launch_bounds__(256) void k_scan(const int* __restrict__ deg, int* __restrict__ offsets){
  __shared__ int part[256];
  int t = threadIdx.x; int base = t*40;
  int s=0;
  for (int k=0;k<40;k++){ int idx=base+k; if (idx<NN) s+=deg[idx]; }
  part[t]=s; __syncthreads();
  if (t==0){ int run=0; for (int i=0;i<256;i++){ int v=part[i]; part[i]=run; run+=v; } }
  __syncthreads();
  int run = part[t];
  for (int k=0;k<40;k++){
    int idx=base+k;
    if (idx<=NN) offsets[idx]=run;
    if (idx<NN) run+=deg[idx];
  }
}
// fill: materialize CSR-ordered edge data
__global__ __launch_bounds__(256) void k_fill(
    const int* __restrict__ eidx, const float* __restrict__ ef, const float* __restrict__ ea,
    const int* __restrict__ offsets, int* __restrict__ cursor,
    int* __restrict__ sndbuf, int* __restrict__ rcvbuf,
    float4* __restrict__ ybuf, float* __restrict__ efb){
  int i = blockIdx.x*256+threadIdx.x;
  if (i<NE){
    int sn = eidx[2*i], rc = eidx[2*i+1];
    int p = offsets[rc] + atomicAdd(&cursor[rc],1);
    sndbuf[p]=sn; rcvbuf[p]=rc;
    ybuf[p] = ((const float4*)ea)[i];
    *(float4*)&efb[(size_t)p*8]     = *(const float4*)&ef[(size_t)i*8];
    *(float4*)&efb[(size_t)p*8 + 4] = *(const float4*)&ef[(size_t)i*8 + 4];
  }
}

// ---------------- K2: edge MLP, 32 edges/wave, batched layer1 loads ----------------
__global__ __launch_bounds__(128) void k_tpw(
    const int* __restrict__ sndbuf, const int* __restrict__ rcvbuf,
    const float* __restrict__ efb,
    const float* __restrict__ pA, const float* __restrict__ pB,
    const float* __restrict__ Wr1, const float* __restrict__ Wd1, const float* __restrict__ Wd2,
    const unsigned short* __restrict__ WTr2, const unsigned short* __restrict__ WTr3,
    const unsigned short* __restrict__ WTr4,
    const int* __restrict__ offsets, int nstart, int nend, int cap,
    unsigned* __restrict__ tpwp, float* __restrict__ densbuf){
  __shared__ unsigned short hS[64][72];   // single buffer: layers run in place
  int ebase = offsets[nstart];
  int eend  = min(offsets[nend], ebase + cap);
  int i0 = ebase + blockIdx.x*64;
  if (i0 >= eend) return;
  int nrows = min(64, eend - i0);
  int tid = threadIdx.x;
  int w = tid>>6, l = tid&63, m0 = w*32, lr = l&15, lg = l>>4;
  int wbase = i0 + m0;
  // metadata: lane l<32 snd, l>=32 rcv (32 edges)
  int v_meta;
  {
    int pos = min(wbase + (l&31), eend-1);
    v_meta = (l < 32) ? sndbuf[pos] : rcvbuf[pos];
  }
  // ef regs: rq holds ef[edge=l&31][k = 2q + (l>>5)]
  float r0,r1,r2,r3;
  {
    int pos = min(wbase + (l&31), eend-1);
    int hi = l>>5;
    r0 = efb[(size_t)pos*8 + 0 + hi];
    r1 = efb[(size_t)pos*8 + 2 + hi];
    r2 = efb[(size_t)pos*8 + 4 + hi];
    r3 = efb[(size_t)pos*8 + 6 + hi];
  }
  // ---- layer1 (VALU, f32), 32 rows, 4 batches of 8 with preloaded av/bv ----
  {
    float wr[8], wd[8];
    #pragma unroll
    for (int k=0;k<8;k++){ wr[k]=Wr1[k*64+l]; wd[k]=Wd1[k*64+l]; }
    float wd2c = Wd2[l];
    #pragma unroll
    for (int jb=0; jb<4; ++jb){
      float2 avb[8], bvb[8];
      #pragma unroll
      for (int q=0;q<8;q++){
        int j = jb*8+q;
        int sn = __shfl(v_meta, j);
        int rc = __shfl(v_meta, 32+j);
        avb[q] = *(const float2*)&pA[(size_t)sn*128 + l*2];
        bvb[q] = *(const float2*)&pB[(size_t)rc*128 + l*2];
      }
      #pragma unroll
      for (int q=0;q<8;q++){
        int j = jb*8+q;
        float e0=__shfl(r0,j), e1=__shfl(r0,32+j);
        float e2=__shfl(r1,j), e3=__shfl(r1,32+j);
        float e4=__shfl(r2,j), e5=__shfl(r2,32+j);
        float e6=__shfl(r3,j), e7=__shfl(r3,32+j);
        float h  = avb[q].x + bvb[q].x;
        float hd = avb[q].y + bvb[q].y;
        h  += e0*wr[0]+e1*wr[1]+e2*wr[2]+e3*wr[3]+e4*wr[4]+e5*wr[5]+e6*wr[6]+e7*wr[7];
        hd += e0*wd[0]+e1*wd[1]+e2*wd[2]+e3*wd[3]+e4*wd[4]+e5*wd[5]+e6*wd[6]+e7*wd[7];
        hS[m0+j][l] = f2bh(silu_f(h));
        float sv = silu_f(hd)*wd2c;
        #pragma unroll
        for (int m=32;m;m>>=1) sv += __shfl_xor(sv, m);
        if (l==0 && m0+j < nrows) densbuf[wbase + j] = tanhf(sv*sv);
      }
    }
  }
  // ---- layer2: in-place (A hoisted to regs first; wave-private rows) ----
  {
    bf16x8 a0[2], a1[2];
    #pragma unroll
    for (int kb=0;kb<2;kb++){
      a0[kb] = *(const bf16x8*)&hS[m0+lr][kb*32 + lg*8];
      a1[kb] = *(const bf16x8*)&hS[m0+16+lr][kb*32 + lg*8];
    }
    #pragma unroll
    for (int nt=0;nt<4;nt++){
      f32x4 c0=(f32x4)(0.f), c1=(f32x4)(0.f);
      #pragma unroll
      for (int kb=0;kb<2;kb++){
        bf16x8 b = *(const bf16x8*)&WTr2[(nt*16+lr)*64 + kb*32 + lg*8];
        c0 = __builtin_amdgcn_mfma_f32_16x16x32_bf16(a0[kb], b, c0, 0,0,0);
        c1 = __builtin_amdgcn_mfma_f32_16x16x32_bf16(a1[kb], b, c1, 0,0,0);
      }
      #pragma unroll
      for (int r=0;r<4;r++){
        hS[m0+lg*4+r][nt*16+lr]    = f2bh(silu_f(c0[r]));
        hS[m0+16+lg*4+r][nt*16+lr] = f2bh(silu_f(c1[r]));
      }
    }
  }
  // ---- layer3: in-place ----
  {
    bf16x8 a0[2], a1[2];
    #pragma unroll
    for (int kb=0;kb<2;kb++){
      a0[kb] = *(const bf16x8*)&hS[m0+lr][kb*32 + lg*8];
      a1[kb] = *(const bf16x8*)&hS[m0+16+lr][kb*32 + lg*8];
    }
    #pragma unroll
    for (int nt=0;nt<4;nt++){
      f32x4 c0=(f32x4)(0.f), c1=(f32x4)(0.f);
      #pragma unroll
      for (int kb=0;kb<2;kb++){
        bf16x8 b = *(const bf16x8*)&WTr3[(nt*16+lr)*64 + kb*32 + lg*8];
        c0 = __builtin_amdgcn_mfma_f32_16x16x32_bf16(a0[kb], b, c0, 0,0,0);
        c1 = __builtin_amdgcn_mfma_f32_16x16x32_bf16(a1[kb], b, c1, 0,0,0);
      }
      #pragma unroll
      for (int r=0;r<4;r++){
        hS[m0+lg*4+r][nt*16+lr]    = f2bh(silu_f(c0[r]));
        hS[m0+16+lg*4+r][nt*16+lr] = f2bh(silu_f(c1[r]));
      }
    }
  }
  // ---- layer4: A-hoisted, B reused across the two batches, packed u32 out ----
  {
    bf16x8 a0[2], a1[2];
    #pragma unroll
    for (int kb=0;kb<2;kb++){
      a0[kb] = *(const bf16x8*)&hS[m0+lr][kb*32 + lg*8];
      a1[kb] = *(const bf16x8*)&hS[m0+16+lr][kb*32 + lg*8];
    }
    int erow0 = i0 - ebase;
    #pragma unroll
    for (int nt=0; nt<4; nt++){
      unsigned pv0[4][4], pv1[4][4];   // [r][G]
      #pragma unroll
      for (int G=0; G<4; G++){
        f32x4 e0=(f32x4)(0.f), o0=(f32x4)(0.f), e1=(f32x4)(0.f), o1=(f32x4)(0.f);
        #pragma unroll
        for (int kb=0; kb<2; kb++){
          bf16x8 bE = *(const bf16x8*)&WTr4[((2*G)*64+nt*16+lr)*64 + kb*32 + lg*8];
          bf16x8 bO = *(const bf16x8*)&WTr4[((2*G+1)*64+nt*16+lr)*64 + kb*32 + lg*8];
          e0 = __builtin_amdgcn_mfma_f32_16x16x32_bf16(a0[kb], bE, e0, 0,0,0);
          o0 = __builtin_amdgcn_mfma_f32_16x16x32_bf16(a0[kb], bO, o0, 0,0,0);
          e1 = __builtin_amdgcn_mfma_f32_16x16x32_bf16(a1[kb], bE, e1, 0,0,0);
          o1 = __builtin_amdgcn_mfma_f32_16x16x32_bf16(a1[kb], bO, o1, 0,0,0);
        }
        #pragma unroll
        for (int r=0;r<4;r++){
          pv0[r][G] = f2b2(e0[r], o0[r]);
          pv1[r][G] = f2b2(e1[r], o1[r]);
        }
      }
      #pragma unroll
      for (int r=0;r<4;r++){
        int row0 = m0 + lg*4 + r;
        int row1 = m0 + 16 + lg*4 + r;
        if (row0 < nrows)
          *(uint4*)&tpwp[(size_t)(erow0+row0)*256 + (nt*16+lr)*4] = *(uint4*)&pv0[r][0];
        if (row1 < nrows)
          *(uint4*)&tpwp[(size_t)(erow0+row1)*256 + (nt*16+lr)*4] = *(uint4*)&pv1[r][0];
      }
    }
  }
}

// ---------------- K3: CSR gather — 4 waves per node (1 block/node), LDS combine ------
__global__ __launch_bounds__(256) void k_gather(
    const unsigned* __restrict__ tpwp, const float4* __restrict__ ybuf,
    const int* __restrict__ sndbuf, const float* __restrict__ densbuf,
    const uint4* __restrict__ upk4,
    const int* __restrict__ offsets, int nstart,
    unsigned short* __restrict__ msg_s16, unsigned short* __restrict__ msg_v16,
    float* __restrict__ density){
  __shared__ float part[3][1024];
  __shared__ float pden[3];
  int w = threadIdx.x>>6, l = threadIdx.x&63;
  int n = nstart + blockIdx.x;
  int ebase = offsets[nstart];
  int s0 = offsets[n], s1 = offsets[n+1];
  float mA0=0,mA1=0,mD0=0,mD1=0;
  float mB00=0,mB01=0,mB10=0,mB11=0,mB20=0,mB21=0;
  float mC00=0,mC01=0,mC10=0,mC11=0,mC20=0,mC21=0;
  float dsum=0;
  #pragma unroll 2
  for (int i=s0+w; i<s1; i+=4){
    int li = i - ebase;
    int sn = sndbuf[i];
    float4 y = ybuf[i];
    dsum += densbuf[i];
    uint4 tq = *(const uint4*)&tpwp[(size_t)li*256 + l*4];
    uint4 uq = upk4[(size_t)sn*64 + l];
    float wA0=b2f_lo(tq.x), wA1=b2f_hi(tq.x);
    float wB0=b2f_lo(tq.y), wB1=b2f_hi(tq.y);
    float wC0=b2f_lo(tq.z), wC1=b2f_hi(tq.z);
    float wD0=b2f_lo(tq.w), wD1=b2f_hi(tq.w);
    float xs0=b2f_lo(uq.x), xs1=b2f_hi(uq.x);
    float xv00=b2f_lo(uq.y), xv01=b2f_hi(uq.y);
    float xv10=b2f_lo(uq.z), xv11=b2f_hi(uq.z);
    float xv20=b2f_lo(uq.w), xv21=b2f_hi(uq.w);
    mA0 += wA0*xs0*y.x; mA1 += wA1*xs1*y.x;
    float dot0 = xv00*y.y + xv10*y.z + xv20*y.w;
    float dot1 = xv01*y.y + xv11*y.z + xv21*y.w;
    mD0 += wD0*dot0; mD1 += wD1*dot1;
    float b0 = wB0*xs0, b1 = wB1*xs1;
    mB00 += b0*y.y; mB01 += b1*y.y;
    mB10 += b0*y.z; mB11 += b1*y.z;
    mB20 += b0*y.w; mB21 += b1*y.w;
    float c0 = wC0*y.x, c1 = wC1*y.x;
    mC00 += c0*xv00; mC01 += c1*xv01;
    mC10 += c0*xv10; mC11 += c1*xv11;
    mC20 += c0*xv20; mC21 += c1*xv21;
  }
  if (w){
    float* P = part[w-1];
    P[0*64+l]=mA0;  P[1*64+l]=mA1;  P[2*64+l]=mD0;  P[3*64+l]=mD1;
    P[4*64+l]=mB00; P[5*64+l]=mB01; P[6*64+l]=mB10; P[7*64+l]=mB11;
    P[8*64+l]=mB20; P[9*64+l]=mB21; P[10*64+l]=mC00; P[11*64+l]=mC01;
    P[12*64+l]=mC10; P[13*64+l]=mC11; P[14*64+l]=mC20; P[15*64+l]=mC21;
    if (l==0) pden[w-1]=dsum;
  }
  __syncthreads();
  if (w==0){
    #pragma unroll
    for (int q=0;q<3;q++){
      const float* P = part[q];
      mA0+=P[0*64+l];  mA1+=P[1*64+l];  mD0+=P[2*64+l];  mD1+=P[3*64+l];
      mB00+=P[4*64+l]; mB01+=P[5*64+l]; mB10+=P[6*64+l]; mB11+=P[7*64+l];
      mB20+=P[8*64+l]; mB21+=P[9*64+l]; mC00+=P[10*64+l]; mC01+=P[11*64+l];
      mC10+=P[12*64+l]; mC11+=P[13*64+l]; mC20+=P[14*64+l]; mC21+=P[15*64+l];
    }
    dsum += pden[0]+pden[1]+pden[2];
    unsigned short* ms = msg_s16 + (size_t)n*256;
    ms[l]=f2bh(mA0); ms[64+l]=f2bh(mA1);
    ms[128+l]=f2bh(mD0*INV_SQRT3); ms[192+l]=f2bh(mD1*INV_SQRT3);
    unsigned short* mv = msg_v16 + (size_t)n*768;
    mv[l]=f2bh(mB00);     mv[64+l]=f2bh(mB01);  mv[128+l]=f2bh(mC00); mv[192+l]=f2bh(mC01);
    mv[256+l]=f2bh(mB10); mv[320+l]=f2bh(mB11); mv[384+l]=f2bh(mC10); mv[448+l]=f2bh(mC11);
    mv[512+l]=f2bh(mB20); mv[576+l]=f2bh(mB21); mv[640+l]=f2bh(mC20); mv[704+l]=f2bh(mC21);
    if (l==0) density[n]=dsum;
  }
}

// ---------------- K4a: lin1 for all 5 N=128 chunks. grid (NB64, 5) ----------------
__global__ __launch_bounds__(256) void k_post1(
    const unsigned short* __restrict__ msg_s16, const unsigned short* __restrict__ msg_v16,
    const float* __restrict__ density,
    const float* __restrict__ res_s, const float* __restrict__ res_v,
    const unsigned short* __restrict__ Wl10T, const unsigned short* __restrict__ Wl11T,
    const float* __restrict__ alphap, const float* __restrict__ betap,
    unsigned short* __restrict__ scal16, unsigned short* __restrict__ gate16,
    unsigned short* __restrict__ vtmp16){
  __shared__ unsigned short sm[64][264];
  __shared__ float sden[64];
  int nb = blockIdx.x*64, y = blockIdx.y;
  int tid = threadIdx.x;
  int w = tid>>6, l = tid&63, m0 = w*16, lr = l&15, lg = l>>4;
  for (int idx=tid; idx<64*32; idx+=256){
    int row = idx>>5, s8 = idx&31;
    int n = min(nb+row, NN-1);
    const unsigned short* src = (y<2)? &msg_s16[(size_t)n*256 + s8*8]
                                     : &msg_v16[(size_t)n*768 + (y-2)*256 + s8*8];
    *(uint4*)&sm[row][s8*8] = *(const uint4*)src;
  }
  if (tid < 64){
    int n = min(nb+tid, NN-1);
    sden[tid] = density[n]*betap[0] + alphap[0]*20.0f;
  }
  __syncthreads();
  const unsigned short* BT = (y<2)? (Wl10T + (size_t)y*128*256) : Wl11T;
  f32x4 acc[8];
  #pragma unroll
  for (int t=0;t<8;t++) acc[t]=(f32x4)(0.f);
  for (int kb=0;kb<8;kb++){
    bf16x8 a = *(const bf16x8*)&sm[m0+lr][kb*32 + lg*8];
    #pragma unroll
    for (int t=0;t<8;t++){
      bf16x8 b = *(const bf16x8*)&BT[(size_t)(t*16+lr)*256 + kb*32 + lg*8];
      acc[t] = __builtin_amdgcn_mfma_f32_16x16x32_bf16(a, b, acc[t], 0,0,0);
    }
  }
  #pragma unroll
  for (int t=0;t<8;t++){
    #pragma unroll
    for (int r=0;r<4;r++){
      int col = t*16+lr;
      int row = m0 + lg*4 + r;
      int n = nb + row;
      if (n < NN){
        float v = acc[t][r]/sden[row];
        if (y==0){
          v += res_s[(size_t)n*256 + col];
          scal16[(size_t)n*128 + col] = f2bh(silu_f(v));
        } else if (y==1){
          v += res_s[(size_t)n*256 + 128 + col];
          gate16[(size_t)n*128 + col] = f2bh(sigmoid_f(v));
        } else {
          int i = y-2;
          v += res_v[((size_t)n*3+i)*128 + col];
          vtmp16[((size_t)i*NN + n)*128 + col] = f2bh(v);
        }
      }
    }
  }
}

// ---------------- K4b: lin2 for 4 output components. grid (NB64, 4) ----------------
__global__ __launch_bounds__(256) void k_post2(
    const unsigned short* __restrict__ scal16, const unsigned short* __restrict__ gate16,
    const unsigned short* __restrict__ vtmp16,
    const unsigned short* __restrict__ Wl20T, const unsigned short* __restrict__ Wl21T,
    float* __restrict__ out_msg){
  __shared__ unsigned short sA[64][136];
  int nb = blockIdx.x*64, y = blockIdx.y;
  int tid = threadIdx.x;
  int w = tid>>6, l = tid&63, m0 = w*16, lr = l&15, lg = l>>4;
  for (int idx=tid; idx<64*16; idx+=256){
    int row = idx>>4, s8 = idx&15;
    int n = min(nb+row, NN-1);
    if (y==0){
      *(uint4*)&sA[row][s8*8] = *(const uint4*)&scal16[(size_t)n*128 + s8*8];
    } else {
      int i = y-1;
      uint4 va = *(const uint4*)&vtmp16[((size_t)i*NN + n)*128 + s8*8];
      uint4 vg = *(const uint4*)&gate16[(size_t)n*128 + s8*8];
      const unsigned short* pa = (const unsigned short*)&va;
      const unsigned short* pg = (const unsigned short*)&vg;
      unsigned short o[8];
      #pragma unroll
      for (int j=0;j<8;j++) o[j] = f2bh(b2f(pa[j])*b2f(pg[j]));
      *(uint4*)&sA[row][s8*8] = *(const uint4*)o;
    }
  }
  __syncthreads();
  const unsigned short* BT = (y==0)? Wl20T : Wl21T;
  f32x4 acc[8];
  #pragma unroll
  for (int t=0;t<8;t++) acc[t]=(f32x4)(0.f);
  #pragma unroll
  for (int kb=0;kb<4;kb++){
    bf16x8 a = *(const bf16x8*)&sA[m0+lr][kb*32 + lg*8];
    #pragma unroll
    for (int t=0;t<8;t++){
      bf16x8 b = *(const bf16x8*)&BT[(size_t)(t*16+lr)*128 + kb*32 + lg*8];
      acc[t] = __builtin_amdgcn_mfma_f32_16x16x32_bf16(a, b, acc[t], 0,0,0);
    }
  }
  #pragma unroll
  for (int t=0;t<8;t++){
    #pragma unroll
    for (int r=0;r<4;r++){
      int col = t*16+lr;
      int n = nb + m0 + lg*4 + r;
      if (n < NN) out_msg[(size_t)n*512 + col*4 + y] = acc[t][r];
    }
  }
}

extern "C" void kernel_launch(void* const* d_in, const int* in_sizes, int n_in,
                              void* d_out, int out_size, void* d_ws, size_t ws_size,
                              hipStream_t stream){
  (void)in_sizes; (void)n_in; (void)out_size;
  const float* attrs = (const float*)d_in[0];
  const float* feats = (const float*)d_in[1];
  const float* ea    = (const float*)d_in[2];
  const float* ef    = (const float*)d_in[3];
  const float* Wsrc  = (const float*)d_in[4];
  const float* Wtgt  = (const float*)d_in[5];
  const float* Wup0  = (const float*)d_in[6];
  const float* Wup1  = (const float*)d_in[7];
  const float* Wsk0  = (const float*)d_in[8];
  const float* Wsk1  = (const float*)d_in[9];
  const float* Wres0 = (const float*)d_in[10];
  const float* Wres1 = (const float*)d_in[11];
  const float* Wl10  = (const float*)d_in[12];
  const float* Wl11  = (const float*)d_in[13];
  const float* Wl20  = (const float*)d_in[14];
  const float* Wl21  = (const float*)d_in[15];
  const float* Wr1   = (const float*)d_in[16];
  const float* Wr2   = (const float*)d_in[17];
  const float* Wr3   = (const float*)d_in[18];
  const float* Wr4   = (const float*)d_in[19];
  const float* Wd1   = (const float*)d_in[20];
  const float* Wd2   = (const float*)d_in[21];
  const float* alphap= (const float*)d_in[22];
  const float* betap = (const float*)d_in[23];
  const int*   eidx  = (const int*)d_in[24];

  const size_t fixed_bytes =
      (size_t)NN*(512 + 1536 + 1024 + 1536 + 4 + 1024 + 256 + 768 + 512 + 512 + 256) +
      (size_t)NE*60 +
      (size_t)286976*2 + 4*ADIM*64*4 +
      (10240+10240+10256)*4 + 64*256;
  int nchunk, npc, cap;
  if (fixed_bytes + (size_t)NE*1024 + 65536 <= ws_size){ nchunk=1; npc=NN;   cap=NE;    }
  else if (fixed_bytes + 81920ULL*1024 + 65536 <= ws_size){ nchunk=2; npc=5000; cap=81920; }
  else { nchunk=4; npc=2500; cap=44032; }

  char* p = (char*)d_ws;
  auto alloc = [&](size_t bytes)->char*{ char* r=p; p += (bytes+255)&~(size_t)255; return r; };
  unsigned* tpwp  = (unsigned*)alloc((size_t)cap*256*4);
  unsigned short* msg_s16 = (unsigned short*)alloc((size_t)NN*256*2);
  unsigned short* msg_v16 = (unsigned short*)alloc((size_t)NN*768*2);
  float*  res_s   = (float*)alloc((size_t)NN*256*4);
  float*  res_v   = (float*)alloc((size_t)NN*384*4);
  float*  density = (float*)alloc((size_t)NN*4);
  float4* ybuf    = (float4*)alloc((size_t)NE*16);
  float*  densbuf = (float*)alloc((size_t)NE*4);
  int*    sndbuf  = (int*)alloc((size_t)NE*4);
  int*    rcvbuf  = (int*)alloc((size_t)NE*4);
  float*  efb     = (float*)alloc((size_t)NE*32);
  uint4*  upk     = (uint4*)alloc((size_t)NN*64*16);
  unsigned short* fs16 = (unsigned short*)alloc((size_t)NN*128*2);
  unsigned short* fv16 = (unsigned short*)alloc((size_t)NN*384*2);
  float* pA = (float*)alloc((size_t)NN*128*4);
  float* pB = (float*)alloc((size_t)NN*128*4);
  float* Wc  = (float*)alloc(4*ADIM*64*4);
  unsigned short* gate16 = (unsigned short*)alloc((size_t)NN*128*2);
  unsigned short* WTr2 = (unsigned short*)alloc(4096*2);
  unsigned short* WTr3 = (unsigned short*)alloc(4096*2);
  unsigned short* WTr4 = (unsigned short*)alloc(32768*2);
  unsigned short* Wl10T = (unsigned short*)alloc(65536*2);
  unsigned short* Wl11T = (unsigned short*)alloc(32768*2);
  unsigned short* Wl20T = (unsigned short*)alloc(16384*2);
  unsigned short* Wl21T = (unsigned short*)alloc(16384*2);
  unsigned short* WnsT  = (unsigned short*)alloc(65536*2);
  unsigned short* WnvT  = (unsigned short*)alloc(49152*2);
  int* deg     = (int*)alloc(10240*4);
  int* cursor  = (int*)alloc(10240*4);
  int* offsets = (int*)alloc(10256*4);

  unsigned short* scal16 = fs16;   // NN*128, fs16 dead after k_node_pre2
  unsigned short* vtmp16 = fv16;   // 3*NN*128, fv16 dead after k_node_pre2

  float* out_msg = (float*)d_out;               // NN*512
  float* out_sc  = out_msg + (size_t)NN*512;    // NN*512

  hipMemsetAsync(deg, 0, 2*10240*sizeof(int), stream);

  k_prep<<<1121, 256, 0, stream>>>(Wr2, Wr3, Wr4, Wl10, Wl11, Wl20, Wl21,
                                   Wsk0, Wup0, Wres0, Wsk1, Wup1, Wres1,
                                   Wsrc, Wtgt, Wr1, Wd1,
                                   WTr2, WTr3, WTr4,
                                   Wl10T, Wl11T, Wl20T, Wl21T, WnsT, WnvT, Wc);
  k_nf<<<22500, 256, 0, stream>>>(attrs, Wc, pA, pB, feats, fs16, fv16);
  k_node_pre2<<<dim3(NB64,13), 256, 0, stream>>>(fs16, fv16, WnsT, WnvT,
                                                 out_sc, (unsigned short*)upk, res_s, res_v);
  k_deg<<<(NE+255)/256, 256, 0, stream>>>(eidx, deg);
  k_scan<<<1, 256, 0, stream>>>(deg, offsets);
  k_fill<<<(NE+255)/256, 256, 0, stream>>>(eidx, ef, ea, offsets, cursor,
                                           sndbuf, rcvbuf, ybuf, efb);

  int tpw_blocks = (cap+63)/64;
  for (int c=0; c<nchunk; ++c){
    k_tpw<<<tpw_blocks, 128, 0, stream>>>(sndbuf, rcvbuf, efb, pA, pB,
                                          Wr1, Wd1, Wd2, WTr2, WTr3, WTr4,
                                          offsets, c*npc, (c+1)*npc, cap,
                                          tpwp, densbuf);
    k_gather<<<npc, 256, 0, stream>>>(tpwp, ybuf, sndbuf, densbuf, upk,
                                      offsets, c*npc, msg_s16, msg_v16, density);
  }

  k_post1<<<dim3(NB64,5), 256, 0, stream>>>(msg_s16, msg_v16, density, res_s, res_v,
                                            Wl10T, Wl11T, alphap, betap,
                                            scal16, gate16, vtmp16);
  k_post2<<<dim3(NB64,4), 256, 0, stream>>>(scal16, gate16, vtmp16,
                                            Wl20T, Wl21T, out_msg);
}